// Round 7
// baseline (1124.310 us; speedup 1.0000x reference)
//
#include <hip/hip_runtime.h>
#include <hip/hip_bf16.h>

typedef unsigned short ushort_t;
typedef __attribute__((ext_vector_type(8))) short short8v;
typedef __attribute__((ext_vector_type(4))) float f32x4;

__device__ __forceinline__ ushort_t f2bs(float v) {
  union { __hip_bfloat16 h; ushort_t u; } cv;
  cv.h = __float2bfloat16(v);
  return cv.u;
}
__device__ __forceinline__ float bs2f(ushort_t u) {
  union { ushort_t u; __hip_bfloat16 h; } cv;
  cv.u = u;
  return __bfloat162float(cv.h);
}

__device__ __forceinline__ void glds16(const ushort_t* g, ushort_t* l) {
  __builtin_amdgcn_global_load_lds(
      (const __attribute__((address_space(1))) unsigned int*)(uintptr_t)g,
      (__attribute__((address_space(3))) unsigned int*)(unsigned int)(uintptr_t)l,
      16, 0, 0);
}

// ---------------- workspace layout ----------------
static constexpr size_t OFF_P = 0;
static constexpr size_t OFF_ENORM = 4194304;
static constexpr size_t OFF_WTD2 = 4194816;
static constexpr size_t OFF_ACC = 4207360;
static constexpr size_t OFF_ZROW = 4207368;
static constexpr size_t OFF_EMBT = 4207432;   // fp32 embT [c=256][code=512]
static constexpr size_t OFF_SSQ = 4338504;    // 8 slots x 256 samples
static constexpr size_t OFF_SHORT = 4340552;  // 16B aligned (x4 bytes)
static constexpr size_t SO_H1H = 0;
static constexpr size_t SO_H1L = 16777216;
static constexpr size_t SO_NBH = 33554432;
static constexpr size_t SO_NBL = 37748736;
static constexpr size_t SO_W1H = 41943040;
static constexpr size_t SO_W1L = 41959424;
static constexpr size_t SO_W2H = 41975808;
static constexpr size_t SO_W2L = 43024384;
static constexpr size_t SO_W3EH = 44072960;
static constexpr size_t SO_W3EL = 45252608;
static constexpr size_t SO_W3D = 46432256;
static constexpr size_t SO_W1REH = 47611904;
static constexpr size_t SO_W1REL = 47742976;
static constexpr size_t SO_W1RD = 47874048;
static constexpr size_t SO_WD1 = 48005120;

__device__ __forceinline__ void split_store(float v, ushort_t* hi, ushort_t* lo, size_t i) {
  ushort_t h = f2bs(v);
  hi[i] = h;
  lo[i] = f2bs(v - bs2f(h));
}

// ---------------- fused prep ----------------
// ranges: [0,64) w1 | [64,4160) w2 | [4160,8768) w3e | [8768,13376) w3d
// [13376,13888) w1re | [13888,14400) w1rd | [14400,18496) wd1 | [18496,18544) dec2
// [18544,18546) enorm | 18546 zero | [18547,34931) conv1 im2col (16384 blocks EXACT)
// [34931,35443) embT
__global__ void __launch_bounds__(256) k_prep(
    const float* __restrict__ x, const float* __restrict__ ew1,
    const float* __restrict__ ew2, const float* __restrict__ r3w,
    const float* __restrict__ r1w, const float* __restrict__ dw1,
    const float* __restrict__ dw2, const float* __restrict__ emb,
    ushort_t* __restrict__ W1H, ushort_t* __restrict__ W1L,
    ushort_t* __restrict__ W2H, ushort_t* __restrict__ W2L,
    ushort_t* __restrict__ W3EH, ushort_t* __restrict__ W3EL,
    ushort_t* __restrict__ W3D, ushort_t* __restrict__ W1REH,
    ushort_t* __restrict__ W1REL, ushort_t* __restrict__ W1RD,
    ushort_t* __restrict__ WD1, float* __restrict__ wTd2,
    float* __restrict__ enorm, float* __restrict__ acc, float* __restrict__ zrow,
    float* __restrict__ embT, float* __restrict__ ssq,
    ushort_t* __restrict__ A1H, ushort_t* __restrict__ A1L) {
  int b = blockIdx.x, t = threadIdx.x;
  if (b < 64) {
    int i = b * 256 + t;
    int oc = i >> 6, k = i & 63;
    float v = 0.f;
    if (k < 48) {
      int tap = k / 3, ic = k - 3 * tap;
      v = ew1[(oc * 3 + ic) * 16 + tap];
    }
    split_store(v, W1H, W1L, i);
  } else if (b < 4160) {
    int i = (b - 64) * 256 + t;
    int oc = i >> 12, k = i & 4095;
    int tap = k >> 8, ic = k & 255;
    split_store(ew2[(oc * 256 + ic) * 16 + tap], W2H, W2L, i);
  } else if (b < 8768) {
    int i = (b - 4160) * 256 + t;
    int rb = i / 589824, r2 = i - rb * 589824;
    int oc = r2 / 2304, k = r2 - oc * 2304;
    int r9 = k >> 8, ic = k & 255;
    split_store(r3w[((rb * 256 + oc) * 256 + ic) * 9 + r9], W3EH, W3EL, i);
  } else if (b < 13376) {
    int i = (b - 8768) * 256 + t;
    int rb = i / 589824, r2 = i - rb * 589824;
    int oc = r2 / 2304, k = r2 - oc * 2304;
    int r9 = k >> 8, ic = k & 255;
    W3D[i] = f2bs(r3w[(((rb + 2) * 256 + oc) * 256 + ic) * 9 + r9]);
  } else if (b < 13888) {
    int i = (b - 13376) * 256 + t;
    split_store(r1w[i], W1REH, W1REL, i);
  } else if (b < 14400) {
    int i = (b - 13888) * 256 + t;
    W1RD[i] = f2bs(r1w[2 * 65536 + i]);
  } else if (b < 18496) {
    int i = (b - 14400) * 256 + t;
    int cls = i >> 18, r2 = i & 262143;
    int oc = r2 >> 10, k = r2 & 1023;
    int tap = k >> 8, ic = k & 255;
    int s = tap >> 1, sx = tap & 1;
    int py = cls >> 1, px = cls & 1;
    int ky = py + 2 - 2 * s, kx = px + 2 - 2 * sx;
    WD1[i] = f2bs(dw1[(ic * 256 + oc) * 16 + ky * 4 + kx]);
  } else if (b < 18544) {
    // dec2 weights, layout [py][px][ic][tap*3+oc]; tap0=(py+2,px+2),
    // tap1=(py+2,px), tap2=(py,px+2), tap3=(py,px)
    int i = (b - 18496) * 256 + t;
    if (i < 12288) {
      int j12 = i % 12;
      int r = i / 12;
      int ic = r & 255, pp = r >> 8;
      int py = pp >> 1, px = pp & 1;
      int tap = j12 / 3, oc = j12 - tap * 3;
      int ky = py + ((tap < 2) ? 2 : 0);
      int kx = px + (((tap & 1) == 0) ? 2 : 0);
      wTd2[i] = dw2[(ic * 3 + oc) * 16 + ky * 4 + kx];
    }
  } else if (b < 18546) {
    int e = (b - 18544) * 256 + t;
    float s = 0.f;
    for (int c = 0; c < 256; ++c) {
      float v = emb[e * 256 + c];
      s += v * v;
    }
    enorm[e] = s;
  } else if (b == 18546) {
    if (t < 2) acc[t] = 0.f;
    if (t < 64) zrow[t] = 0.f;
    for (int k = t; k < 2048; k += 256) ssq[k] = 0.f;
  } else if (b < 34931) {  // conv1 im2col: exactly 16384 blocks
    int i = (b - 18547) * 256 + t;
    int t1 = i >> 6, k = i & 63;
    float v = 0.f;
    if (k < 48) {
      int tap = k / 3, ic = k - 3 * tap;
      int n = t1 >> 8, oy = (t1 >> 4) & 15, ox = t1 & 15;
      int ky = tap >> 2, kx = tap & 3;
      int iy = 2 * oy - 1 + ky, ix = 2 * ox - 1 + kx;
      if ((unsigned)iy < 32u && (unsigned)ix < 32u)
        v = x[((n * 3 + ic) * 32 + iy) * 32 + ix];
    }
    split_store(v, A1H, A1L, i);
  } else {  // [34931, 35443): embT [c][code] fp32
    int i = (b - 34931) * 256 + t;
    int code = i >> 8, c = i & 255;
    embT[c * 512 + code] = emb[i];
  }
}

// ---------------- MFMA GEMM (full-width BN=256, BM=64, 8 waves, PIPE=3) ----
// Each block owns ALL 256 output channels for 64 rows -> A is staged exactly
// ONCE. All blocks read the SAME 32 KB B-slice per K-step -> B staging is
// L2-hit traffic. Counted-vmcnt depth-3 pipeline, vmcnt(5).
template <int MODE, int EPI, int STYLE, int SSQ>
__global__ __launch_bounds__(512) void k_gemm(const ushort_t* __restrict__ Ah,
                                              const ushort_t* __restrict__ Al,
                                              const ushort_t* __restrict__ Bh,
                                              const ushort_t* __restrict__ Bl, int K,
                                              const float* __restrict__ bias,
                                              const float* __restrict__ res,
                                              float* __restrict__ outf,
                                              ushort_t* __restrict__ outb,
                                              ushort_t* __restrict__ outb2,
                                              const ushort_t* __restrict__ zrow,
                                              float* __restrict__ ssqp) {
  constexpr int PIPE = 3;
  __shared__ __align__(16) ushort_t A0[PIPE][64 * 32];
  __shared__ __align__(16) ushort_t A1s[PIPE][64 * 32];
  __shared__ __align__(16) ushort_t B0[PIPE][256 * 32];
  __shared__ __align__(16) ushort_t B1[PIPE][256 * 32];
  const int t = threadIdx.x;
  const int w = t >> 6, l = t & 63;
  const int M0 = blockIdx.x * 64;
  int py = 0, px = 0;
  const ushort_t* Bb = Bh;
  if (MODE == 3) {
    int cls = blockIdx.z;
    py = cls >> 1;
    px = cls & 1;
    Bb = Bh + (size_t)cls * 262144;
  }
  const int srow = l & 15, chunk = l >> 4;
  const int fr = l & 15, quad = l >> 4;
  const int m_off = (w & 1) * 32, n_off = (w >> 1) * 64;
  const int mset = (m_off >> 4), nset = (n_off >> 4);

  // staging assignment
  const int aw = w & 3;              // A 16-row group this wave stages
  const bool aH = (w < 4);           // stage A-H (else A-L / A-hi-k)
  const int atok = M0 + aw * 16 + srow;
  const size_t bb0 = (size_t)(2 * w * 16 + srow) * K + chunk * 8;
  const size_t bb1 = (size_t)((2 * w + 1) * 16 + srow) * K + chunk * 8;

  f32x4 acc[2][4];
#pragma unroll
  for (int i = 0; i < 2; ++i)
#pragma unroll
    for (int j = 0; j < 4; ++j) acc[i][j] = (f32x4){0.f, 0.f, 0.f, 0.f};

  const int n1 = atok >> 6, oy1 = (atok >> 3) & 7, ox1 = atok & 7;
  const ushort_t* zp = zrow + chunk * 8;

  const int SUB = (STYLE == 1) ? 32 : 64;

  // persistent per-tap staging state (recomputed when (kk&255)==0)
  size_t r1s = 0;
  bool v1s = true;
  if (MODE == 0) r1s = (size_t)atok * K + chunk * 8;

  auto stage = [&](int kk, int s) {
    const ushort_t* pa;
    if (MODE == 0) {
      size_t o = r1s + kk;
      pa = aH ? (Ah + o) : ((STYLE == 1) ? (Al + o) : (Ah + o + 32));
    } else {
      if ((kk & 255) == 0) {
        int tap = kk >> 8;
        int iy, ix;
        unsigned lim;
        if (MODE == 1) {
          int ky = tap >> 2, kx = tap & 3;
          iy = 2 * oy1 - 1 + ky; ix = 2 * ox1 - 1 + kx;
          lim = 16u;
        } else if (MODE == 2) {
          int ky = tap / 3, kx = tap - ky * 3;
          iy = oy1 - 1 + ky; ix = ox1 - 1 + kx;
          lim = 8u;
        } else {
          int s2 = tap >> 1, sx = tap & 1;
          iy = oy1 + s2 - py; ix = ox1 + sx - px;
          lim = 8u;
        }
        v1s = ((unsigned)iy < lim && (unsigned)ix < lim);
        if (MODE == 1)
          r1s = (size_t)(((n1 << 8) + (iy << 4) + ix)) << 8;
        else
          r1s = (size_t)(((n1 << 6) + (iy << 3) + ix)) << 8;
      }
      int kin = (kk & 255) + chunk * 8;
      if (v1s)
        pa = aH ? (Ah + r1s + kin)
                : ((STYLE == 1) ? (Al + r1s + kin) : (Ah + r1s + kin + 32));
      else
        pa = zp;
    }
    size_t bo0 = bb0 + kk, bo1 = bb1 + kk;
    glds16(pa, (aH ? A0[s] : A1s[s]) + aw * 512);
    glds16(Bb + bo0, B0[s] + (2 * w) * 512);
    glds16(Bb + bo1, B0[s] + (2 * w + 1) * 512);
    glds16((STYLE == 1) ? (Bl + bo0) : (Bb + bo0 + 32), B1[s] + (2 * w) * 512);
    glds16((STYLE == 1) ? (Bl + bo1) : (Bb + bo1 + 32), B1[s] + (2 * w + 1) * 512);
  };

  auto compute = [&](int s) {
    short8v af0[2], af1[2], bf0[4], bf1[4];
#pragma unroll
    for (int mi = 0; mi < 2; ++mi) {
      af0[mi] = *(const short8v*)(A0[s] + (mset + mi) * 512 + quad * 128 + fr * 8);
      af1[mi] = *(const short8v*)(A1s[s] + (mset + mi) * 512 + quad * 128 + fr * 8);
    }
#pragma unroll
    for (int nj = 0; nj < 4; ++nj) {
      bf0[nj] = *(const short8v*)(B0[s] + (nset + nj) * 512 + quad * 128 + fr * 8);
      bf1[nj] = *(const short8v*)(B1[s] + (nset + nj) * 512 + quad * 128 + fr * 8);
    }
#pragma unroll
    for (int mi = 0; mi < 2; ++mi)
#pragma unroll
      for (int nj = 0; nj < 4; ++nj) {
        acc[mi][nj] =
            __builtin_amdgcn_mfma_f32_16x16x32_bf16(af0[mi], bf0[nj], acc[mi][nj], 0, 0, 0);
        if (STYLE == 1) {
          acc[mi][nj] =
              __builtin_amdgcn_mfma_f32_16x16x32_bf16(af1[mi], bf0[nj], acc[mi][nj], 0, 0, 0);
          acc[mi][nj] =
              __builtin_amdgcn_mfma_f32_16x16x32_bf16(af0[mi], bf1[nj], acc[mi][nj], 0, 0, 0);
        } else {
          acc[mi][nj] =
              __builtin_amdgcn_mfma_f32_16x16x32_bf16(af1[mi], bf1[nj], acc[mi][nj], 0, 0, 0);
        }
      }
  };

  // ---- counted-vmcnt pipeline (per-wave: 5 loads/step; <=10 in flight) ----
  {
    const int nt = K / SUB;
    stage(0, 0);
    int ns = 1;
    if (nt > 1) {
      stage(SUB, 1);
      ns = 2;
    }
    int cb = 0, sb2 = ns % PIPE;
    for (int tt = 0; tt < nt; ++tt) {
      if (ns > tt + 1) {
        asm volatile("s_waitcnt vmcnt(5)" ::: "memory");
      } else {
        asm volatile("s_waitcnt vmcnt(0)" ::: "memory");
      }
      asm volatile("s_barrier" ::: "memory");
      if (ns < nt) {
        stage(ns * SUB, sb2);
        ++ns;
        sb2 = (sb2 + 1 == PIPE) ? 0 : sb2 + 1;
      }
      compute(cb);
      cb = (cb + 1 == PIPE) ? 0 : cb + 1;
    }
  }

  float sq = 0.f;
#pragma unroll
  for (int mi = 0; mi < 2; ++mi) {
    int mrow = m_off + mi * 16 + quad * 4;
#pragma unroll
    for (int nj = 0; nj < 4; ++nj) {
      int col = n_off + nj * 16 + fr;
      float bv = bias[col];
#pragma unroll
      for (int i = 0; i < 4; ++i) {
        int m = M0 + mrow + i;
        float v = fmaxf(acc[mi][nj][i] + bv, 0.f);
        if (EPI == 1) {
          outf[(size_t)m * 256 + col] = v;
          if (SSQ) sq += v * v;
        } else if (EPI == 2) {
          size_t o = (size_t)m * 256 + col;
          float vv = res[o] + v;
          outf[o] = vv;
          if (SSQ) sq += vv * vv;
        } else if (EPI == 3) {
          int nn = m >> 6, jj = (m >> 3) & 7, ii = m & 7;
          int oy = 2 * jj + 1 - py, ox = 2 * ii + 1 - px;
          outb[(size_t)((nn << 8) + oy * 16 + ox) * 256 + col] = f2bs(v);
        } else if (EPI == 4) {
          size_t o = (size_t)m * 256 + col;
          ushort_t h = f2bs(v);
          outb[o] = h;
          outb2[o] = f2bs(v - bs2f(h));
        } else {  // EPI 5
          size_t o = (size_t)m * 256 + col;
          float vv = res[o] + v;
          outf[o] = vv;
          outb[o] = f2bs(vv);
        }
      }
    }
  }
  if (SSQ) {
#pragma unroll
    for (int off = 32; off > 0; off >>= 1) sq += __shfl_down(sq, off, 64);
    if (l == 0) atomicAdd(&ssqp[M0 >> 6], sq);
  }
}

// ---------------- rmsnorm normalize-only (scale from fused SSQ table) ----------
template <int SPLIT>
__global__ void __launch_bounds__(256) k_rmsnorm(const float* __restrict__ in,
                                                 const float* __restrict__ rmsw,
                                                 const float* __restrict__ ssq,
                                                 ushort_t* __restrict__ NBh,
                                                 ushort_t* __restrict__ NBl) {
  extern __shared__ float wT[];  // 64*257 floats
  int n = blockIdx.x, t = threadIdx.x;
  const float* p = in + (size_t)n * 16384;
  for (int k = 0; k < 64; ++k) {
    int i = k * 256 + t;  // i = c*64 + j
    wT[(i & 63) * 257 + (i >> 6)] = rmsw[i];
  }
  float scale = 1.0f / sqrtf(ssq[n] / 16384.f + 1.1920929e-07f);
  __syncthreads();
  ushort_t* oh = NBh + (size_t)n * 16384;
  ushort_t* ol = NBl + (size_t)n * 16384;
  for (int j = 0; j < 64; ++j) {
    int i = j * 256 + t;
    float v = p[i] * scale * wT[j * 257 + t];
    ushort_t h = f2bs(v);
    oh[i] = h;
    if (SPLIT) ol[i] = f2bs(v - bs2f(h));
  }
}

// ---------------- VQ (coalesced embT scores; fused q-SSQ) ----------------
__global__ void __launch_bounds__(256) k_vq(const float* __restrict__ enc,
                                            const float* __restrict__ embT,
                                            const float* __restrict__ emb,
                                            const float* __restrict__ enorm,
                                            float* __restrict__ q, float* __restrict__ sse,
                                            float* __restrict__ ssq4) {
  __shared__ float z[16][256];
  __shared__ float sc[512 * 16];
  __shared__ float bv[16][16];
  __shared__ int bi[16][16];
  __shared__ int idxs[16];
  int T0 = blockIdx.x * 16;
  int t = threadIdx.x;
  for (int j = 0; j < 16; ++j) z[j][t] = enc[(size_t)(T0 + j) * 256 + t];
  __syncthreads();
  float d0[16], d1[16];
#pragma unroll
  for (int j = 0; j < 16; ++j) { d0[j] = 0.f; d1[j] = 0.f; }
  for (int c4 = 0; c4 < 64; ++c4) {
    const float* eb = embT + (size_t)(c4 * 4) * 512 + t;  // [c][code] -> coalesced
    float e00 = eb[0], f00 = eb[256];
    float e01 = eb[512], f01 = eb[768];
    float e02 = eb[1024], f02 = eb[1280];
    float e03 = eb[1536], f03 = eb[1792];
#pragma unroll
    for (int j = 0; j < 16; ++j) {
      float4 zv = *(const float4*)&z[j][c4 * 4];
      d0[j] += zv.x * e00 + zv.y * e01 + zv.z * e02 + zv.w * e03;
      d1[j] += zv.x * f00 + zv.y * f01 + zv.z * f02 + zv.w * f03;
    }
  }
  float en0 = enorm[t], en1 = enorm[t + 256];
#pragma unroll
  for (int j = 0; j < 16; ++j) {
    sc[t * 16 + j] = en0 - 2.f * d0[j];
    sc[(t + 256) * 16 + j] = en1 - 2.f * d1[j];
  }
  __syncthreads();
  {
    int j = t & 15, chunk = t >> 4;
    float best = 3.4e38f;
    int bidx = 0;
    int c0 = chunk * 32;
    for (int cc = 0; cc < 32; ++cc) {
      float v = sc[(c0 + cc) * 16 + j];
      if (v < best) { best = v; bidx = c0 + cc; }
    }
    bv[chunk][j] = best;
    bi[chunk][j] = bidx;
  }
  __syncthreads();
  if (t < 16) {
    float best = 3.4e38f;
    int bidx = 0;
    for (int c = 0; c < 16; ++c) {
      float v = bv[c][t];
      if (v < best) { best = v; bidx = bi[c][t]; }
    }
    idxs[t] = bidx;
  }
  __syncthreads();
  float sq = 0.f, sqq = 0.f;
  for (int j = 0; j < 16; ++j) {
    float e = emb[(size_t)idxs[j] * 256 + t];
    q[(size_t)(T0 + j) * 256 + t] = e;
    float d = z[j][t] - e;
    sq += d * d;
    sqq += e * e;
  }
  __syncthreads();
  sc[t] = sq;
  __syncthreads();
  for (int k = 128; k > 0; k >>= 1) {
    if (t < k) sc[t] += sc[t + k];
    __syncthreads();
  }
  if (t == 0) atomicAdd(sse, sc[0]);
  __syncthreads();
  sc[t] = sqq;
  __syncthreads();
  for (int k = 128; k > 0; k >>= 1) {
    if (t < k) sc[t] += sc[t + k];
    __syncthreads();
  }
  if (t == 0) atomicAdd(&ssq4[blockIdx.x >> 2], sc[0]);
}

// ---------------- deconv2 + reconst loss (vectorized operand feeding) ------
// patch layout [pos=36][icg=8 x 36 (+4 pad/pos)]: pos-stride 292, group-stride
// 36 -> both b128 staging writes and b128 compute reads land 8 lanes per
// 4-bank group = conflict-free (old layout: 8-way write + read conflicts,
// 6.2M SQ_LDS_BANK_CONFLICT/dispatch). Weights from prep-transposed
// [py][px][ic][12]: 3x float4 per ic (L1-hot) instead of 384 scalar VMEM.
// Accumulation order (ic ascending, v00..v11 per ic) identical to original.
__global__ void __launch_bounds__(256) k_deconv2(const ushort_t* __restrict__ in,
                                                 const float* __restrict__ wT,
                                                 const float* __restrict__ bias,
                                                 const float* __restrict__ x,
                                                 float* __restrict__ dec,
                                                 float* __restrict__ sse) {
  __shared__ __align__(16) float patch[36 * 292];
  __shared__ float red[768];
  int blk = blockIdx.x;
  int oy = blk & 31, n = blk >> 5;
  int t = threadIdx.x;
  int py = (oy + 1) & 1;
  int dy = (oy + 1 - py) >> 1;
  // ---- staging: wave wv stages pos p = rep*4+wv; lane ln -> channels ln*4..+3
  {
    int wv = t >> 6, ln = t & 63;
    int icg = ln >> 3, ico = (ln & 7) * 4;
#pragma unroll
    for (int rep = 0; rep < 9; ++rep) {
      int p = rep * 4 + wv;
      int s = (p >= 18) ? 1 : 0;
      int col = p - s * 18;
      int iy = dy - 1 + s, ix = col - 1;
      f32x4 vv = {0.f, 0.f, 0.f, 0.f};
      if ((unsigned)iy < 16u && (unsigned)ix < 16u) {
        const ushort_t* src = in + (size_t)((n << 8) + iy * 16 + ix) * 256 + ln * 4;
        unsigned long long raw = *(const unsigned long long*)src;
        vv.x = bs2f((ushort_t)(raw));
        vv.y = bs2f((ushort_t)(raw >> 16));
        vv.z = bs2f((ushort_t)(raw >> 32));
        vv.w = bs2f((ushort_t)(raw >> 48));
      }
      *(f32x4*)(patch + p * 292 + icg * 36 + ico) = vv;
    }
  }
  __syncthreads();
  int ox = t & 31, g = t >> 5;
  int px = (ox + 1) & 1;
  int dx = (ox + 1 - px) >> 1;
  const float* wp = wT + (size_t)((py * 2 + px) * 256 + g * 32) * 12;
  const float* p00 = patch + dx * 292 + g * 36;
  const float* p01 = p00 + 292;
  const float* p10 = patch + (18 + dx) * 292 + g * 36;
  const float* p11 = p10 + 292;
  float a0 = 0.f, a1 = 0.f, a2 = 0.f;
#pragma unroll
  for (int u = 0; u < 8; ++u) {
    int ico = u * 4;
    f32x4 v00 = *(const f32x4*)(p00 + ico);
    f32x4 v01 = *(const f32x4*)(p01 + ico);
    f32x4 v10 = *(const f32x4*)(p10 + ico);
    f32x4 v11 = *(const f32x4*)(p11 + ico);
#pragma unroll
    for (int e = 0; e < 4; ++e) {
      const float* wq = wp + (size_t)(ico + e) * 12;
      f32x4 w0 = *(const f32x4*)(wq);
      f32x4 w1 = *(const f32x4*)(wq + 4);
      f32x4 w2 = *(const f32x4*)(wq + 8);
      float s00 = v00[e], s01 = v01[e], s10 = v10[e], s11 = v11[e];
      a0 += s00 * w0.x + s01 * w0.w + s10 * w1.z + s11 * w2.y;
      a1 += s00 * w0.y + s01 * w1.x + s10 * w1.w + s11 * w2.z;
      a2 += s00 * w0.z + s01 * w1.y + s10 * w2.x + s11 * w2.w;
    }
  }
  red[t * 3 + 0] = a0;
  red[t * 3 + 1] = a1;
  red[t * 3 + 2] = a2;
  __syncthreads();
  float sq = 0.f;
  if (t < 96) {
    int ox2 = t & 31, oc = t >> 5;
    float v = bias[oc];
#pragma unroll
    for (int g2 = 0; g2 < 8; ++g2) v += red[(g2 * 32 + ox2) * 3 + oc];
    int oi = ((n * 3 + oc) * 32 + oy) * 32 + ox2;
    dec[oi] = v;
    float d = v - x[oi];
    sq = d * d;
  }
  __syncthreads();
  red[t] = sq;
  __syncthreads();
  for (int k = 128; k > 0; k >>= 1) {
    if (t < k) red[t] += red[t + k];
    __syncthreads();
  }
  if (t == 0) atomicAdd(sse, red[0]);
}

__global__ void k_final(const float* __restrict__ acc, float* __restrict__ out) {
  if (threadIdx.x == 0 && blockIdx.x == 0) {
    float vq = acc[0] / 4194304.f;
    float rec = acc[1] / 786432.f;
    out[0] = rec + 2.f * vq;
    out[1] = rec;
    out[2] = vq;
    out[3] = vq;
  }
}

extern "C" void kernel_launch(void* const* d_in, const int* in_sizes, int n_in,
                              void* d_out, int out_size, void* d_ws, size_t ws_size,
                              hipStream_t stream) {
  (void)in_sizes; (void)n_in; (void)out_size; (void)ws_size;
  const float* x = (const float*)d_in[0];
  const float* ew1 = (const float*)d_in[1];
  const float* eb1 = (const float*)d_in[2];
  const float* ew2 = (const float*)d_in[3];
  const float* eb2 = (const float*)d_in[4];
  const float* rmsw = (const float*)d_in[5];
  const float* r3w = (const float*)d_in[6];
  const float* r3b = (const float*)d_in[7];
  const float* r1w = (const float*)d_in[8];
  const float* r1b = (const float*)d_in[9];
  const float* emb = (const float*)d_in[10];
  const float* dw1 = (const float*)d_in[11];
  const float* db1 = (const float*)d_in[12];
  const float* dw2 = (const float*)d_in[13];
  const float* db2 = (const float*)d_in[14];
  float* out = (float*)d_out;

  float* wsf = (float*)d_ws;
  float* P = wsf + OFF_P;
  float* enorm = wsf + OFF_ENORM;
  float* wTd2 = wsf + OFF_WTD2;
  float* acc = wsf + OFF_ACC;
  float* zrowf = wsf + OFF_ZROW;
  float* embT = wsf + OFF_EMBT;
  float* ssq = wsf + OFF_SSQ;
  ushort_t* sb = (ushort_t*)(wsf + OFF_SHORT);
  ushort_t* H1H = sb + SO_H1H;
  ushort_t* H1L = sb + SO_H1L;
  float* Qf = (float*)(sb + SO_H1L);
  ushort_t* NBH = sb + SO_NBH;
  ushort_t* NBL = sb + SO_NBL;
  ushort_t* A1H = NBH;
  ushort_t* A1L = NBL;
  ushort_t* QB = NBL;
  ushort_t* W1H = sb + SO_W1H;
  ushort_t* W1L = sb + SO_W1L;
  ushort_t* W2H = sb + SO_W2H;
  ushort_t* W2L = sb + SO_W2L;
  ushort_t* W3EH = sb + SO_W3EH;
  ushort_t* W3EL = sb + SO_W3EL;
  ushort_t* W3D = sb + SO_W3D;
  ushort_t* W1REH = sb + SO_W1REH;
  ushort_t* W1REL = sb + SO_W1REL;
  ushort_t* W1RD = sb + SO_W1RD;
  ushort_t* WD1 = sb + SO_WD1;
  const ushort_t* zrow = (const ushort_t*)zrowf;
  const size_t RMS_LDS = 64 * 257 * sizeof(float);

  k_prep<<<35443, 256, 0, stream>>>(x, ew1, ew2, r3w, r1w, dw1, dw2, emb,
                                    W1H, W1L, W2H, W2L, W3EH, W3EL, W3D,
                                    W1REH, W1REL, W1RD, WD1, wTd2, enorm, acc,
                                    zrowf, embT, ssq, A1H, A1L);

  // conv1 (split, K=64): M=65536 -> 1024 blocks
  k_gemm<0, 4, 1, 0><<<dim3(1024), 512, 0, stream>>>(
      A1H, A1L, W1H, W1L, 64, eb1, nullptr, nullptr, H1H, H1L, zrow, nullptr);
  // conv2 (split, K=4096) -> P, ssq slot 0
  k_gemm<1, 1, 1, 1><<<dim3(256), 512, 0, stream>>>(
      H1H, H1L, W2H, W2L, 4096, eb2, nullptr, P, nullptr, nullptr, zrow, ssq + 0);
  for (int rb = 0; rb < 2; ++rb) {
    k_rmsnorm<1><<<256, 256, RMS_LDS, stream>>>(
        P, rmsw + (size_t)(rb * 2 + 0) * 16384, ssq + (rb * 2 + 0) * 256, NBH, NBL);
    if (rb == 0)
      k_gemm<2, 2, 1, 1><<<dim3(256), 512, 0, stream>>>(
          NBH, NBL, W3EH, W3EL, 2304, r3b, P, Qf, nullptr, nullptr, zrow, ssq + 256);
    else
      k_gemm<2, 2, 1, 1><<<dim3(256), 512, 0, stream>>>(
          NBH, NBL, W3EH + 589824, W3EL + 589824, 2304, r3b + 256, P, Qf, nullptr,
          nullptr, zrow, ssq + 768);
    k_rmsnorm<1><<<256, 256, RMS_LDS, stream>>>(
        Qf, rmsw + (size_t)(rb * 2 + 1) * 16384, ssq + (rb * 2 + 1) * 256, NBH, NBL);
    if (rb == 0)
      k_gemm<0, 2, 1, 1><<<dim3(256), 512, 0, stream>>>(
          NBH, NBL, W1REH, W1REL, 256, r1b, Qf, P, nullptr, nullptr, zrow, ssq + 512);
    else
      k_gemm<0, 2, 1, 0><<<dim3(256), 512, 0, stream>>>(
          NBH, NBL, W1REH + 65536, W1REL + 65536, 256, r1b + 256, Qf, P, nullptr,
          nullptr, zrow, nullptr);
  }

  // VQ: P -> Qf (q), sse -> acc[0], q-ssq -> slot 4
  k_vq<<<1024, 256, 0, stream>>>(P, embT, emb, enorm, Qf, acc + 0, ssq + 1024);

  for (int rb = 2; rb < 4; ++rb) {
    k_rmsnorm<0><<<256, 256, RMS_LDS, stream>>>(
        Qf, rmsw + (size_t)(rb * 2 + 0) * 16384, ssq + (rb * 2 + 0) * 256, NBH, NBL);
    if (rb == 2)
      k_gemm<2, 2, 0, 1><<<dim3(256), 512, 0, stream>>>(
          NBH, nullptr, W3D, nullptr, 2304, r3b + 2 * 256, Qf, P, nullptr, nullptr,
          zrow, ssq + 1280);
    else
      k_gemm<2, 2, 0, 1><<<dim3(256), 512, 0, stream>>>(
          NBH, nullptr, W3D + 589824, nullptr, 2304, r3b + 3 * 256, Qf, P, nullptr,
          nullptr, zrow, ssq + 1792);
    k_rmsnorm<0><<<256, 256, RMS_LDS, stream>>>(
        P, rmsw + (size_t)(rb * 2 + 1) * 16384, ssq + (rb * 2 + 1) * 256, NBH, NBL);
    if (rb == 3) {
      k_gemm<0, 5, 0, 0><<<dim3(256), 512, 0, stream>>>(
          NBH, nullptr, W1RD + 65536, nullptr, 256, r1b + 3 * 256, P, Qf, QB, nullptr,
          zrow, nullptr);
    } else {
      k_gemm<0, 2, 0, 1><<<dim3(256), 512, 0, stream>>>(
          NBH, nullptr, W1RD, nullptr, 256, r1b + 2 * 256, P, Qf, nullptr, nullptr,
          zrow, ssq + 1536);
    }
  }

  // deconv1 (K=1024, 4 parity classes via z)
  k_gemm<3, 3, 0, 0><<<dim3(256, 1, 4), 512, 0, stream>>>(
      QB, nullptr, WD1, nullptr, 1024, db1, nullptr, nullptr, H1H, nullptr, zrow, nullptr);

  k_deconv2<<<8192, 256, 0, stream>>>(H1H, wTd2, db2, x, out + 4, acc + 1);
  k_final<<<1, 64, 0, stream>>>(acc, out);
}

// Round 9
// 931.267 us; speedup vs baseline: 1.2073x; 1.2073x over previous
//
#include <hip/hip_runtime.h>
#include <hip/hip_bf16.h>

typedef unsigned short ushort_t;
typedef __attribute__((ext_vector_type(8))) short short8v;
typedef __attribute__((ext_vector_type(4))) float f32x4;

__device__ __forceinline__ ushort_t f2bs(float v) {
  union { __hip_bfloat16 h; ushort_t u; } cv;
  cv.h = __float2bfloat16(v);
  return cv.u;
}
__device__ __forceinline__ float bs2f(ushort_t u) {
  union { ushort_t u; __hip_bfloat16 h; } cv;
  cv.u = u;
  return __bfloat162float(cv.h);
}

__device__ __forceinline__ void glds16(const ushort_t* g, ushort_t* l) {
  __builtin_amdgcn_global_load_lds(
      (const __attribute__((address_space(1))) unsigned int*)(uintptr_t)g,
      (__attribute__((address_space(3))) unsigned int*)(unsigned int)(uintptr_t)l,
      16, 0, 0);
}

// ---------------- workspace layout ----------------
static constexpr size_t OFF_P = 0;
static constexpr size_t OFF_ENORM = 4194304;
static constexpr size_t OFF_WD2 = 4194816;    // WD2H[12288]+WD2L[12288] ushorts
                                              // (49152 B, fits the 50176 B
                                              // freed wTd2 region — NO growth
                                              // past the original ws high-mark)
static constexpr size_t OFF_ACC = 4207360;
static constexpr size_t OFF_ZROW = 4207368;
static constexpr size_t OFF_EMBT = 4207432;   // fp32 embT [c=256][code=512]
static constexpr size_t OFF_SSQ = 4338504;    // 8 slots x 256 samples
static constexpr size_t OFF_SHORT = 4340552;  // 16B aligned (x4 bytes)
static constexpr size_t SO_H1H = 0;
static constexpr size_t SO_H1L = 16777216;
static constexpr size_t SO_NBH = 33554432;
static constexpr size_t SO_NBL = 37748736;
static constexpr size_t SO_W1H = 41943040;
static constexpr size_t SO_W1L = 41959424;
static constexpr size_t SO_W2H = 41975808;
static constexpr size_t SO_W2L = 43024384;
static constexpr size_t SO_W3EH = 44072960;
static constexpr size_t SO_W3EL = 45252608;
static constexpr size_t SO_W3D = 46432256;
static constexpr size_t SO_W1REH = 47611904;
static constexpr size_t SO_W1REL = 47742976;
static constexpr size_t SO_W1RD = 47874048;
static constexpr size_t SO_WD1 = 48005120;

__device__ __forceinline__ void split_store(float v, ushort_t* hi, ushort_t* lo, size_t i) {
  ushort_t h = f2bs(v);
  hi[i] = h;
  lo[i] = f2bs(v - bs2f(h));
}

// ---------------- fused prep ----------------
// ranges: [0,64) w1 | [64,4160) w2 | [4160,8768) w3e | [8768,13376) w3d
// [13376,13888) w1re | [13888,14400) w1rd | [14400,18496) wd1 | [18496,18544) wd2
// [18544,18546) enorm | 18546 zero | [18547,34931) conv1 im2col (16384 blocks EXACT)
// [34931,35443) embT
__global__ void __launch_bounds__(256) k_prep(
    const float* __restrict__ x, const float* __restrict__ ew1,
    const float* __restrict__ ew2, const float* __restrict__ r3w,
    const float* __restrict__ r1w, const float* __restrict__ dw1,
    const float* __restrict__ dw2, const float* __restrict__ emb,
    ushort_t* __restrict__ W1H, ushort_t* __restrict__ W1L,
    ushort_t* __restrict__ W2H, ushort_t* __restrict__ W2L,
    ushort_t* __restrict__ W3EH, ushort_t* __restrict__ W3EL,
    ushort_t* __restrict__ W3D, ushort_t* __restrict__ W1REH,
    ushort_t* __restrict__ W1REL, ushort_t* __restrict__ W1RD,
    ushort_t* __restrict__ WD1, ushort_t* __restrict__ WD2H,
    ushort_t* __restrict__ WD2L,
    float* __restrict__ enorm, float* __restrict__ acc, float* __restrict__ zrow,
    float* __restrict__ embT, float* __restrict__ ssq,
    ushort_t* __restrict__ A1H, ushort_t* __restrict__ A1L) {
  int b = blockIdx.x, t = threadIdx.x;
  if (b < 64) {
    int i = b * 256 + t;
    int oc = i >> 6, k = i & 63;
    float v = 0.f;
    if (k < 48) {
      int tap = k / 3, ic = k - 3 * tap;
      v = ew1[(oc * 3 + ic) * 16 + tap];
    }
    split_store(v, W1H, W1L, i);
  } else if (b < 4160) {
    int i = (b - 64) * 256 + t;
    int oc = i >> 12, k = i & 4095;
    int tap = k >> 8, ic = k & 255;
    split_store(ew2[(oc * 256 + ic) * 16 + tap], W2H, W2L, i);
  } else if (b < 8768) {
    int i = (b - 4160) * 256 + t;
    int rb = i / 589824, r2 = i - rb * 589824;
    int oc = r2 / 2304, k = r2 - oc * 2304;
    int r9 = k >> 8, ic = k & 255;
    split_store(r3w[((rb * 256 + oc) * 256 + ic) * 9 + r9], W3EH, W3EL, i);
  } else if (b < 13376) {
    int i = (b - 8768) * 256 + t;
    int rb = i / 589824, r2 = i - rb * 589824;
    int oc = r2 / 2304, k = r2 - oc * 2304;
    int r9 = k >> 8, ic = k & 255;
    W3D[i] = f2bs(r3w[(((rb + 2) * 256 + oc) * 256 + ic) * 9 + r9]);
  } else if (b < 13888) {
    int i = (b - 13376) * 256 + t;
    split_store(r1w[i], W1REH, W1REL, i);
  } else if (b < 14400) {
    int i = (b - 13888) * 256 + t;
    W1RD[i] = f2bs(r1w[2 * 65536 + i]);
  } else if (b < 18496) {
    int i = (b - 14400) * 256 + t;
    int cls = i >> 18, r2 = i & 262143;
    int oc = r2 >> 10, k = r2 & 1023;
    int tap = k >> 8, ic = k & 255;
    int s = tap >> 1, sx = tap & 1;
    int py = cls >> 1, px = cls & 1;
    int ky = py + 2 - 2 * s, kx = px + 2 - 2 * sx;
    WD1[i] = f2bs(dw1[(ic * 256 + oc) * 16 + ky * 4 + kx]);
  } else if (b < 18544) {
    // dec2 weights as GEMM-B: row j = (ky*4+kx)*3+oc (48 rows), K = ic,
    // split hi/lo bf16 for fp32-accuracy weights
    int i = (b - 18496) * 256 + t;  // [0, 12288)
    int j = i >> 8, ic = i & 255;
    int kyx = j / 3, oc = j - kyx * 3;
    split_store(dw2[(ic * 3 + oc) * 16 + kyx], WD2H, WD2L, (size_t)j * 256 + ic);
  } else if (b < 18546) {
    int e = (b - 18544) * 256 + t;
    float s = 0.f;
    for (int c = 0; c < 256; ++c) {
      float v = emb[e * 256 + c];
      s += v * v;
    }
    enorm[e] = s;
  } else if (b == 18546) {
    if (t < 2) acc[t] = 0.f;
    if (t < 64) zrow[t] = 0.f;
    for (int k = t; k < 2048; k += 256) ssq[k] = 0.f;
  } else if (b < 34931) {  // conv1 im2col: exactly 16384 blocks
    int i = (b - 18547) * 256 + t;
    int t1 = i >> 6, k = i & 63;
    float v = 0.f;
    if (k < 48) {
      int tap = k / 3, ic = k - 3 * tap;
      int n = t1 >> 8, oy = (t1 >> 4) & 15, ox = t1 & 15;
      int ky = tap >> 2, kx = tap & 3;
      int iy = 2 * oy - 1 + ky, ix = 2 * ox - 1 + kx;
      if ((unsigned)iy < 32u && (unsigned)ix < 32u)
        v = x[((n * 3 + ic) * 32 + iy) * 32 + ix];
    }
    split_store(v, A1H, A1L, i);
  } else {  // [34931, 35443): embT [c][code] fp32
    int i = (b - 34931) * 256 + t;
    int code = i >> 8, c = i & 255;
    embT[c * 512 + code] = emb[i];
  }
}

// ---------------- MFMA GEMM (full-width BN=256, BM=64, 8 waves, PIPE=3) ----
// Each block owns ALL 256 output channels for 64 rows -> A is staged exactly
// ONCE. All blocks read the SAME 32 KB B-slice per K-step -> B staging is
// L2-hit traffic. Counted-vmcnt depth-3 pipeline, vmcnt(5).
template <int MODE, int EPI, int STYLE, int SSQ>
__global__ __launch_bounds__(512) void k_gemm(const ushort_t* __restrict__ Ah,
                                              const ushort_t* __restrict__ Al,
                                              const ushort_t* __restrict__ Bh,
                                              const ushort_t* __restrict__ Bl, int K,
                                              const float* __restrict__ bias,
                                              const float* __restrict__ res,
                                              float* __restrict__ outf,
                                              ushort_t* __restrict__ outb,
                                              ushort_t* __restrict__ outb2,
                                              const ushort_t* __restrict__ zrow,
                                              float* __restrict__ ssqp) {
  constexpr int PIPE = 3;
  __shared__ __align__(16) ushort_t A0[PIPE][64 * 32];
  __shared__ __align__(16) ushort_t A1s[PIPE][64 * 32];
  __shared__ __align__(16) ushort_t B0[PIPE][256 * 32];
  __shared__ __align__(16) ushort_t B1[PIPE][256 * 32];
  const int t = threadIdx.x;
  const int w = t >> 6, l = t & 63;
  const int M0 = blockIdx.x * 64;
  int py = 0, px = 0;
  const ushort_t* Bb = Bh;
  if (MODE == 3) {
    int cls = blockIdx.z;
    py = cls >> 1;
    px = cls & 1;
    Bb = Bh + (size_t)cls * 262144;
  }
  const int srow = l & 15, chunk = l >> 4;
  const int fr = l & 15, quad = l >> 4;
  const int m_off = (w & 1) * 32, n_off = (w >> 1) * 64;
  const int mset = (m_off >> 4), nset = (n_off >> 4);

  // staging assignment
  const int aw = w & 3;              // A 16-row group this wave stages
  const bool aH = (w < 4);           // stage A-H (else A-L / A-hi-k)
  const int atok = M0 + aw * 16 + srow;
  const size_t bb0 = (size_t)(2 * w * 16 + srow) * K + chunk * 8;
  const size_t bb1 = (size_t)((2 * w + 1) * 16 + srow) * K + chunk * 8;

  f32x4 acc[2][4];
#pragma unroll
  for (int i = 0; i < 2; ++i)
#pragma unroll
    for (int j = 0; j < 4; ++j) acc[i][j] = (f32x4){0.f, 0.f, 0.f, 0.f};

  const int n1 = atok >> 6, oy1 = (atok >> 3) & 7, ox1 = atok & 7;
  const ushort_t* zp = zrow + chunk * 8;

  const int SUB = (STYLE == 1) ? 32 : 64;

  // persistent per-tap staging state (recomputed when (kk&255)==0)
  size_t r1s = 0;
  bool v1s = true;
  if (MODE == 0) r1s = (size_t)atok * K + chunk * 8;

  auto stage = [&](int kk, int s) {
    const ushort_t* pa;
    if (MODE == 0) {
      size_t o = r1s + kk;
      pa = aH ? (Ah + o) : ((STYLE == 1) ? (Al + o) : (Ah + o + 32));
    } else {
      if ((kk & 255) == 0) {
        int tap = kk >> 8;
        int iy, ix;
        unsigned lim;
        if (MODE == 1) {
          int ky = tap >> 2, kx = tap & 3;
          iy = 2 * oy1 - 1 + ky; ix = 2 * ox1 - 1 + kx;
          lim = 16u;
        } else if (MODE == 2) {
          int ky = tap / 3, kx = tap - ky * 3;
          iy = oy1 - 1 + ky; ix = ox1 - 1 + kx;
          lim = 8u;
        } else {
          int s2 = tap >> 1, sx = tap & 1;
          iy = oy1 + s2 - py; ix = ox1 + sx - px;
          lim = 8u;
        }
        v1s = ((unsigned)iy < lim && (unsigned)ix < lim);
        if (MODE == 1)
          r1s = (size_t)(((n1 << 8) + (iy << 4) + ix)) << 8;
        else
          r1s = (size_t)(((n1 << 6) + (iy << 3) + ix)) << 8;
      }
      int kin = (kk & 255) + chunk * 8;
      if (v1s)
        pa = aH ? (Ah + r1s + kin)
                : ((STYLE == 1) ? (Al + r1s + kin) : (Ah + r1s + kin + 32));
      else
        pa = zp;
    }
    size_t bo0 = bb0 + kk, bo1 = bb1 + kk;
    glds16(pa, (aH ? A0[s] : A1s[s]) + aw * 512);
    glds16(Bb + bo0, B0[s] + (2 * w) * 512);
    glds16(Bb + bo1, B0[s] + (2 * w + 1) * 512);
    glds16((STYLE == 1) ? (Bl + bo0) : (Bb + bo0 + 32), B1[s] + (2 * w) * 512);
    glds16((STYLE == 1) ? (Bl + bo1) : (Bb + bo1 + 32), B1[s] + (2 * w + 1) * 512);
  };

  auto compute = [&](int s) {
    short8v af0[2], af1[2], bf0[4], bf1[4];
#pragma unroll
    for (int mi = 0; mi < 2; ++mi) {
      af0[mi] = *(const short8v*)(A0[s] + (mset + mi) * 512 + quad * 128 + fr * 8);
      af1[mi] = *(const short8v*)(A1s[s] + (mset + mi) * 512 + quad * 128 + fr * 8);
    }
#pragma unroll
    for (int nj = 0; nj < 4; ++nj) {
      bf0[nj] = *(const short8v*)(B0[s] + (nset + nj) * 512 + quad * 128 + fr * 8);
      bf1[nj] = *(const short8v*)(B1[s] + (nset + nj) * 512 + quad * 128 + fr * 8);
    }
#pragma unroll
    for (int mi = 0; mi < 2; ++mi)
#pragma unroll
      for (int nj = 0; nj < 4; ++nj) {
        acc[mi][nj] =
            __builtin_amdgcn_mfma_f32_16x16x32_bf16(af0[mi], bf0[nj], acc[mi][nj], 0, 0, 0);
        if (STYLE == 1) {
          acc[mi][nj] =
              __builtin_amdgcn_mfma_f32_16x16x32_bf16(af1[mi], bf0[nj], acc[mi][nj], 0, 0, 0);
          acc[mi][nj] =
              __builtin_amdgcn_mfma_f32_16x16x32_bf16(af0[mi], bf1[nj], acc[mi][nj], 0, 0, 0);
        } else {
          acc[mi][nj] =
              __builtin_amdgcn_mfma_f32_16x16x32_bf16(af1[mi], bf1[nj], acc[mi][nj], 0, 0, 0);
        }
      }
  };

  // ---- counted-vmcnt pipeline (per-wave: 5 loads/step; <=10 in flight) ----
  {
    const int nt = K / SUB;
    stage(0, 0);
    int ns = 1;
    if (nt > 1) {
      stage(SUB, 1);
      ns = 2;
    }
    int cb = 0, sb2 = ns % PIPE;
    for (int tt = 0; tt < nt; ++tt) {
      if (ns > tt + 1) {
        asm volatile("s_waitcnt vmcnt(5)" ::: "memory");
      } else {
        asm volatile("s_waitcnt vmcnt(0)" ::: "memory");
      }
      asm volatile("s_barrier" ::: "memory");
      if (ns < nt) {
        stage(ns * SUB, sb2);
        ++ns;
        sb2 = (sb2 + 1 == PIPE) ? 0 : sb2 + 1;
      }
      compute(cb);
      cb = (cb + 1 == PIPE) ? 0 : cb + 1;
    }
  }

  float sq = 0.f;
#pragma unroll
  for (int mi = 0; mi < 2; ++mi) {
    int mrow = m_off + mi * 16 + quad * 4;
#pragma unroll
    for (int nj = 0; nj < 4; ++nj) {
      int col = n_off + nj * 16 + fr;
      float bv = bias[col];
#pragma unroll
      for (int i = 0; i < 4; ++i) {
        int m = M0 + mrow + i;
        float v = fmaxf(acc[mi][nj][i] + bv, 0.f);
        if (EPI == 1) {
          outf[(size_t)m * 256 + col] = v;
          if (SSQ) sq += v * v;
        } else if (EPI == 2) {
          size_t o = (size_t)m * 256 + col;
          float vv = res[o] + v;
          outf[o] = vv;
          if (SSQ) sq += vv * vv;
        } else if (EPI == 3) {
          int nn = m >> 6, jj = (m >> 3) & 7, ii = m & 7;
          int oy = 2 * jj + 1 - py, ox = 2 * ii + 1 - px;
          outb[(size_t)((nn << 8) + oy * 16 + ox) * 256 + col] = f2bs(v);
        } else if (EPI == 4) {
          size_t o = (size_t)m * 256 + col;
          ushort_t h = f2bs(v);
          outb[o] = h;
          outb2[o] = f2bs(v - bs2f(h));
        } else {  // EPI 5
          size_t o = (size_t)m * 256 + col;
          float vv = res[o] + v;
          outf[o] = vv;
          outb[o] = f2bs(vv);
        }
      }
    }
  }
  if (SSQ) {
#pragma unroll
    for (int off = 32; off > 0; off >>= 1) sq += __shfl_down(sq, off, 64);
    if (l == 0) atomicAdd(&ssqp[M0 >> 6], sq);
  }
}

// ---------------- rmsnorm normalize-only (scale from fused SSQ table) ----------
template <int SPLIT>
__global__ void __launch_bounds__(256) k_rmsnorm(const float* __restrict__ in,
                                                 const float* __restrict__ rmsw,
                                                 const float* __restrict__ ssq,
                                                 ushort_t* __restrict__ NBh,
                                                 ushort_t* __restrict__ NBl) {
  extern __shared__ float wT[];  // 64*257 floats
  int n = blockIdx.x, t = threadIdx.x;
  const float* p = in + (size_t)n * 16384;
  for (int k = 0; k < 64; ++k) {
    int i = k * 256 + t;  // i = c*64 + j
    wT[(i & 63) * 257 + (i >> 6)] = rmsw[i];
  }
  float scale = 1.0f / sqrtf(ssq[n] / 16384.f + 1.1920929e-07f);
  __syncthreads();
  ushort_t* oh = NBh + (size_t)n * 16384;
  ushort_t* ol = NBl + (size_t)n * 16384;
  for (int j = 0; j < 64; ++j) {
    int i = j * 256 + t;
    float v = p[i] * scale * wT[j * 257 + t];
    ushort_t h = f2bs(v);
    oh[i] = h;
    if (SPLIT) ol[i] = f2bs(v - bs2f(h));
  }
}

// ---------------- VQ (coalesced embT scores; fused q-SSQ) ----------------
__global__ void __launch_bounds__(256) k_vq(const float* __restrict__ enc,
                                            const float* __restrict__ embT,
                                            const float* __restrict__ emb,
                                            const float* __restrict__ enorm,
                                            float* __restrict__ q, float* __restrict__ sse,
                                            float* __restrict__ ssq4) {
  __shared__ float z[16][256];
  __shared__ float sc[512 * 16];
  __shared__ float bv[16][16];
  __shared__ int bi[16][16];
  __shared__ int idxs[16];
  int T0 = blockIdx.x * 16;
  int t = threadIdx.x;
  for (int j = 0; j < 16; ++j) z[j][t] = enc[(size_t)(T0 + j) * 256 + t];
  __syncthreads();
  float d0[16], d1[16];
#pragma unroll
  for (int j = 0; j < 16; ++j) { d0[j] = 0.f; d1[j] = 0.f; }
  for (int c4 = 0; c4 < 64; ++c4) {
    const float* eb = embT + (size_t)(c4 * 4) * 512 + t;  // [c][code] -> coalesced
    float e00 = eb[0], f00 = eb[256];
    float e01 = eb[512], f01 = eb[768];
    float e02 = eb[1024], f02 = eb[1280];
    float e03 = eb[1536], f03 = eb[1792];
#pragma unroll
    for (int j = 0; j < 16; ++j) {
      float4 zv = *(const float4*)&z[j][c4 * 4];
      d0[j] += zv.x * e00 + zv.y * e01 + zv.z * e02 + zv.w * e03;
      d1[j] += zv.x * f00 + zv.y * f01 + zv.z * f02 + zv.w * f03;
    }
  }
  float en0 = enorm[t], en1 = enorm[t + 256];
#pragma unroll
  for (int j = 0; j < 16; ++j) {
    sc[t * 16 + j] = en0 - 2.f * d0[j];
    sc[(t + 256) * 16 + j] = en1 - 2.f * d1[j];
  }
  __syncthreads();
  {
    int j = t & 15, chunk = t >> 4;
    float best = 3.4e38f;
    int bidx = 0;
    int c0 = chunk * 32;
    for (int cc = 0; cc < 32; ++cc) {
      float v = sc[(c0 + cc) * 16 + j];
      if (v < best) { best = v; bidx = c0 + cc; }
    }
    bv[chunk][j] = best;
    bi[chunk][j] = bidx;
  }
  __syncthreads();
  if (t < 16) {
    float best = 3.4e38f;
    int bidx = 0;
    for (int c = 0; c < 16; ++c) {
      float v = bv[c][t];
      if (v < best) { best = v; bidx = bi[c][t]; }
    }
    idxs[t] = bidx;
  }
  __syncthreads();
  float sq = 0.f, sqq = 0.f;
  for (int j = 0; j < 16; ++j) {
    float e = emb[(size_t)idxs[j] * 256 + t];
    q[(size_t)(T0 + j) * 256 + t] = e;
    float d = z[j][t] - e;
    sq += d * d;
    sqq += e * e;
  }
  __syncthreads();
  sc[t] = sq;
  __syncthreads();
  for (int k = 128; k > 0; k >>= 1) {
    if (t < k) sc[t] += sc[t + k];
    __syncthreads();
  }
  if (t == 0) atomicAdd(sse, sc[0]);
  __syncthreads();
  sc[t] = sqq;
  __syncthreads();
  for (int k = 128; k > 0; k >>= 1) {
    if (t < k) sc[t] += sc[t + k];
    __syncthreads();
  }
  if (t == 0) atomicAdd(&ssq4[blockIdx.x >> 2], sc[0]);
}

// ---------------- deconv2 as GEMM: G[token][48] = in . W ----------------
// M=65536 tokens, N=48 (16 taps x 3 oc), K=256. B (48x256 bf16 H+L, 48KB)
// staged ONCE into LDS; A fragments loaded direct from global (wave-exclusive
// rows, 8-step fully-unrolled K-loop, no barriers -> compiler pipelines the
// 16 independent loads). MFMA: af.(bh+bl) for fp32-accuracy weights.
__global__ void __launch_bounds__(256) k_dec2gemm(const ushort_t* __restrict__ A,
                                                  const ushort_t* __restrict__ BH,
                                                  const ushort_t* __restrict__ BL,
                                                  float* __restrict__ G) {
  __shared__ __align__(16) ushort_t sBH[48 * 256];
  __shared__ __align__(16) ushort_t sBL[48 * 256];
  const int t = threadIdx.x;
  const int w = t >> 6, l = t & 63;
  const int fr = l & 15, quad = l >> 4, quad8 = quad * 8;
  for (int i = t * 8; i < 12288; i += 2048) {
    *(short8v*)(sBH + i) = *(const short8v*)(BH + i);
    *(short8v*)(sBL + i) = *(const short8v*)(BL + i);
  }
  __syncthreads();
  const int tok0 = blockIdx.x * 128 + w * 32;
  f32x4 acc[2][3];
#pragma unroll
  for (int i = 0; i < 2; ++i)
#pragma unroll
    for (int j = 0; j < 3; ++j) acc[i][j] = (f32x4){0.f, 0.f, 0.f, 0.f};
#pragma unroll
  for (int kk = 0; kk < 256; kk += 32) {
    short8v af[2];
#pragma unroll
    for (int mi = 0; mi < 2; ++mi)
      af[mi] = *(const short8v*)(A + (size_t)(tok0 + mi * 16 + fr) * 256 + kk + quad8);
#pragma unroll
    for (int nj = 0; nj < 3; ++nj) {
      short8v bh = *(const short8v*)(sBH + (nj * 16 + fr) * 256 + kk + quad8);
      short8v bl = *(const short8v*)(sBL + (nj * 16 + fr) * 256 + kk + quad8);
#pragma unroll
      for (int mi = 0; mi < 2; ++mi) {
        acc[mi][nj] =
            __builtin_amdgcn_mfma_f32_16x16x32_bf16(af[mi], bh, acc[mi][nj], 0, 0, 0);
        acc[mi][nj] =
            __builtin_amdgcn_mfma_f32_16x16x32_bf16(af[mi], bl, acc[mi][nj], 0, 0, 0);
      }
    }
  }
#pragma unroll
  for (int mi = 0; mi < 2; ++mi) {
    int mrow = mi * 16 + quad * 4;
#pragma unroll
    for (int nj = 0; nj < 3; ++nj) {
      int col = nj * 16 + fr;
#pragma unroll
      for (int i = 0; i < 4; ++i)
        G[(size_t)(tok0 + mrow + i) * 64 + col] = acc[mi][nj][i];
    }
  }
}

// ---------------- deconv2 gather + reconst loss ----------------
// out(n,oy,ox,oc) = bias[oc] + sum over <=4 valid taps of
//   G[token(n,iy,ix)][(ky*4+kx)*3+oc]   (exact mapping of the original
// patch/weight indexing: v00<->tap(py+2,px+2) at (dy-1,dx-1), v01<->(py+2,px)
// at (dy-1,dx), v10<->(py,px+2) at (dy,dx-1), v11<->(py,px) at (dy,dx)).
// One block per image: stage the 256x48 G-slab into LDS (stride 49), gather.
__global__ void __launch_bounds__(256) k_dec2gather(const float* __restrict__ G,
                                                    const float* __restrict__ bias,
                                                    const float* __restrict__ x,
                                                    float* __restrict__ dec,
                                                    float* __restrict__ sse) {
  __shared__ float GL[256 * 49];
  __shared__ float red[256];
  int n = blockIdx.x, t = threadIdx.x;
  for (int i = t; i < 12288; i += 256) {
    int r = i / 48, c = i - r * 48;
    GL[r * 49 + c] = G[(size_t)((n << 8) + r) * 64 + c];
  }
  __syncthreads();
  float sq = 0.f;
  for (int rep = 0; rep < 12; ++rep) {
    int o = rep * 256 + t;
    int oc = o >> 10, rem = o & 1023;
    int oy = rem >> 5, ox = rem & 31;
    int py = (oy + 1) & 1, dy = (oy + 1 - py) >> 1;
    int px = (ox + 1) & 1, dx = (ox + 1 - px) >> 1;
    int iy0 = dy - 1, ix0 = dx - 1;
    bool y0 = (unsigned)iy0 < 16u, y1 = (unsigned)dy < 16u;
    bool x0 = (unsigned)ix0 < 16u, x1 = (unsigned)dx < 16u;
    float v = bias[oc];
    if (y0 && x0) v += GL[(iy0 * 16 + ix0) * 49 + ((py + 2) * 4 + px + 2) * 3 + oc];
    if (y0 && x1) v += GL[(iy0 * 16 + dx) * 49 + ((py + 2) * 4 + px) * 3 + oc];
    if (y1 && x0) v += GL[(dy * 16 + ix0) * 49 + (py * 4 + px + 2) * 3 + oc];
    if (y1 && x1) v += GL[(dy * 16 + dx) * 49 + (py * 4 + px) * 3 + oc];
    int oi = ((n * 3 + oc) * 32 + oy) * 32 + ox;
    dec[oi] = v;
    float d = v - x[oi];
    sq += d * d;
  }
  red[t] = sq;
  __syncthreads();
  for (int k = 128; k > 0; k >>= 1) {
    if (t < k) red[t] += red[t + k];
    __syncthreads();
  }
  if (t == 0) atomicAdd(sse, red[0]);
}

__global__ void k_final(const float* __restrict__ acc, float* __restrict__ out) {
  if (threadIdx.x == 0 && blockIdx.x == 0) {
    float vq = acc[0] / 4194304.f;
    float rec = acc[1] / 786432.f;
    out[0] = rec + 2.f * vq;
    out[1] = rec;
    out[2] = vq;
    out[3] = vq;
  }
}

extern "C" void kernel_launch(void* const* d_in, const int* in_sizes, int n_in,
                              void* d_out, int out_size, void* d_ws, size_t ws_size,
                              hipStream_t stream) {
  (void)in_sizes; (void)n_in; (void)out_size; (void)ws_size;
  const float* x = (const float*)d_in[0];
  const float* ew1 = (const float*)d_in[1];
  const float* eb1 = (const float*)d_in[2];
  const float* ew2 = (const float*)d_in[3];
  const float* eb2 = (const float*)d_in[4];
  const float* rmsw = (const float*)d_in[5];
  const float* r3w = (const float*)d_in[6];
  const float* r3b = (const float*)d_in[7];
  const float* r1w = (const float*)d_in[8];
  const float* r1b = (const float*)d_in[9];
  const float* emb = (const float*)d_in[10];
  const float* dw1 = (const float*)d_in[11];
  const float* db1 = (const float*)d_in[12];
  const float* dw2 = (const float*)d_in[13];
  const float* db2 = (const float*)d_in[14];
  float* out = (float*)d_out;

  float* wsf = (float*)d_ws;
  float* P = wsf + OFF_P;
  float* enorm = wsf + OFF_ENORM;
  float* acc = wsf + OFF_ACC;
  float* zrowf = wsf + OFF_ZROW;
  float* embT = wsf + OFF_EMBT;
  float* ssq = wsf + OFF_SSQ;
  ushort_t* WD2H = (ushort_t*)(wsf + OFF_WD2);
  ushort_t* WD2L = WD2H + 12288;
  ushort_t* sb = (ushort_t*)(wsf + OFF_SHORT);
  ushort_t* H1H = sb + SO_H1H;
  ushort_t* H1L = sb + SO_H1L;
  float* Qf = (float*)(sb + SO_H1L);
  ushort_t* NBH = sb + SO_NBH;
  ushort_t* NBL = sb + SO_NBL;
  ushort_t* A1H = NBH;
  ushort_t* A1L = NBL;
  ushort_t* QB = NBL;
  ushort_t* W1H = sb + SO_W1H;
  ushort_t* W1L = sb + SO_W1L;
  ushort_t* W2H = sb + SO_W2H;
  ushort_t* W2L = sb + SO_W2L;
  ushort_t* W3EH = sb + SO_W3EH;
  ushort_t* W3EL = sb + SO_W3EL;
  ushort_t* W3D = sb + SO_W3D;
  ushort_t* W1REH = sb + SO_W1REH;
  ushort_t* W1REL = sb + SO_W1REL;
  ushort_t* W1RD = sb + SO_W1RD;
  ushort_t* WD1 = sb + SO_WD1;
  const ushort_t* zrow = (const ushort_t*)zrowf;
  const size_t RMS_LDS = 64 * 257 * sizeof(float);

  k_prep<<<35443, 256, 0, stream>>>(x, ew1, ew2, r3w, r1w, dw1, dw2, emb,
                                    W1H, W1L, W2H, W2L, W3EH, W3EL, W3D,
                                    W1REH, W1REL, W1RD, WD1, WD2H, WD2L, enorm,
                                    acc, zrowf, embT, ssq, A1H, A1L);

  // conv1 (split, K=64): M=65536 -> 1024 blocks
  k_gemm<0, 4, 1, 0><<<dim3(1024), 512, 0, stream>>>(
      A1H, A1L, W1H, W1L, 64, eb1, nullptr, nullptr, H1H, H1L, zrow, nullptr);
  // conv2 (split, K=4096) -> P, ssq slot 0
  k_gemm<1, 1, 1, 1><<<dim3(256), 512, 0, stream>>>(
      H1H, H1L, W2H, W2L, 4096, eb2, nullptr, P, nullptr, nullptr, zrow, ssq + 0);
  for (int rb = 0; rb < 2; ++rb) {
    k_rmsnorm<1><<<256, 256, RMS_LDS, stream>>>(
        P, rmsw + (size_t)(rb * 2 + 0) * 16384, ssq + (rb * 2 + 0) * 256, NBH, NBL);
    if (rb == 0)
      k_gemm<2, 2, 1, 1><<<dim3(256), 512, 0, stream>>>(
          NBH, NBL, W3EH, W3EL, 2304, r3b, P, Qf, nullptr, nullptr, zrow, ssq + 256);
    else
      k_gemm<2, 2, 1, 1><<<dim3(256), 512, 0, stream>>>(
          NBH, NBL, W3EH + 589824, W3EL + 589824, 2304, r3b + 256, P, Qf, nullptr,
          nullptr, zrow, ssq + 768);
    k_rmsnorm<1><<<256, 256, RMS_LDS, stream>>>(
        Qf, rmsw + (size_t)(rb * 2 + 1) * 16384, ssq + (rb * 2 + 1) * 256, NBH, NBL);
    if (rb == 0)
      k_gemm<0, 2, 1, 1><<<dim3(256), 512, 0, stream>>>(
          NBH, NBL, W1REH, W1REL, 256, r1b, Qf, P, nullptr, nullptr, zrow, ssq + 512);
    else
      k_gemm<0, 2, 1, 0><<<dim3(256), 512, 0, stream>>>(
          NBH, NBL, W1REH + 65536, W1REL + 65536, 256, r1b + 256, Qf, P, nullptr,
          nullptr, zrow, nullptr);
  }

  // VQ: P -> Qf (q), sse -> acc[0], q-ssq -> slot 4
  k_vq<<<1024, 256, 0, stream>>>(P, embT, emb, enorm, Qf, acc + 0, ssq + 1024);

  for (int rb = 2; rb < 4; ++rb) {
    k_rmsnorm<0><<<256, 256, RMS_LDS, stream>>>(
        Qf, rmsw + (size_t)(rb * 2 + 0) * 16384, ssq + (rb * 2 + 0) * 256, NBH, NBL);
    if (rb == 2)
      k_gemm<2, 2, 0, 1><<<dim3(256), 512, 0, stream>>>(
          NBH, nullptr, W3D, nullptr, 2304, r3b + 2 * 256, Qf, P, nullptr, nullptr,
          zrow, ssq + 1280);
    else
      k_gemm<2, 2, 0, 1><<<dim3(256), 512, 0, stream>>>(
          NBH, nullptr, W3D + 589824, nullptr, 2304, r3b + 3 * 256, Qf, P, nullptr,
          nullptr, zrow, ssq + 1792);
    k_rmsnorm<0><<<256, 256, RMS_LDS, stream>>>(
        P, rmsw + (size_t)(rb * 2 + 1) * 16384, ssq + (rb * 2 + 1) * 256, NBH, NBL);
    if (rb == 3) {
      k_gemm<0, 5, 0, 0><<<dim3(256), 512, 0, stream>>>(
          NBH, nullptr, W1RD + 65536, nullptr, 256, r1b + 3 * 256, P, Qf, QB, nullptr,
          zrow, nullptr);
    } else {
      k_gemm<0, 2, 0, 1><<<dim3(256), 512, 0, stream>>>(
          NBH, nullptr, W1RD, nullptr, 256, r1b + 2 * 256, P, Qf, nullptr, nullptr,
          zrow, ssq + 1536);
    }
  }

  // deconv1 (K=1024, 4 parity classes via z)
  k_gemm<3, 3, 0, 0><<<dim3(256, 1, 4), 512, 0, stream>>>(
      QB, nullptr, WD1, nullptr, 1024, db1, nullptr, nullptr, H1H, nullptr, zrow, nullptr);

  // deconv2: GEMM (G = tokens x W, 48 cols) + gather/loss. G lives in P.
  k_dec2gemm<<<512, 256, 0, stream>>>(H1H, WD2H, WD2L, P);
  k_dec2gather<<<256, 256, 0, stream>>>(P, db2, x, out + 4, acc + 1);
  k_final<<<1, 64, 0, stream>>>(acc, out);
}

// Round 10
// 831.662 us; speedup vs baseline: 1.3519x; 1.1198x over previous
//
#include <hip/hip_runtime.h>
#include <hip/hip_bf16.h>

typedef unsigned short ushort_t;
typedef __attribute__((ext_vector_type(8))) short short8v;
typedef __attribute__((ext_vector_type(4))) float f32x4;

__device__ __forceinline__ ushort_t f2bs(float v) {
  union { __hip_bfloat16 h; ushort_t u; } cv;
  cv.h = __float2bfloat16(v);
  return cv.u;
}
__device__ __forceinline__ float bs2f(ushort_t u) {
  union { ushort_t u; __hip_bfloat16 h; } cv;
  cv.u = u;
  return __bfloat162float(cv.h);
}

__device__ __forceinline__ void glds16(const ushort_t* g, ushort_t* l) {
  __builtin_amdgcn_global_load_lds(
      (const __attribute__((address_space(1))) unsigned int*)(uintptr_t)g,
      (__attribute__((address_space(3))) unsigned int*)(unsigned int)(uintptr_t)l,
      16, 0, 0);
}

// ---------------- workspace layout ----------------
static constexpr size_t OFF_P = 0;
static constexpr size_t OFF_ENORM = 4194304;
static constexpr size_t OFF_WD2 = 4194816;    // WD2H[12288]+WD2L[12288] ushorts
static constexpr size_t OFF_ACC = 4207360;
static constexpr size_t OFF_ZROW = 4207368;
static constexpr size_t OFF_EMBT = 4207432;   // fp32 embT [c=256][code=512]
static constexpr size_t OFF_SSQ = 4338504;    // 8 slots x 256 samples
static constexpr size_t OFF_SHORT = 4340552;  // 16B aligned (x4 bytes)
static constexpr size_t SO_H1H = 0;
static constexpr size_t SO_H1L = 16777216;
static constexpr size_t SO_NBH = 33554432;
static constexpr size_t SO_NBL = 37748736;
static constexpr size_t SO_W1H = 41943040;
static constexpr size_t SO_W1L = 41959424;
static constexpr size_t SO_W2H = 41975808;
static constexpr size_t SO_W2L = 43024384;
static constexpr size_t SO_W3EH = 44072960;
static constexpr size_t SO_W3EL = 45252608;
static constexpr size_t SO_W3D = 46432256;
static constexpr size_t SO_W1REH = 47611904;
static constexpr size_t SO_W1REL = 47742976;
static constexpr size_t SO_W1RD = 47874048;
static constexpr size_t SO_WD1 = 48005120;

__device__ __forceinline__ void split_store(float v, ushort_t* hi, ushort_t* lo, size_t i) {
  ushort_t h = f2bs(v);
  hi[i] = h;
  lo[i] = f2bs(v - bs2f(h));
}

// ---------------- fused prep (unchanged from r9) ----------------
__global__ void __launch_bounds__(256) k_prep(
    const float* __restrict__ x, const float* __restrict__ ew1,
    const float* __restrict__ ew2, const float* __restrict__ r3w,
    const float* __restrict__ r1w, const float* __restrict__ dw1,
    const float* __restrict__ dw2, const float* __restrict__ emb,
    ushort_t* __restrict__ W1H, ushort_t* __restrict__ W1L,
    ushort_t* __restrict__ W2H, ushort_t* __restrict__ W2L,
    ushort_t* __restrict__ W3EH, ushort_t* __restrict__ W3EL,
    ushort_t* __restrict__ W3D, ushort_t* __restrict__ W1REH,
    ushort_t* __restrict__ W1REL, ushort_t* __restrict__ W1RD,
    ushort_t* __restrict__ WD1, ushort_t* __restrict__ WD2H,
    ushort_t* __restrict__ WD2L,
    float* __restrict__ enorm, float* __restrict__ acc, float* __restrict__ zrow,
    float* __restrict__ embT, float* __restrict__ ssq,
    ushort_t* __restrict__ A1H, ushort_t* __restrict__ A1L) {
  int b = blockIdx.x, t = threadIdx.x;
  if (b < 64) {
    int i = b * 256 + t;
    int oc = i >> 6, k = i & 63;
    float v = 0.f;
    if (k < 48) {
      int tap = k / 3, ic = k - 3 * tap;
      v = ew1[(oc * 3 + ic) * 16 + tap];
    }
    split_store(v, W1H, W1L, i);
  } else if (b < 4160) {
    int i = (b - 64) * 256 + t;
    int oc = i >> 12, k = i & 4095;
    int tap = k >> 8, ic = k & 255;
    split_store(ew2[(oc * 256 + ic) * 16 + tap], W2H, W2L, i);
  } else if (b < 8768) {
    int i = (b - 4160) * 256 + t;
    int rb = i / 589824, r2 = i - rb * 589824;
    int oc = r2 / 2304, k = r2 - oc * 2304;
    int r9 = k >> 8, ic = k & 255;
    split_store(r3w[((rb * 256 + oc) * 256 + ic) * 9 + r9], W3EH, W3EL, i);
  } else if (b < 13376) {
    int i = (b - 8768) * 256 + t;
    int rb = i / 589824, r2 = i - rb * 589824;
    int oc = r2 / 2304, k = r2 - oc * 2304;
    int r9 = k >> 8, ic = k & 255;
    W3D[i] = f2bs(r3w[(((rb + 2) * 256 + oc) * 256 + ic) * 9 + r9]);
  } else if (b < 13888) {
    int i = (b - 13376) * 256 + t;
    split_store(r1w[i], W1REH, W1REL, i);
  } else if (b < 14400) {
    int i = (b - 13888) * 256 + t;
    W1RD[i] = f2bs(r1w[2 * 65536 + i]);
  } else if (b < 18496) {
    int i = (b - 14400) * 256 + t;
    int cls = i >> 18, r2 = i & 262143;
    int oc = r2 >> 10, k = r2 & 1023;
    int tap = k >> 8, ic = k & 255;
    int s = tap >> 1, sx = tap & 1;
    int py = cls >> 1, px = cls & 1;
    int ky = py + 2 - 2 * s, kx = px + 2 - 2 * sx;
    WD1[i] = f2bs(dw1[(ic * 256 + oc) * 16 + ky * 4 + kx]);
  } else if (b < 18544) {
    int i = (b - 18496) * 256 + t;  // [0, 12288)
    int j = i >> 8, ic = i & 255;
    int kyx = j / 3, oc = j - kyx * 3;
    split_store(dw2[(ic * 3 + oc) * 16 + kyx], WD2H, WD2L, (size_t)j * 256 + ic);
  } else if (b < 18546) {
    int e = (b - 18544) * 256 + t;
    float s = 0.f;
    for (int c = 0; c < 256; ++c) {
      float v = emb[e * 256 + c];
      s += v * v;
    }
    enorm[e] = s;
  } else if (b == 18546) {
    if (t < 2) acc[t] = 0.f;
    if (t < 64) zrow[t] = 0.f;
    for (int k = t; k < 2048; k += 256) ssq[k] = 0.f;
  } else if (b < 34931) {
    int i = (b - 18547) * 256 + t;
    int t1 = i >> 6, k = i & 63;
    float v = 0.f;
    if (k < 48) {
      int tap = k / 3, ic = k - 3 * tap;
      int n = t1 >> 8, oy = (t1 >> 4) & 15, ox = t1 & 15;
      int ky = tap >> 2, kx = tap & 3;
      int iy = 2 * oy - 1 + ky, ix = 2 * ox - 1 + kx;
      if ((unsigned)iy < 32u && (unsigned)ix < 32u)
        v = x[((n * 3 + ic) * 32 + iy) * 32 + ix];
    }
    split_store(v, A1H, A1L, i);
  } else {
    int i = (b - 34931) * 256 + t;
    int code = i >> 8, c = i & 255;
    embT[c * 512 + code] = emb[i];
  }
}

// ---------------- MFMA GEMM (BN=256, BM=64, 8 waves, PIPE=3) — r9 proven ----
template <int MODE, int EPI, int STYLE, int SSQ>
__global__ __launch_bounds__(512) void k_gemm(const ushort_t* __restrict__ Ah,
                                              const ushort_t* __restrict__ Al,
                                              const ushort_t* __restrict__ Bh,
                                              const ushort_t* __restrict__ Bl, int K,
                                              const float* __restrict__ bias,
                                              const float* __restrict__ res,
                                              float* __restrict__ outf,
                                              ushort_t* __restrict__ outb,
                                              ushort_t* __restrict__ outb2,
                                              const ushort_t* __restrict__ zrow,
                                              float* __restrict__ ssqp) {
  constexpr int PIPE = 3;
  __shared__ __align__(16) ushort_t A0[PIPE][64 * 32];
  __shared__ __align__(16) ushort_t A1s[PIPE][64 * 32];
  __shared__ __align__(16) ushort_t B0[PIPE][256 * 32];
  __shared__ __align__(16) ushort_t B1[PIPE][256 * 32];
  const int t = threadIdx.x;
  const int w = t >> 6, l = t & 63;
  const int M0 = blockIdx.x * 64;
  int py = 0, px = 0;
  const ushort_t* Bb = Bh;
  if (MODE == 3) {
    int cls = blockIdx.z;
    py = cls >> 1;
    px = cls & 1;
    Bb = Bh + (size_t)cls * 262144;
  }
  const int srow = l & 15, chunk = l >> 4;
  const int fr = l & 15, quad = l >> 4;
  const int m_off = (w & 1) * 32, n_off = (w >> 1) * 64;
  const int mset = (m_off >> 4), nset = (n_off >> 4);

  const int aw = w & 3;
  const bool aH = (w < 4);
  const int atok = M0 + aw * 16 + srow;
  const size_t bb0 = (size_t)(2 * w * 16 + srow) * K + chunk * 8;
  const size_t bb1 = (size_t)((2 * w + 1) * 16 + srow) * K + chunk * 8;

  f32x4 acc[2][4];
#pragma unroll
  for (int i = 0; i < 2; ++i)
#pragma unroll
    for (int j = 0; j < 4; ++j) acc[i][j] = (f32x4){0.f, 0.f, 0.f, 0.f};

  const int n1 = atok >> 6, oy1 = (atok >> 3) & 7, ox1 = atok & 7;
  const ushort_t* zp = zrow + chunk * 8;

  const int SUB = (STYLE == 1) ? 32 : 64;

  size_t r1s = 0;
  bool v1s = true;
  if (MODE == 0) r1s = (size_t)atok * K + chunk * 8;

  auto stage = [&](int kk, int s) {
    const ushort_t* pa;
    if (MODE == 0) {
      size_t o = r1s + kk;
      pa = aH ? (Ah + o) : ((STYLE == 1) ? (Al + o) : (Ah + o + 32));
    } else {
      if ((kk & 255) == 0) {
        int tap = kk >> 8;
        int iy, ix;
        unsigned lim;
        if (MODE == 1) {
          int ky = tap >> 2, kx = tap & 3;
          iy = 2 * oy1 - 1 + ky; ix = 2 * ox1 - 1 + kx;
          lim = 16u;
        } else if (MODE == 2) {
          int ky = tap / 3, kx = tap - ky * 3;
          iy = oy1 - 1 + ky; ix = ox1 - 1 + kx;
          lim = 8u;
        } else {
          int s2 = tap >> 1, sx = tap & 1;
          iy = oy1 + s2 - py; ix = ox1 + sx - px;
          lim = 8u;
        }
        v1s = ((unsigned)iy < lim && (unsigned)ix < lim);
        if (MODE == 1)
          r1s = (size_t)(((n1 << 8) + (iy << 4) + ix)) << 8;
        else
          r1s = (size_t)(((n1 << 6) + (iy << 3) + ix)) << 8;
      }
      int kin = (kk & 255) + chunk * 8;
      if (v1s)
        pa = aH ? (Ah + r1s + kin)
                : ((STYLE == 1) ? (Al + r1s + kin) : (Ah + r1s + kin + 32));
      else
        pa = zp;
    }
    size_t bo0 = bb0 + kk, bo1 = bb1 + kk;
    glds16(pa, (aH ? A0[s] : A1s[s]) + aw * 512);
    glds16(Bb + bo0, B0[s] + (2 * w) * 512);
    glds16(Bb + bo1, B0[s] + (2 * w + 1) * 512);
    glds16((STYLE == 1) ? (Bl + bo0) : (Bb + bo0 + 32), B1[s] + (2 * w) * 512);
    glds16((STYLE == 1) ? (Bl + bo1) : (Bb + bo1 + 32), B1[s] + (2 * w + 1) * 512);
  };

  auto compute = [&](int s) {
    short8v af0[2], af1[2], bf0[4], bf1[4];
#pragma unroll
    for (int mi = 0; mi < 2; ++mi) {
      af0[mi] = *(const short8v*)(A0[s] + (mset + mi) * 512 + quad * 128 + fr * 8);
      af1[mi] = *(const short8v*)(A1s[s] + (mset + mi) * 512 + quad * 128 + fr * 8);
    }
#pragma unroll
    for (int nj = 0; nj < 4; ++nj) {
      bf0[nj] = *(const short8v*)(B0[s] + (nset + nj) * 512 + quad * 128 + fr * 8);
      bf1[nj] = *(const short8v*)(B1[s] + (nset + nj) * 512 + quad * 128 + fr * 8);
    }
#pragma unroll
    for (int mi = 0; mi < 2; ++mi)
#pragma unroll
      for (int nj = 0; nj < 4; ++nj) {
        acc[mi][nj] =
            __builtin_amdgcn_mfma_f32_16x16x32_bf16(af0[mi], bf0[nj], acc[mi][nj], 0, 0, 0);
        if (STYLE == 1) {
          acc[mi][nj] =
              __builtin_amdgcn_mfma_f32_16x16x32_bf16(af1[mi], bf0[nj], acc[mi][nj], 0, 0, 0);
          acc[mi][nj] =
              __builtin_amdgcn_mfma_f32_16x16x32_bf16(af0[mi], bf1[nj], acc[mi][nj], 0, 0, 0);
        } else {
          acc[mi][nj] =
              __builtin_amdgcn_mfma_f32_16x16x32_bf16(af1[mi], bf1[nj], acc[mi][nj], 0, 0, 0);
        }
      }
  };

  {
    const int nt = K / SUB;
    stage(0, 0);
    int ns = 1;
    if (nt > 1) {
      stage(SUB, 1);
      ns = 2;
    }
    int cb = 0, sb2 = ns % PIPE;
    for (int tt = 0; tt < nt; ++tt) {
      if (ns > tt + 1) {
        asm volatile("s_waitcnt vmcnt(5)" ::: "memory");
      } else {
        asm volatile("s_waitcnt vmcnt(0)" ::: "memory");
      }
      asm volatile("s_barrier" ::: "memory");
      if (ns < nt) {
        stage(ns * SUB, sb2);
        ++ns;
        sb2 = (sb2 + 1 == PIPE) ? 0 : sb2 + 1;
      }
      compute(cb);
      cb = (cb + 1 == PIPE) ? 0 : cb + 1;
    }
  }

  float sq = 0.f;
#pragma unroll
  for (int mi = 0; mi < 2; ++mi) {
    int mrow = m_off + mi * 16 + quad * 4;
#pragma unroll
    for (int nj = 0; nj < 4; ++nj) {
      int col = n_off + nj * 16 + fr;
      float bv = bias[col];
#pragma unroll
      for (int i = 0; i < 4; ++i) {
        int m = M0 + mrow + i;
        float v = fmaxf(acc[mi][nj][i] + bv, 0.f);
        if (EPI == 1) {
          outf[(size_t)m * 256 + col] = v;
          if (SSQ) sq += v * v;
        } else if (EPI == 2) {
          size_t o = (size_t)m * 256 + col;
          float vv = res[o] + v;
          outf[o] = vv;
          if (SSQ) sq += vv * vv;
        } else if (EPI == 3) {
          int nn = m >> 6, jj = (m >> 3) & 7, ii = m & 7;
          int oy = 2 * jj + 1 - py, ox = 2 * ii + 1 - px;
          outb[(size_t)((nn << 8) + oy * 16 + ox) * 256 + col] = f2bs(v);
        } else if (EPI == 4) {
          size_t o = (size_t)m * 256 + col;
          ushort_t h = f2bs(v);
          outb[o] = h;
          outb2[o] = f2bs(v - bs2f(h));
        } else {  // EPI 5
          size_t o = (size_t)m * 256 + col;
          float vv = res[o] + v;
          outf[o] = vv;
          outb[o] = f2bs(vv);
        }
      }
    }
  }
  if (SSQ) {
#pragma unroll
    for (int off = 32; off > 0; off >>= 1) sq += __shfl_down(sq, off, 64);
    if (l == 0) atomicAdd(&ssqp[M0 >> 6], sq);
  }
}

// ---------------- K-split MFMA GEMM (BM=128, BN=256, grid (M/128, 2)) ------
// Halves the per-block count and doubles BM -> staged bytes drop 40%
// (total = M*N*K*4*(1/BM+1/BN)); all 256 CUs stay busy via the K-split.
// blockIdx.y selects K-half [koff, koff+KH); raw fp32 partial -> sc0/sc1.
// Bias/ReLU/residual/SSQ deferred to k_epi (no inter-block ordering needed).
// 8 waves, wave tile 64x64 (acc[4][4]); 6 glds/wave/step -> vmcnt(6).
// LDS = 3*(8+8+16+16) KB = 144 KB -> 1 block/CU.
template <int MODE, int STYLE>
__global__ __launch_bounds__(512) void k_gemmks(const ushort_t* __restrict__ Ah,
                                                const ushort_t* __restrict__ Al,
                                                const ushort_t* __restrict__ Bh,
                                                const ushort_t* __restrict__ Bl,
                                                int K, int KH,
                                                float* __restrict__ sc0,
                                                float* __restrict__ sc1,
                                                const ushort_t* __restrict__ zrow) {
  constexpr int PIPE = 3;
  __shared__ __align__(16) ushort_t A0[PIPE][128 * 32];
  __shared__ __align__(16) ushort_t A1s[PIPE][128 * 32];
  __shared__ __align__(16) ushort_t B0[PIPE][256 * 32];
  __shared__ __align__(16) ushort_t B1[PIPE][256 * 32];
  const int t = threadIdx.x;
  const int w = t >> 6, l = t & 63;
  const int M0 = blockIdx.x * 128;
  const int koff = blockIdx.y * KH;
  float* outp = blockIdx.y ? sc1 : sc0;
  const int srow = l & 15, chunk = l >> 4;
  const int fr = l & 15, quad = l >> 4;
  const int m_off = (w & 1) * 64, n_off = (w >> 1) * 64;
  const int mset = m_off >> 4, nset = n_off >> 4;

  // wave w stages A row-group w (16 rows, H and L) + B row-groups {2w,2w+1}
  const int atok = M0 + w * 16 + srow;
  const size_t bb0 = (size_t)(2 * w * 16 + srow) * K + chunk * 8;
  const size_t bb1 = (size_t)((2 * w + 1) * 16 + srow) * K + chunk * 8;

  f32x4 acc[4][4];
#pragma unroll
  for (int i = 0; i < 4; ++i)
#pragma unroll
    for (int j = 0; j < 4; ++j) acc[i][j] = (f32x4){0.f, 0.f, 0.f, 0.f};

  const int n1 = atok >> 6, oy1 = (atok >> 3) & 7, ox1 = atok & 7;
  const ushort_t* zp = zrow + chunk * 8;
  const int SUB = (STYLE == 1) ? 32 : 64;

  size_t r1s = 0;
  bool v1s = true;
  if (MODE == 0) r1s = (size_t)atok * K + chunk * 8;

  auto stage = [&](int kk, int s) {
    const ushort_t *pa, *pa2;
    if (MODE == 0) {
      size_t o = r1s + kk;
      pa = Ah + o;
      pa2 = (STYLE == 1) ? (Al + o) : (Ah + o + 32);
    } else {
      if ((kk & 255) == 0 || kk == koff) {  // koff may start mid-tap
        int tap = kk >> 8;
        int iy, ix;
        unsigned lim;
        if (MODE == 1) {
          int ky = tap >> 2, kx = tap & 3;
          iy = 2 * oy1 - 1 + ky; ix = 2 * ox1 - 1 + kx;
          lim = 16u;
        } else {  // MODE 2
          int ky = tap / 3, kx = tap - ky * 3;
          iy = oy1 - 1 + ky; ix = ox1 - 1 + kx;
          lim = 8u;
        }
        v1s = ((unsigned)iy < lim && (unsigned)ix < lim);
        if (MODE == 1)
          r1s = (size_t)(((n1 << 8) + (iy << 4) + ix)) << 8;
        else
          r1s = (size_t)(((n1 << 6) + (iy << 3) + ix)) << 8;
      }
      int kin = (kk & 255) + chunk * 8;
      if (v1s) {
        pa = Ah + r1s + kin;
        pa2 = (STYLE == 1) ? (Al + r1s + kin) : (Ah + r1s + kin + 32);
      } else {
        pa = zp;
        pa2 = zp;
      }
    }
    size_t bo0 = bb0 + kk, bo1 = bb1 + kk;
    glds16(pa, A0[s] + w * 512);
    glds16(pa2, A1s[s] + w * 512);
    glds16(Bh + bo0, B0[s] + (2 * w) * 512);
    glds16(Bh + bo1, B0[s] + (2 * w + 1) * 512);
    glds16((STYLE == 1) ? (Bl + bo0) : (Bh + bo0 + 32), B1[s] + (2 * w) * 512);
    glds16((STYLE == 1) ? (Bl + bo1) : (Bh + bo1 + 32), B1[s] + (2 * w + 1) * 512);
  };

  auto compute = [&](int s) {
    short8v af0[4], af1[4], bf0[4], bf1[4];
#pragma unroll
    for (int mi = 0; mi < 4; ++mi) {
      af0[mi] = *(const short8v*)(A0[s] + (mset + mi) * 512 + quad * 128 + fr * 8);
      af1[mi] = *(const short8v*)(A1s[s] + (mset + mi) * 512 + quad * 128 + fr * 8);
    }
#pragma unroll
    for (int nj = 0; nj < 4; ++nj) {
      bf0[nj] = *(const short8v*)(B0[s] + (nset + nj) * 512 + quad * 128 + fr * 8);
      bf1[nj] = *(const short8v*)(B1[s] + (nset + nj) * 512 + quad * 128 + fr * 8);
    }
#pragma unroll
    for (int mi = 0; mi < 4; ++mi)
#pragma unroll
      for (int nj = 0; nj < 4; ++nj) {
        acc[mi][nj] =
            __builtin_amdgcn_mfma_f32_16x16x32_bf16(af0[mi], bf0[nj], acc[mi][nj], 0, 0, 0);
        if (STYLE == 1) {
          acc[mi][nj] =
              __builtin_amdgcn_mfma_f32_16x16x32_bf16(af1[mi], bf0[nj], acc[mi][nj], 0, 0, 0);
          acc[mi][nj] =
              __builtin_amdgcn_mfma_f32_16x16x32_bf16(af0[mi], bf1[nj], acc[mi][nj], 0, 0, 0);
        } else {
          acc[mi][nj] =
              __builtin_amdgcn_mfma_f32_16x16x32_bf16(af1[mi], bf1[nj], acc[mi][nj], 0, 0, 0);
        }
      }
  };

  {
    const int nt = KH / SUB;
    stage(koff, 0);
    int ns = 1;
    if (nt > 1) {
      stage(koff + SUB, 1);
      ns = 2;
    }
    int cb = 0, sb2 = ns % PIPE;
    for (int tt = 0; tt < nt; ++tt) {
      if (ns > tt + 1) {
        asm volatile("s_waitcnt vmcnt(6)" ::: "memory");
      } else {
        asm volatile("s_waitcnt vmcnt(0)" ::: "memory");
      }
      asm volatile("s_barrier" ::: "memory");
      if (ns < nt) {
        stage(koff + ns * SUB, sb2);
        ++ns;
        sb2 = (sb2 + 1 == PIPE) ? 0 : sb2 + 1;
      }
      compute(cb);
      cb = (cb + 1 == PIPE) ? 0 : cb + 1;
    }
  }

  // raw fp32 partial store (bias/relu/res/ssq deferred to k_epi)
#pragma unroll
  for (int mi = 0; mi < 4; ++mi) {
    int mrow = m_off + mi * 16 + quad * 4;
#pragma unroll
    for (int nj = 0; nj < 4; ++nj) {
      int col = n_off + nj * 16 + fr;
#pragma unroll
      for (int i = 0; i < 4; ++i)
        outp[(size_t)(M0 + mrow + i) * 256 + col] = acc[mi][nj][i];
    }
  }
}

// ---------------- K-split epilogue: out = [res +] relu(sc0+sc1+bias), SSQ ---
// One block per 64-token sample -> direct ssqp[sample] store (no atomics).
template <int RES>
__global__ void __launch_bounds__(256) k_epi(const float* __restrict__ sc0,
                                             const float* __restrict__ sc1,
                                             const float* __restrict__ bias,
                                             const float* __restrict__ res,
                                             float* __restrict__ out,
                                             float* __restrict__ ssqp) {
  __shared__ float red[256];
  int s = blockIdx.x, t = threadIdx.x;
  size_t base = (size_t)s * 64 * 256;
  float bv = bias[t];
  float sq = 0.f;
  for (int r = 0; r < 64; ++r) {
    size_t o = base + (size_t)r * 256 + t;
    float v = fmaxf(sc0[o] + sc1[o] + bv, 0.f);
    if (RES) v += res[o];
    out[o] = v;
    sq += v * v;
  }
  red[t] = sq;
  __syncthreads();
  for (int k = 128; k > 0; k >>= 1) {
    if (t < k) red[t] += red[t + k];
    __syncthreads();
  }
  if (t == 0) ssqp[s] = red[0];
}

// ---------------- rmsnorm normalize-only (unchanged) ----------
template <int SPLIT>
__global__ void __launch_bounds__(256) k_rmsnorm(const float* __restrict__ in,
                                                 const float* __restrict__ rmsw,
                                                 const float* __restrict__ ssq,
                                                 ushort_t* __restrict__ NBh,
                                                 ushort_t* __restrict__ NBl) {
  extern __shared__ float wT[];  // 64*257 floats
  int n = blockIdx.x, t = threadIdx.x;
  const float* p = in + (size_t)n * 16384;
  for (int k = 0; k < 64; ++k) {
    int i = k * 256 + t;  // i = c*64 + j
    wT[(i & 63) * 257 + (i >> 6)] = rmsw[i];
  }
  float scale = 1.0f / sqrtf(ssq[n] / 16384.f + 1.1920929e-07f);
  __syncthreads();
  ushort_t* oh = NBh + (size_t)n * 16384;
  ushort_t* ol = NBl + (size_t)n * 16384;
  for (int j = 0; j < 64; ++j) {
    int i = j * 256 + t;
    float v = p[i] * scale * wT[j * 257 + t];
    ushort_t h = f2bs(v);
    oh[i] = h;
    if (SPLIT) ol[i] = f2bs(v - bs2f(h));
  }
}

// ---------------- VQ (unchanged) ----------------
__global__ void __launch_bounds__(256) k_vq(const float* __restrict__ enc,
                                            const float* __restrict__ embT,
                                            const float* __restrict__ emb,
                                            const float* __restrict__ enorm,
                                            float* __restrict__ q, float* __restrict__ sse,
                                            float* __restrict__ ssq4) {
  __shared__ float z[16][256];
  __shared__ float sc[512 * 16];
  __shared__ float bv[16][16];
  __shared__ int bi[16][16];
  __shared__ int idxs[16];
  int T0 = blockIdx.x * 16;
  int t = threadIdx.x;
  for (int j = 0; j < 16; ++j) z[j][t] = enc[(size_t)(T0 + j) * 256 + t];
  __syncthreads();
  float d0[16], d1[16];
#pragma unroll
  for (int j = 0; j < 16; ++j) { d0[j] = 0.f; d1[j] = 0.f; }
  for (int c4 = 0; c4 < 64; ++c4) {
    const float* eb = embT + (size_t)(c4 * 4) * 512 + t;
    float e00 = eb[0], f00 = eb[256];
    float e01 = eb[512], f01 = eb[768];
    float e02 = eb[1024], f02 = eb[1280];
    float e03 = eb[1536], f03 = eb[1792];
#pragma unroll
    for (int j = 0; j < 16; ++j) {
      float4 zv = *(const float4*)&z[j][c4 * 4];
      d0[j] += zv.x * e00 + zv.y * e01 + zv.z * e02 + zv.w * e03;
      d1[j] += zv.x * f00 + zv.y * f01 + zv.z * f02 + zv.w * f03;
    }
  }
  float en0 = enorm[t], en1 = enorm[t + 256];
#pragma unroll
  for (int j = 0; j < 16; ++j) {
    sc[t * 16 + j] = en0 - 2.f * d0[j];
    sc[(t + 256) * 16 + j] = en1 - 2.f * d1[j];
  }
  __syncthreads();
  {
    int j = t & 15, chunk = t >> 4;
    float best = 3.4e38f;
    int bidx = 0;
    int c0 = chunk * 32;
    for (int cc = 0; cc < 32; ++cc) {
      float v = sc[(c0 + cc) * 16 + j];
      if (v < best) { best = v; bidx = c0 + cc; }
    }
    bv[chunk][j] = best;
    bi[chunk][j] = bidx;
  }
  __syncthreads();
  if (t < 16) {
    float best = 3.4e38f;
    int bidx = 0;
    for (int c = 0; c < 16; ++c) {
      float v = bv[c][t];
      if (v < best) { best = v; bidx = bi[c][t]; }
    }
    idxs[t] = bidx;
  }
  __syncthreads();
  float sq = 0.f, sqq = 0.f;
  for (int j = 0; j < 16; ++j) {
    float e = emb[(size_t)idxs[j] * 256 + t];
    q[(size_t)(T0 + j) * 256 + t] = e;
    float d = z[j][t] - e;
    sq += d * d;
    sqq += e * e;
  }
  __syncthreads();
  sc[t] = sq;
  __syncthreads();
  for (int k = 128; k > 0; k >>= 1) {
    if (t < k) sc[t] += sc[t + k];
    __syncthreads();
  }
  if (t == 0) atomicAdd(sse, sc[0]);
  __syncthreads();
  sc[t] = sqq;
  __syncthreads();
  for (int k = 128; k > 0; k >>= 1) {
    if (t < k) sc[t] += sc[t + k];
    __syncthreads();
  }
  if (t == 0) atomicAdd(&ssq4[blockIdx.x >> 2], sc[0]);
}

// ---------------- deconv2 as GEMM (unchanged from r9) ----------------
__global__ void __launch_bounds__(256) k_dec2gemm(const ushort_t* __restrict__ A,
                                                  const ushort_t* __restrict__ BH,
                                                  const ushort_t* __restrict__ BL,
                                                  float* __restrict__ G) {
  __shared__ __align__(16) ushort_t sBH[48 * 256];
  __shared__ __align__(16) ushort_t sBL[48 * 256];
  const int t = threadIdx.x;
  const int w = t >> 6, l = t & 63;
  const int fr = l & 15, quad = l >> 4, quad8 = quad * 8;
  for (int i = t * 8; i < 12288; i += 2048) {
    *(short8v*)(sBH + i) = *(const short8v*)(BH + i);
    *(short8v*)(sBL + i) = *(const short8v*)(BL + i);
  }
  __syncthreads();
  const int tok0 = blockIdx.x * 128 + w * 32;
  f32x4 acc[2][3];
#pragma unroll
  for (int i = 0; i < 2; ++i)
#pragma unroll
    for (int j = 0; j < 3; ++j) acc[i][j] = (f32x4){0.f, 0.f, 0.f, 0.f};
#pragma unroll
  for (int kk = 0; kk < 256; kk += 32) {
    short8v af[2];
#pragma unroll
    for (int mi = 0; mi < 2; ++mi)
      af[mi] = *(const short8v*)(A + (size_t)(tok0 + mi * 16 + fr) * 256 + kk + quad8);
#pragma unroll
    for (int nj = 0; nj < 3; ++nj) {
      short8v bh = *(const short8v*)(sBH + (nj * 16 + fr) * 256 + kk + quad8);
      short8v bl = *(const short8v*)(sBL + (nj * 16 + fr) * 256 + kk + quad8);
#pragma unroll
      for (int mi = 0; mi < 2; ++mi) {
        acc[mi][nj] =
            __builtin_amdgcn_mfma_f32_16x16x32_bf16(af[mi], bh, acc[mi][nj], 0, 0, 0);
        acc[mi][nj] =
            __builtin_amdgcn_mfma_f32_16x16x32_bf16(af[mi], bl, acc[mi][nj], 0, 0, 0);
      }
    }
  }
#pragma unroll
  for (int mi = 0; mi < 2; ++mi) {
    int mrow = mi * 16 + quad * 4;
#pragma unroll
    for (int nj = 0; nj < 3; ++nj) {
      int col = nj * 16 + fr;
#pragma unroll
      for (int i = 0; i < 4; ++i)
        G[(size_t)(tok0 + mrow + i) * 64 + col] = acc[mi][nj][i];
    }
  }
}

// ---------------- deconv2 gather + reconst loss (unchanged) ----------------
__global__ void __launch_bounds__(256) k_dec2gather(const float* __restrict__ G,
                                                    const float* __restrict__ bias,
                                                    const float* __restrict__ x,
                                                    float* __restrict__ dec,
                                                    float* __restrict__ sse) {
  __shared__ float GL[256 * 49];
  __shared__ float red[256];
  int n = blockIdx.x, t = threadIdx.x;
  for (int i = t; i < 12288; i += 256) {
    int r = i / 48, c = i - r * 48;
    GL[r * 49 + c] = G[(size_t)((n << 8) + r) * 64 + c];
  }
  __syncthreads();
  float sq = 0.f;
  for (int rep = 0; rep < 12; ++rep) {
    int o = rep * 256 + t;
    int oc = o >> 10, rem = o & 1023;
    int oy = rem >> 5, ox = rem & 31;
    int py = (oy + 1) & 1, dy = (oy + 1 - py) >> 1;
    int px = (ox + 1) & 1, dx = (ox + 1 - px) >> 1;
    int iy0 = dy - 1, ix0 = dx - 1;
    bool y0 = (unsigned)iy0 < 16u, y1 = (unsigned)dy < 16u;
    bool x0 = (unsigned)ix0 < 16u, x1 = (unsigned)dx < 16u;
    float v = bias[oc];
    if (y0 && x0) v += GL[(iy0 * 16 + ix0) * 49 + ((py + 2) * 4 + px + 2) * 3 + oc];
    if (y0 && x1) v += GL[(iy0 * 16 + dx) * 49 + ((py + 2) * 4 + px) * 3 + oc];
    if (y1 && x0) v += GL[(dy * 16 + ix0) * 49 + (py * 4 + px + 2) * 3 + oc];
    if (y1 && x1) v += GL[(dy * 16 + dx) * 49 + (py * 4 + px) * 3 + oc];
    int oi = ((n * 3 + oc) * 32 + oy) * 32 + ox;
    dec[oi] = v;
    float d = v - x[oi];
    sq += d * d;
  }
  red[t] = sq;
  __syncthreads();
  for (int k = 128; k > 0; k >>= 1) {
    if (t < k) red[t] += red[t + k];
    __syncthreads();
  }
  if (t == 0) atomicAdd(sse, red[0]);
}

__global__ void k_final(const float* __restrict__ acc, float* __restrict__ out) {
  if (threadIdx.x == 0 && blockIdx.x == 0) {
    float vq = acc[0] / 4194304.f;
    float rec = acc[1] / 786432.f;
    out[0] = rec + 2.f * vq;
    out[1] = rec;
    out[2] = vq;
    out[3] = vq;
  }
}

extern "C" void kernel_launch(void* const* d_in, const int* in_sizes, int n_in,
                              void* d_out, int out_size, void* d_ws, size_t ws_size,
                              hipStream_t stream) {
  (void)in_sizes; (void)n_in; (void)out_size; (void)ws_size;
  const float* x = (const float*)d_in[0];
  const float* ew1 = (const float*)d_in[1];
  const float* eb1 = (const float*)d_in[2];
  const float* ew2 = (const float*)d_in[3];
  const float* eb2 = (const float*)d_in[4];
  const float* rmsw = (const float*)d_in[5];
  const float* r3w = (const float*)d_in[6];
  const float* r3b = (const float*)d_in[7];
  const float* r1w = (const float*)d_in[8];
  const float* r1b = (const float*)d_in[9];
  const float* emb = (const float*)d_in[10];
  const float* dw1 = (const float*)d_in[11];
  const float* db1 = (const float*)d_in[12];
  const float* dw2 = (const float*)d_in[13];
  const float* db2 = (const float*)d_in[14];
  float* out = (float*)d_out;

  float* wsf = (float*)d_ws;
  float* P = wsf + OFF_P;
  float* enorm = wsf + OFF_ENORM;
  float* acc = wsf + OFF_ACC;
  float* zrowf = wsf + OFF_ZROW;
  float* embT = wsf + OFF_EMBT;
  float* ssq = wsf + OFF_SSQ;
  ushort_t* WD2H = (ushort_t*)(wsf + OFF_WD2);
  ushort_t* WD2L = WD2H + 12288;
  ushort_t* sb = (ushort_t*)(wsf + OFF_SHORT);
  ushort_t* H1H = sb + SO_H1H;
  ushort_t* H1L = sb + SO_H1L;
  float* Qf = (float*)(sb + SO_H1L);
  ushort_t* NBH = sb + SO_NBH;
  ushort_t* NBL = sb + SO_NBL;
  ushort_t* A1H = NBH;
  ushort_t* A1L = NBL;
  ushort_t* QB = NBL;
  ushort_t* W1H = sb + SO_W1H;
  ushort_t* W1L = sb + SO_W1L;
  ushort_t* W2H = sb + SO_W2H;
  ushort_t* W2L = sb + SO_W2L;
  ushort_t* W3EH = sb + SO_W3EH;
  ushort_t* W3EL = sb + SO_W3EL;
  ushort_t* W3D = sb + SO_W3D;
  ushort_t* W1REH = sb + SO_W1REH;
  ushort_t* W1REL = sb + SO_W1REL;
  ushort_t* W1RD = sb + SO_W1RD;
  ushort_t* WD1 = sb + SO_WD1;
  const ushort_t* zrow = (const ushort_t*)zrowf;
  // K-split scratch (raw fp32 partials), all in regions dead at time of use:
  float* NBf = (float*)(sb + SO_NBH);   // conv2 SC0 (A1 consumed by conv1)
  float* H1f = (float*)(sb + SO_H1H);   // res3 SC0 (H1 dead after conv2)
  const size_t RMS_LDS = 64 * 257 * sizeof(float);

  k_prep<<<35443, 256, 0, stream>>>(x, ew1, ew2, r3w, r1w, dw1, dw2, emb,
                                    W1H, W1L, W2H, W2L, W3EH, W3EL, W3D,
                                    W1REH, W1REL, W1RD, WD1, WD2H, WD2L, enorm,
                                    acc, zrowf, embT, ssq, A1H, A1L);

  // conv1 (split, K=64): M=65536 -> 1024 blocks (unchanged)
  k_gemm<0, 4, 1, 0><<<dim3(1024), 512, 0, stream>>>(
      A1H, A1L, W1H, W1L, 64, eb1, nullptr, nullptr, H1H, H1L, zrow, nullptr);
  // conv2 (split, K=4096) K-split: partials -> NBf / P; epi -> P + ssq0
  k_gemmks<1, 1><<<dim3(128, 2), 512, 0, stream>>>(
      H1H, H1L, W2H, W2L, 4096, 2048, NBf, P, zrow);
  k_epi<0><<<256, 256, 0, stream>>>(NBf, P, eb2, nullptr, P, ssq + 0);
  for (int rb = 0; rb < 2; ++rb) {
    k_rmsnorm<1><<<256, 256, RMS_LDS, stream>>>(
        P, rmsw + (size_t)(rb * 2 + 0) * 16384, ssq + (rb * 2 + 0) * 256, NBH, NBL);
    // res3-enc K-split: partials -> H1f / Qf; epi: Qf = P + relu(.), ssq
    if (rb == 0) {
      k_gemmks<2, 1><<<dim3(128, 2), 512, 0, stream>>>(
          NBH, NBL, W3EH, W3EL, 2304, 1152, H1f, Qf, zrow);
      k_epi<1><<<256, 256, 0, stream>>>(H1f, Qf, r3b, P, Qf, ssq + 256);
    } else {
      k_gemmks<2, 1><<<dim3(128, 2), 512, 0, stream>>>(
          NBH, NBL, W3EH + 589824, W3EL + 589824, 2304, 1152, H1f, Qf, zrow);
      k_epi<1><<<256, 256, 0, stream>>>(H1f, Qf, r3b + 256, P, Qf, ssq + 768);
    }
    k_rmsnorm<1><<<256, 256, RMS_LDS, stream>>>(
        Qf, rmsw + (size_t)(rb * 2 + 1) * 16384, ssq + (rb * 2 + 1) * 256, NBH, NBL);
    if (rb == 0)
      k_gemm<0, 2, 1, 1><<<dim3(256), 512, 0, stream>>>(
          NBH, NBL, W1REH, W1REL, 256, r1b, Qf, P, nullptr, nullptr, zrow, ssq + 512);
    else
      k_gemm<0, 2, 1, 0><<<dim3(256), 512, 0, stream>>>(
          NBH, NBL, W1REH + 65536, W1REL + 65536, 256, r1b + 256, Qf, P, nullptr,
          nullptr, zrow, nullptr);
  }

  // VQ: P -> Qf (q), sse -> acc[0], q-ssq -> slot 4
  k_vq<<<1024, 256, 0, stream>>>(P, embT, emb, enorm, Qf, acc + 0, ssq + 1024);

  for (int rb = 2; rb < 4; ++rb) {
    k_rmsnorm<0><<<256, 256, RMS_LDS, stream>>>(
        Qf, rmsw + (size_t)(rb * 2 + 0) * 16384, ssq + (rb * 2 + 0) * 256, NBH, NBL);
    // res3-dec K-split: partials -> H1f / P; epi: P = Qf + relu(.), ssq
    if (rb == 2) {
      k_gemmks<2, 0><<<dim3(128, 2), 512, 0, stream>>>(
          NBH, nullptr, W3D, nullptr, 2304, 1152, H1f, P, zrow);
      k_epi<1><<<256, 256, 0, stream>>>(H1f, P, r3b + 2 * 256, Qf, P, ssq + 1280);
    } else {
      k_gemmks<2, 0><<<dim3(128, 2), 512, 0, stream>>>(
          NBH, nullptr, W3D + 589824, nullptr, 2304, 1152, H1f, P, zrow);
      k_epi<1><<<256, 256, 0, stream>>>(H1f, P, r3b + 3 * 256, Qf, P, ssq + 1792);
    }
    k_rmsnorm<0><<<256, 256, RMS_LDS, stream>>>(
        P, rmsw + (size_t)(rb * 2 + 1) * 16384, ssq + (rb * 2 + 1) * 256, NBH, NBL);
    if (rb == 3) {
      k_gemm<0, 5, 0, 0><<<dim3(256), 512, 0, stream>>>(
          NBH, nullptr, W1RD + 65536, nullptr, 256, r1b + 3 * 256, P, Qf, QB, nullptr,
          zrow, nullptr);
    } else {
      k_gemm<0, 2, 0, 1><<<dim3(256), 512, 0, stream>>>(
          NBH, nullptr, W1RD, nullptr, 256, r1b + 2 * 256, P, Qf, nullptr, nullptr,
          zrow, ssq + 1536);
    }
  }

  // deconv1 (K=1024, 4 parity classes via z; unchanged)
  k_gemm<3, 3, 0, 0><<<dim3(256, 1, 4), 512, 0, stream>>>(
      QB, nullptr, WD1, nullptr, 1024, db1, nullptr, nullptr, H1H, nullptr, zrow, nullptr);

  // deconv2: GEMM (G = tokens x W, 48 cols) + gather/loss. G lives in P.
  k_dec2gemm<<<512, 256, 0, stream>>>(H1H, WD2H, WD2L, P);
  k_dec2gather<<<256, 256, 0, stream>>>(P, db2, x, out + 4, acc + 1);
  k_final<<<1, 64, 0, stream>>>(acc, out);
}

// Round 11
// 826.095 us; speedup vs baseline: 1.3610x; 1.0067x over previous
//
#include <hip/hip_runtime.h>
#include <hip/hip_bf16.h>

typedef unsigned short ushort_t;
typedef __attribute__((ext_vector_type(8))) short short8v;
typedef __attribute__((ext_vector_type(4))) float f32x4;

__device__ __forceinline__ ushort_t f2bs(float v) {
  union { __hip_bfloat16 h; ushort_t u; } cv;
  cv.h = __float2bfloat16(v);
  return cv.u;
}
__device__ __forceinline__ float bs2f(ushort_t u) {
  union { ushort_t u; __hip_bfloat16 h; } cv;
  cv.u = u;
  return __bfloat162float(cv.h);
}

__device__ __forceinline__ void glds16(const ushort_t* g, ushort_t* l) {
  __builtin_amdgcn_global_load_lds(
      (const __attribute__((address_space(1))) unsigned int*)(uintptr_t)g,
      (__attribute__((address_space(3))) unsigned int*)(unsigned int)(uintptr_t)l,
      16, 0, 0);
}

// ---------------- workspace layout ----------------
static constexpr size_t OFF_P = 0;
static constexpr size_t OFF_ENORM = 4194304;
static constexpr size_t OFF_WD2 = 4194816;    // WD2H[12288]+WD2L[12288] ushorts
static constexpr size_t OFF_ACC = 4207360;
static constexpr size_t OFF_ZROW = 4207368;
static constexpr size_t OFF_EMBT = 4207432;   // fp32 embT [c=256][code=512]
static constexpr size_t OFF_SSQ = 4338504;    // 8 slots x 256 samples
static constexpr size_t OFF_SHORT = 4340552;  // 16B aligned (x4 bytes)
static constexpr size_t SO_H1H = 0;
static constexpr size_t SO_H1L = 16777216;
static constexpr size_t SO_NBH = 33554432;
static constexpr size_t SO_NBL = 37748736;
static constexpr size_t SO_W1H = 41943040;
static constexpr size_t SO_W1L = 41959424;
static constexpr size_t SO_W2H = 41975808;
static constexpr size_t SO_W2L = 43024384;
static constexpr size_t SO_W3EH = 44072960;
static constexpr size_t SO_W3EL = 45252608;
static constexpr size_t SO_W3D = 46432256;
static constexpr size_t SO_W1REH = 47611904;
static constexpr size_t SO_W1REL = 47742976;
static constexpr size_t SO_W1RD = 47874048;
static constexpr size_t SO_WD1 = 48005120;

__device__ __forceinline__ void split_store(float v, ushort_t* hi, ushort_t* lo, size_t i) {
  ushort_t h = f2bs(v);
  hi[i] = h;
  lo[i] = f2bs(v - bs2f(h));
}

// ---------------- fused prep (unchanged from r10) ----------------
__global__ void __launch_bounds__(256) k_prep(
    const float* __restrict__ x, const float* __restrict__ ew1,
    const float* __restrict__ ew2, const float* __restrict__ r3w,
    const float* __restrict__ r1w, const float* __restrict__ dw1,
    const float* __restrict__ dw2, const float* __restrict__ emb,
    ushort_t* __restrict__ W1H, ushort_t* __restrict__ W1L,
    ushort_t* __restrict__ W2H, ushort_t* __restrict__ W2L,
    ushort_t* __restrict__ W3EH, ushort_t* __restrict__ W3EL,
    ushort_t* __restrict__ W3D, ushort_t* __restrict__ W1REH,
    ushort_t* __restrict__ W1REL, ushort_t* __restrict__ W1RD,
    ushort_t* __restrict__ WD1, ushort_t* __restrict__ WD2H,
    ushort_t* __restrict__ WD2L,
    float* __restrict__ enorm, float* __restrict__ acc, float* __restrict__ zrow,
    float* __restrict__ embT, float* __restrict__ ssq,
    ushort_t* __restrict__ A1H, ushort_t* __restrict__ A1L) {
  int b = blockIdx.x, t = threadIdx.x;
  if (b < 64) {
    int i = b * 256 + t;
    int oc = i >> 6, k = i & 63;
    float v = 0.f;
    if (k < 48) {
      int tap = k / 3, ic = k - 3 * tap;
      v = ew1[(oc * 3 + ic) * 16 + tap];
    }
    split_store(v, W1H, W1L, i);
  } else if (b < 4160) {
    int i = (b - 64) * 256 + t;
    int oc = i >> 12, k = i & 4095;
    int tap = k >> 8, ic = k & 255;
    split_store(ew2[(oc * 256 + ic) * 16 + tap], W2H, W2L, i);
  } else if (b < 8768) {
    int i = (b - 4160) * 256 + t;
    int rb = i / 589824, r2 = i - rb * 589824;
    int oc = r2 / 2304, k = r2 - oc * 2304;
    int r9 = k >> 8, ic = k & 255;
    split_store(r3w[((rb * 256 + oc) * 256 + ic) * 9 + r9], W3EH, W3EL, i);
  } else if (b < 13376) {
    int i = (b - 8768) * 256 + t;
    int rb = i / 589824, r2 = i - rb * 589824;
    int oc = r2 / 2304, k = r2 - oc * 2304;
    int r9 = k >> 8, ic = k & 255;
    W3D[i] = f2bs(r3w[(((rb + 2) * 256 + oc) * 256 + ic) * 9 + r9]);
  } else if (b < 13888) {
    int i = (b - 13376) * 256 + t;
    split_store(r1w[i], W1REH, W1REL, i);
  } else if (b < 14400) {
    int i = (b - 13888) * 256 + t;
    W1RD[i] = f2bs(r1w[2 * 65536 + i]);
  } else if (b < 18496) {
    int i = (b - 14400) * 256 + t;
    int cls = i >> 18, r2 = i & 262143;
    int oc = r2 >> 10, k = r2 & 1023;
    int tap = k >> 8, ic = k & 255;
    int s = tap >> 1, sx = tap & 1;
    int py = cls >> 1, px = cls & 1;
    int ky = py + 2 - 2 * s, kx = px + 2 - 2 * sx;
    WD1[i] = f2bs(dw1[(ic * 256 + oc) * 16 + ky * 4 + kx]);
  } else if (b < 18544) {
    int i = (b - 18496) * 256 + t;  // [0, 12288)
    int j = i >> 8, ic = i & 255;
    int kyx = j / 3, oc = j - kyx * 3;
    split_store(dw2[(ic * 3 + oc) * 16 + kyx], WD2H, WD2L, (size_t)j * 256 + ic);
  } else if (b < 18546) {
    int e = (b - 18544) * 256 + t;
    float s = 0.f;
    for (int c = 0; c < 256; ++c) {
      float v = emb[e * 256 + c];
      s += v * v;
    }
    enorm[e] = s;
  } else if (b == 18546) {
    if (t < 2) acc[t] = 0.f;
    if (t < 64) zrow[t] = 0.f;
    for (int k = t; k < 2048; k += 256) ssq[k] = 0.f;
  } else if (b < 34931) {
    int i = (b - 18547) * 256 + t;
    int t1 = i >> 6, k = i & 63;
    float v = 0.f;
    if (k < 48) {
      int tap = k / 3, ic = k - 3 * tap;
      int n = t1 >> 8, oy = (t1 >> 4) & 15, ox = t1 & 15;
      int ky = tap >> 2, kx = tap & 3;
      int iy = 2 * oy - 1 + ky, ix = 2 * ox - 1 + kx;
      if ((unsigned)iy < 32u && (unsigned)ix < 32u)
        v = x[((n * 3 + ic) * 32 + iy) * 32 + ix];
    }
    split_store(v, A1H, A1L, i);
  } else {
    int i = (b - 34931) * 256 + t;
    int code = i >> 8, c = i & 255;
    embT[c * 512 + code] = emb[i];
  }
}

// ---------------- MFMA GEMM (BN=256, BM=64, 8 waves, PIPE=3) — r9 proven ----
template <int MODE, int EPI, int STYLE, int SSQ>
__global__ __launch_bounds__(512) void k_gemm(const ushort_t* __restrict__ Ah,
                                              const ushort_t* __restrict__ Al,
                                              const ushort_t* __restrict__ Bh,
                                              const ushort_t* __restrict__ Bl, int K,
                                              const float* __restrict__ bias,
                                              const float* __restrict__ res,
                                              float* __restrict__ outf,
                                              ushort_t* __restrict__ outb,
                                              ushort_t* __restrict__ outb2,
                                              const ushort_t* __restrict__ zrow,
                                              float* __restrict__ ssqp) {
  constexpr int PIPE = 3;
  __shared__ __align__(16) ushort_t A0[PIPE][64 * 32];
  __shared__ __align__(16) ushort_t A1s[PIPE][64 * 32];
  __shared__ __align__(16) ushort_t B0[PIPE][256 * 32];
  __shared__ __align__(16) ushort_t B1[PIPE][256 * 32];
  const int t = threadIdx.x;
  const int w = t >> 6, l = t & 63;
  const int M0 = blockIdx.x * 64;
  int py = 0, px = 0;
  const ushort_t* Bb = Bh;
  if (MODE == 3) {
    int cls = blockIdx.z;
    py = cls >> 1;
    px = cls & 1;
    Bb = Bh + (size_t)cls * 262144;
  }
  const int srow = l & 15, chunk = l >> 4;
  const int fr = l & 15, quad = l >> 4;
  const int m_off = (w & 1) * 32, n_off = (w >> 1) * 64;
  const int mset = (m_off >> 4), nset = (n_off >> 4);

  const int aw = w & 3;
  const bool aH = (w < 4);
  const int atok = M0 + aw * 16 + srow;
  const size_t bb0 = (size_t)(2 * w * 16 + srow) * K + chunk * 8;
  const size_t bb1 = (size_t)((2 * w + 1) * 16 + srow) * K + chunk * 8;

  f32x4 acc[2][4];
#pragma unroll
  for (int i = 0; i < 2; ++i)
#pragma unroll
    for (int j = 0; j < 4; ++j) acc[i][j] = (f32x4){0.f, 0.f, 0.f, 0.f};

  const int n1 = atok >> 6, oy1 = (atok >> 3) & 7, ox1 = atok & 7;
  const ushort_t* zp = zrow + chunk * 8;

  const int SUB = (STYLE == 1) ? 32 : 64;

  size_t r1s = 0;
  bool v1s = true;
  if (MODE == 0) r1s = (size_t)atok * K + chunk * 8;

  auto stage = [&](int kk, int s) {
    const ushort_t* pa;
    if (MODE == 0) {
      size_t o = r1s + kk;
      pa = aH ? (Ah + o) : ((STYLE == 1) ? (Al + o) : (Ah + o + 32));
    } else {
      if ((kk & 255) == 0) {
        int tap = kk >> 8;
        int iy, ix;
        unsigned lim;
        if (MODE == 1) {
          int ky = tap >> 2, kx = tap & 3;
          iy = 2 * oy1 - 1 + ky; ix = 2 * ox1 - 1 + kx;
          lim = 16u;
        } else if (MODE == 2) {
          int ky = tap / 3, kx = tap - ky * 3;
          iy = oy1 - 1 + ky; ix = ox1 - 1 + kx;
          lim = 8u;
        } else {
          int s2 = tap >> 1, sx = tap & 1;
          iy = oy1 + s2 - py; ix = ox1 + sx - px;
          lim = 8u;
        }
        v1s = ((unsigned)iy < lim && (unsigned)ix < lim);
        if (MODE == 1)
          r1s = (size_t)(((n1 << 8) + (iy << 4) + ix)) << 8;
        else
          r1s = (size_t)(((n1 << 6) + (iy << 3) + ix)) << 8;
      }
      int kin = (kk & 255) + chunk * 8;
      if (v1s)
        pa = aH ? (Ah + r1s + kin)
                : ((STYLE == 1) ? (Al + r1s + kin) : (Ah + r1s + kin + 32));
      else
        pa = zp;
    }
    size_t bo0 = bb0 + kk, bo1 = bb1 + kk;
    glds16(pa, (aH ? A0[s] : A1s[s]) + aw * 512);
    glds16(Bb + bo0, B0[s] + (2 * w) * 512);
    glds16(Bb + bo1, B0[s] + (2 * w + 1) * 512);
    glds16((STYLE == 1) ? (Bl + bo0) : (Bb + bo0 + 32), B1[s] + (2 * w) * 512);
    glds16((STYLE == 1) ? (Bl + bo1) : (Bb + bo1 + 32), B1[s] + (2 * w + 1) * 512);
  };

  auto compute = [&](int s) {
    short8v af0[2], af1[2], bf0[4], bf1[4];
#pragma unroll
    for (int mi = 0; mi < 2; ++mi) {
      af0[mi] = *(const short8v*)(A0[s] + (mset + mi) * 512 + quad * 128 + fr * 8);
      af1[mi] = *(const short8v*)(A1s[s] + (mset + mi) * 512 + quad * 128 + fr * 8);
    }
#pragma unroll
    for (int nj = 0; nj < 4; ++nj) {
      bf0[nj] = *(const short8v*)(B0[s] + (nset + nj) * 512 + quad * 128 + fr * 8);
      bf1[nj] = *(const short8v*)(B1[s] + (nset + nj) * 512 + quad * 128 + fr * 8);
    }
#pragma unroll
    for (int mi = 0; mi < 2; ++mi)
#pragma unroll
      for (int nj = 0; nj < 4; ++nj) {
        acc[mi][nj] =
            __builtin_amdgcn_mfma_f32_16x16x32_bf16(af0[mi], bf0[nj], acc[mi][nj], 0, 0, 0);
        if (STYLE == 1) {
          acc[mi][nj] =
              __builtin_amdgcn_mfma_f32_16x16x32_bf16(af1[mi], bf0[nj], acc[mi][nj], 0, 0, 0);
          acc[mi][nj] =
              __builtin_amdgcn_mfma_f32_16x16x32_bf16(af0[mi], bf1[nj], acc[mi][nj], 0, 0, 0);
        } else {
          acc[mi][nj] =
              __builtin_amdgcn_mfma_f32_16x16x32_bf16(af1[mi], bf1[nj], acc[mi][nj], 0, 0, 0);
        }
      }
  };

  {
    const int nt = K / SUB;
    stage(0, 0);
    int ns = 1;
    if (nt > 1) {
      stage(SUB, 1);
      ns = 2;
    }
    int cb = 0, sb2 = ns % PIPE;
    for (int tt = 0; tt < nt; ++tt) {
      if (ns > tt + 1) {
        asm volatile("s_waitcnt vmcnt(5)" ::: "memory");
      } else {
        asm volatile("s_waitcnt vmcnt(0)" ::: "memory");
      }
      asm volatile("s_barrier" ::: "memory");
      if (ns < nt) {
        stage(ns * SUB, sb2);
        ++ns;
        sb2 = (sb2 + 1 == PIPE) ? 0 : sb2 + 1;
      }
      compute(cb);
      cb = (cb + 1 == PIPE) ? 0 : cb + 1;
    }
  }

  float sq = 0.f;
#pragma unroll
  for (int mi = 0; mi < 2; ++mi) {
    int mrow = m_off + mi * 16 + quad * 4;
#pragma unroll
    for (int nj = 0; nj < 4; ++nj) {
      int col = n_off + nj * 16 + fr;
      float bv = bias[col];
#pragma unroll
      for (int i = 0; i < 4; ++i) {
        int m = M0 + mrow + i;
        float v = fmaxf(acc[mi][nj][i] + bv, 0.f);
        if (EPI == 1) {
          outf[(size_t)m * 256 + col] = v;
          if (SSQ) sq += v * v;
        } else if (EPI == 2) {
          size_t o = (size_t)m * 256 + col;
          float vv = res[o] + v;
          outf[o] = vv;
          if (SSQ) sq += vv * vv;
        } else if (EPI == 3) {
          int nn = m >> 6, jj = (m >> 3) & 7, ii = m & 7;
          int oy = 2 * jj + 1 - py, ox = 2 * ii + 1 - px;
          outb[(size_t)((nn << 8) + oy * 16 + ox) * 256 + col] = f2bs(v);
        } else if (EPI == 4) {
          size_t o = (size_t)m * 256 + col;
          ushort_t h = f2bs(v);
          outb[o] = h;
          outb2[o] = f2bs(v - bs2f(h));
        } else {  // EPI 5
          size_t o = (size_t)m * 256 + col;
          float vv = res[o] + v;
          outf[o] = vv;
          outb[o] = f2bs(vv);
        }
      }
    }
  }
  if (SSQ) {
#pragma unroll
    for (int off = 32; off > 0; off >>= 1) sq += __shfl_down(sq, off, 64);
    if (l == 0) atomicAdd(&ssqp[M0 >> 6], sq);
  }
}

// ---------------- K-split / wide MFMA GEMM (BM=128, BN=256) ----------------
// EPIKS=0: raw fp32 partial -> sc0/sc1 (by blockIdx.y). EPIKS=3: direct
// bias+relu+bf16 scatter (deconv1; grid (128,1,4), KH=K, no split).
// 8 waves, wave tile 64x64 (acc[4][4]); 6 glds/wave/step -> vmcnt(6).
template <int MODE, int STYLE, int EPIKS>
__global__ __launch_bounds__(512) void k_gemmks(const ushort_t* __restrict__ Ah,
                                                const ushort_t* __restrict__ Al,
                                                const ushort_t* __restrict__ Bh,
                                                const ushort_t* __restrict__ Bl,
                                                int K, int KH,
                                                float* __restrict__ sc0,
                                                float* __restrict__ sc1,
                                                const float* __restrict__ bias,
                                                ushort_t* __restrict__ outb,
                                                const ushort_t* __restrict__ zrow) {
  constexpr int PIPE = 3;
  __shared__ __align__(16) ushort_t A0[PIPE][128 * 32];
  __shared__ __align__(16) ushort_t A1s[PIPE][128 * 32];
  __shared__ __align__(16) ushort_t B0[PIPE][256 * 32];
  __shared__ __align__(16) ushort_t B1[PIPE][256 * 32];
  const int t = threadIdx.x;
  const int w = t >> 6, l = t & 63;
  const int M0 = blockIdx.x * 128;
  const int koff = blockIdx.y * KH;
  float* outp = blockIdx.y ? sc1 : sc0;
  int py = 0, px = 0;
  const ushort_t* Bb = Bh;
  if (MODE == 3) {
    int cls = blockIdx.z;
    py = cls >> 1;
    px = cls & 1;
    Bb = Bh + (size_t)cls * 262144;
  }
  const int srow = l & 15, chunk = l >> 4;
  const int fr = l & 15, quad = l >> 4;
  const int m_off = (w & 1) * 64, n_off = (w >> 1) * 64;
  const int mset = m_off >> 4, nset = n_off >> 4;

  const int atok = M0 + w * 16 + srow;
  const size_t bb0 = (size_t)(2 * w * 16 + srow) * K + chunk * 8;
  const size_t bb1 = (size_t)((2 * w + 1) * 16 + srow) * K + chunk * 8;

  f32x4 acc[4][4];
#pragma unroll
  for (int i = 0; i < 4; ++i)
#pragma unroll
    for (int j = 0; j < 4; ++j) acc[i][j] = (f32x4){0.f, 0.f, 0.f, 0.f};

  const int n1 = atok >> 6, oy1 = (atok >> 3) & 7, ox1 = atok & 7;
  const ushort_t* zp = zrow + chunk * 8;
  const int SUB = (STYLE == 1) ? 32 : 64;

  size_t r1s = 0;
  bool v1s = true;
  if (MODE == 0) r1s = (size_t)atok * K + chunk * 8;

  auto stage = [&](int kk, int s) {
    const ushort_t *pa, *pa2;
    if (MODE == 0) {
      size_t o = r1s + kk;
      pa = Ah + o;
      pa2 = (STYLE == 1) ? (Al + o) : (Ah + o + 32);
    } else {
      if ((kk & 255) == 0 || kk == koff) {  // koff may start mid-tap
        int tap = kk >> 8;
        int iy, ix;
        unsigned lim;
        if (MODE == 1) {
          int ky = tap >> 2, kx = tap & 3;
          iy = 2 * oy1 - 1 + ky; ix = 2 * ox1 - 1 + kx;
          lim = 16u;
        } else if (MODE == 2) {
          int ky = tap / 3, kx = tap - ky * 3;
          iy = oy1 - 1 + ky; ix = ox1 - 1 + kx;
          lim = 8u;
        } else {  // MODE 3
          int s2 = tap >> 1, sx = tap & 1;
          iy = oy1 + s2 - py; ix = ox1 + sx - px;
          lim = 8u;
        }
        v1s = ((unsigned)iy < lim && (unsigned)ix < lim);
        if (MODE == 1)
          r1s = (size_t)(((n1 << 8) + (iy << 4) + ix)) << 8;
        else
          r1s = (size_t)(((n1 << 6) + (iy << 3) + ix)) << 8;
      }
      int kin = (kk & 255) + chunk * 8;
      if (v1s) {
        pa = Ah + r1s + kin;
        pa2 = (STYLE == 1) ? (Al + r1s + kin) : (Ah + r1s + kin + 32);
      } else {
        pa = zp;
        pa2 = zp;
      }
    }
    size_t bo0 = bb0 + kk, bo1 = bb1 + kk;
    glds16(pa, A0[s] + w * 512);
    glds16(pa2, A1s[s] + w * 512);
    glds16(Bb + bo0, B0[s] + (2 * w) * 512);
    glds16(Bb + bo1, B0[s] + (2 * w + 1) * 512);
    glds16((STYLE == 1) ? (Bl + bo0) : (Bb + bo0 + 32), B1[s] + (2 * w) * 512);
    glds16((STYLE == 1) ? (Bl + bo1) : (Bb + bo1 + 32), B1[s] + (2 * w + 1) * 512);
  };

  auto compute = [&](int s) {
    short8v af0[4], af1[4], bf0[4], bf1[4];
#pragma unroll
    for (int mi = 0; mi < 4; ++mi) {
      af0[mi] = *(const short8v*)(A0[s] + (mset + mi) * 512 + quad * 128 + fr * 8);
      af1[mi] = *(const short8v*)(A1s[s] + (mset + mi) * 512 + quad * 128 + fr * 8);
    }
#pragma unroll
    for (int nj = 0; nj < 4; ++nj) {
      bf0[nj] = *(const short8v*)(B0[s] + (nset + nj) * 512 + quad * 128 + fr * 8);
      bf1[nj] = *(const short8v*)(B1[s] + (nset + nj) * 512 + quad * 128 + fr * 8);
    }
#pragma unroll
    for (int mi = 0; mi < 4; ++mi)
#pragma unroll
      for (int nj = 0; nj < 4; ++nj) {
        acc[mi][nj] =
            __builtin_amdgcn_mfma_f32_16x16x32_bf16(af0[mi], bf0[nj], acc[mi][nj], 0, 0, 0);
        if (STYLE == 1) {
          acc[mi][nj] =
              __builtin_amdgcn_mfma_f32_16x16x32_bf16(af1[mi], bf0[nj], acc[mi][nj], 0, 0, 0);
          acc[mi][nj] =
              __builtin_amdgcn_mfma_f32_16x16x32_bf16(af0[mi], bf1[nj], acc[mi][nj], 0, 0, 0);
        } else {
          acc[mi][nj] =
              __builtin_amdgcn_mfma_f32_16x16x32_bf16(af1[mi], bf1[nj], acc[mi][nj], 0, 0, 0);
        }
      }
  };

  {
    const int nt = KH / SUB;
    stage(koff, 0);
    int ns = 1;
    if (nt > 1) {
      stage(koff + SUB, 1);
      ns = 2;
    }
    int cb = 0, sb2 = ns % PIPE;
    for (int tt = 0; tt < nt; ++tt) {
      if (ns > tt + 1) {
        asm volatile("s_waitcnt vmcnt(6)" ::: "memory");
      } else {
        asm volatile("s_waitcnt vmcnt(0)" ::: "memory");
      }
      asm volatile("s_barrier" ::: "memory");
      if (ns < nt) {
        stage(koff + ns * SUB, sb2);
        ++ns;
        sb2 = (sb2 + 1 == PIPE) ? 0 : sb2 + 1;
      }
      compute(cb);
      cb = (cb + 1 == PIPE) ? 0 : cb + 1;
    }
  }

#pragma unroll
  for (int mi = 0; mi < 4; ++mi) {
    int mrow = m_off + mi * 16 + quad * 4;
#pragma unroll
    for (int nj = 0; nj < 4; ++nj) {
      int col = n_off + nj * 16 + fr;
      if (EPIKS == 0) {
#pragma unroll
        for (int i = 0; i < 4; ++i)
          outp[(size_t)(M0 + mrow + i) * 256 + col] = acc[mi][nj][i];
      } else {  // EPIKS 3: bias + relu + bf16 scatter (deconv1)
        float bv = bias[col];
#pragma unroll
        for (int i = 0; i < 4; ++i) {
          int m = M0 + mrow + i;
          float v = fmaxf(acc[mi][nj][i] + bv, 0.f);
          int nn = m >> 6, jj = (m >> 3) & 7, ii = m & 7;
          int oy = 2 * jj + 1 - py, ox = 2 * ii + 1 - px;
          outb[(size_t)((nn << 8) + oy * 16 + ox) * 256 + col] = f2bs(v);
        }
      }
    }
  }
}

// ---------------- K-split epilogue (+ optional fused rmsnorm) --------------
// One block per 64-token sample: v = [res +] relu(sc0+sc1+bias); full-sample
// SSQ known in-block -> NORM>0 normalizes in-kernel and writes NBh(/NBl),
// replacing the separate k_rmsnorm pass. v stashed in LDS (pass2 reads stash,
// so overwriting sc-aliased NB regions is safe). Weights LDS-staged with +1
// pad -> conflict-free [ch][pos] reads. Math identical to k_epi+k_rmsnorm.
template <int RES, int NORM>
__global__ void __launch_bounds__(256) k_epi(const float* __restrict__ sc0,
                                             const float* __restrict__ sc1,
                                             const float* __restrict__ bias,
                                             const float* __restrict__ res,
                                             float* __restrict__ out,
                                             float* __restrict__ ssqp,
                                             const float* __restrict__ rmsw,
                                             ushort_t* __restrict__ NBh,
                                             ushort_t* __restrict__ NBl) {
  __shared__ float red[256];
  __shared__ float st[64 * 256];
  __shared__ float wl[256 * 65];
  int s = blockIdx.x, t = threadIdx.x;
  size_t base = (size_t)s * 16384;
  float bv = bias[t];
  if (NORM) {
    for (int k = 0; k < 64; ++k) {
      int i = k * 256 + t;
      wl[(i >> 6) * 65 + (i & 63)] = rmsw[i];
    }
  }
  float sq = 0.f;
  for (int r = 0; r < 64; ++r) {
    size_t o = base + (size_t)r * 256 + t;
    float v = fmaxf(sc0[o] + sc1[o] + bv, 0.f);
    if (RES) v += res[o];
    out[o] = v;
    st[r * 256 + t] = v;
    sq += v * v;
  }
  red[t] = sq;
  __syncthreads();
  for (int k = 128; k > 0; k >>= 1) {
    if (t < k) red[t] += red[t + k];
    __syncthreads();
  }
  if (t == 0) ssqp[s] = red[0];
  if (NORM) {
    float scale = 1.0f / sqrtf(red[0] / 16384.f + 1.1920929e-07f);
    ushort_t* oh = NBh + base;
    ushort_t* ol = (NORM == 1) ? (NBl + base) : nullptr;
    for (int r = 0; r < 64; ++r) {
      float v = st[r * 256 + t] * scale * wl[t * 65 + r];
      ushort_t h = f2bs(v);
      oh[r * 256 + t] = h;
      if (NORM == 1) ol[r * 256 + t] = f2bs(v - bs2f(h));
    }
  }
}

// ---------------- rmsnorm normalize-only (3 standalone sites) ----------
template <int SPLIT>
__global__ void __launch_bounds__(256) k_rmsnorm(const float* __restrict__ in,
                                                 const float* __restrict__ rmsw,
                                                 const float* __restrict__ ssq,
                                                 ushort_t* __restrict__ NBh,
                                                 ushort_t* __restrict__ NBl) {
  extern __shared__ float wT[];  // 64*257 floats
  int n = blockIdx.x, t = threadIdx.x;
  const float* p = in + (size_t)n * 16384;
  for (int k = 0; k < 64; ++k) {
    int i = k * 256 + t;  // i = c*64 + j
    wT[(i & 63) * 257 + (i >> 6)] = rmsw[i];
  }
  float scale = 1.0f / sqrtf(ssq[n] / 16384.f + 1.1920929e-07f);
  __syncthreads();
  ushort_t* oh = NBh + (size_t)n * 16384;
  ushort_t* ol = NBl + (size_t)n * 16384;
  for (int j = 0; j < 64; ++j) {
    int i = j * 256 + t;
    float v = p[i] * scale * wT[j * 257 + t];
    ushort_t h = f2bs(v);
    oh[i] = h;
    if (SPLIT) ol[i] = f2bs(v - bs2f(h));
  }
}

// ---------------- VQ (unchanged) ----------------
__global__ void __launch_bounds__(256) k_vq(const float* __restrict__ enc,
                                            const float* __restrict__ embT,
                                            const float* __restrict__ emb,
                                            const float* __restrict__ enorm,
                                            float* __restrict__ q, float* __restrict__ sse,
                                            float* __restrict__ ssq4) {
  __shared__ float z[16][256];
  __shared__ float sc[512 * 16];
  __shared__ float bv[16][16];
  __shared__ int bi[16][16];
  __shared__ int idxs[16];
  int T0 = blockIdx.x * 16;
  int t = threadIdx.x;
  for (int j = 0; j < 16; ++j) z[j][t] = enc[(size_t)(T0 + j) * 256 + t];
  __syncthreads();
  float d0[16], d1[16];
#pragma unroll
  for (int j = 0; j < 16; ++j) { d0[j] = 0.f; d1[j] = 0.f; }
  for (int c4 = 0; c4 < 64; ++c4) {
    const float* eb = embT + (size_t)(c4 * 4) * 512 + t;
    float e00 = eb[0], f00 = eb[256];
    float e01 = eb[512], f01 = eb[768];
    float e02 = eb[1024], f02 = eb[1280];
    float e03 = eb[1536], f03 = eb[1792];
#pragma unroll
    for (int j = 0; j < 16; ++j) {
      float4 zv = *(const float4*)&z[j][c4 * 4];
      d0[j] += zv.x * e00 + zv.y * e01 + zv.z * e02 + zv.w * e03;
      d1[j] += zv.x * f00 + zv.y * f01 + zv.z * f02 + zv.w * f03;
    }
  }
  float en0 = enorm[t], en1 = enorm[t + 256];
#pragma unroll
  for (int j = 0; j < 16; ++j) {
    sc[t * 16 + j] = en0 - 2.f * d0[j];
    sc[(t + 256) * 16 + j] = en1 - 2.f * d1[j];
  }
  __syncthreads();
  {
    int j = t & 15, chunk = t >> 4;
    float best = 3.4e38f;
    int bidx = 0;
    int c0 = chunk * 32;
    for (int cc = 0; cc < 32; ++cc) {
      float v = sc[(c0 + cc) * 16 + j];
      if (v < best) { best = v; bidx = c0 + cc; }
    }
    bv[chunk][j] = best;
    bi[chunk][j] = bidx;
  }
  __syncthreads();
  if (t < 16) {
    float best = 3.4e38f;
    int bidx = 0;
    for (int c = 0; c < 16; ++c) {
      float v = bv[c][t];
      if (v < best) { best = v; bidx = bi[c][t]; }
    }
    idxs[t] = bidx;
  }
  __syncthreads();
  float sq = 0.f, sqq = 0.f;
  for (int j = 0; j < 16; ++j) {
    float e = emb[(size_t)idxs[j] * 256 + t];
    q[(size_t)(T0 + j) * 256 + t] = e;
    float d = z[j][t] - e;
    sq += d * d;
    sqq += e * e;
  }
  __syncthreads();
  sc[t] = sq;
  __syncthreads();
  for (int k = 128; k > 0; k >>= 1) {
    if (t < k) sc[t] += sc[t + k];
    __syncthreads();
  }
  if (t == 0) atomicAdd(sse, sc[0]);
  __syncthreads();
  sc[t] = sqq;
  __syncthreads();
  for (int k = 128; k > 0; k >>= 1) {
    if (t < k) sc[t] += sc[t + k];
    __syncthreads();
  }
  if (t == 0) atomicAdd(&ssq4[blockIdx.x >> 2], sc[0]);
}

// ---------------- deconv2 as GEMM (unchanged from r9) ----------------
__global__ void __launch_bounds__(256) k_dec2gemm(const ushort_t* __restrict__ A,
                                                  const ushort_t* __restrict__ BH,
                                                  const ushort_t* __restrict__ BL,
                                                  float* __restrict__ G) {
  __shared__ __align__(16) ushort_t sBH[48 * 256];
  __shared__ __align__(16) ushort_t sBL[48 * 256];
  const int t = threadIdx.x;
  const int w = t >> 6, l = t & 63;
  const int fr = l & 15, quad = l >> 4, quad8 = quad * 8;
  for (int i = t * 8; i < 12288; i += 2048) {
    *(short8v*)(sBH + i) = *(const short8v*)(BH + i);
    *(short8v*)(sBL + i) = *(const short8v*)(BL + i);
  }
  __syncthreads();
  const int tok0 = blockIdx.x * 128 + w * 32;
  f32x4 acc[2][3];
#pragma unroll
  for (int i = 0; i < 2; ++i)
#pragma unroll
    for (int j = 0; j < 3; ++j) acc[i][j] = (f32x4){0.f, 0.f, 0.f, 0.f};
#pragma unroll
  for (int kk = 0; kk < 256; kk += 32) {
    short8v af[2];
#pragma unroll
    for (int mi = 0; mi < 2; ++mi)
      af[mi] = *(const short8v*)(A + (size_t)(tok0 + mi * 16 + fr) * 256 + kk + quad8);
#pragma unroll
    for (int nj = 0; nj < 3; ++nj) {
      short8v bh = *(const short8v*)(sBH + (nj * 16 + fr) * 256 + kk + quad8);
      short8v bl = *(const short8v*)(sBL + (nj * 16 + fr) * 256 + kk + quad8);
#pragma unroll
      for (int mi = 0; mi < 2; ++mi) {
        acc[mi][nj] =
            __builtin_amdgcn_mfma_f32_16x16x32_bf16(af[mi], bh, acc[mi][nj], 0, 0, 0);
        acc[mi][nj] =
            __builtin_amdgcn_mfma_f32_16x16x32_bf16(af[mi], bl, acc[mi][nj], 0, 0, 0);
      }
    }
  }
#pragma unroll
  for (int mi = 0; mi < 2; ++mi) {
    int mrow = mi * 16 + quad * 4;
#pragma unroll
    for (int nj = 0; nj < 3; ++nj) {
      int col = nj * 16 + fr;
#pragma unroll
      for (int i = 0; i < 4; ++i)
        G[(size_t)(tok0 + mrow + i) * 64 + col] = acc[mi][nj][i];
    }
  }
}

// ---------------- deconv2 gather + reconst loss (unchanged) ----------------
__global__ void __launch_bounds__(256) k_dec2gather(const float* __restrict__ G,
                                                    const float* __restrict__ bias,
                                                    const float* __restrict__ x,
                                                    float* __restrict__ dec,
                                                    float* __restrict__ sse) {
  __shared__ float GL[256 * 49];
  __shared__ float red[256];
  int n = blockIdx.x, t = threadIdx.x;
  for (int i = t; i < 12288; i += 256) {
    int r = i / 48, c = i - r * 48;
    GL[r * 49 + c] = G[(size_t)((n << 8) + r) * 64 + c];
  }
  __syncthreads();
  float sq = 0.f;
  for (int rep = 0; rep < 12; ++rep) {
    int o = rep * 256 + t;
    int oc = o >> 10, rem = o & 1023;
    int oy = rem >> 5, ox = rem & 31;
    int py = (oy + 1) & 1, dy = (oy + 1 - py) >> 1;
    int px = (ox + 1) & 1, dx = (ox + 1 - px) >> 1;
    int iy0 = dy - 1, ix0 = dx - 1;
    bool y0 = (unsigned)iy0 < 16u, y1 = (unsigned)dy < 16u;
    bool x0 = (unsigned)ix0 < 16u, x1 = (unsigned)dx < 16u;
    float v = bias[oc];
    if (y0 && x0) v += GL[(iy0 * 16 + ix0) * 49 + ((py + 2) * 4 + px + 2) * 3 + oc];
    if (y0 && x1) v += GL[(iy0 * 16 + dx) * 49 + ((py + 2) * 4 + px) * 3 + oc];
    if (y1 && x0) v += GL[(dy * 16 + ix0) * 49 + (py * 4 + px + 2) * 3 + oc];
    if (y1 && x1) v += GL[(dy * 16 + dx) * 49 + (py * 4 + px) * 3 + oc];
    int oi = ((n * 3 + oc) * 32 + oy) * 32 + ox;
    dec[oi] = v;
    float d = v - x[oi];
    sq += d * d;
  }
  red[t] = sq;
  __syncthreads();
  for (int k = 128; k > 0; k >>= 1) {
    if (t < k) red[t] += red[t + k];
    __syncthreads();
  }
  if (t == 0) atomicAdd(sse, red[0]);
}

__global__ void k_final(const float* __restrict__ acc, float* __restrict__ out) {
  if (threadIdx.x == 0 && blockIdx.x == 0) {
    float vq = acc[0] / 4194304.f;
    float rec = acc[1] / 786432.f;
    out[0] = rec + 2.f * vq;
    out[1] = rec;
    out[2] = vq;
    out[3] = vq;
  }
}

extern "C" void kernel_launch(void* const* d_in, const int* in_sizes, int n_in,
                              void* d_out, int out_size, void* d_ws, size_t ws_size,
                              hipStream_t stream) {
  (void)in_sizes; (void)n_in; (void)out_size; (void)ws_size;
  const float* x = (const float*)d_in[0];
  const float* ew1 = (const float*)d_in[1];
  const float* eb1 = (const float*)d_in[2];
  const float* ew2 = (const float*)d_in[3];
  const float* eb2 = (const float*)d_in[4];
  const float* rmsw = (const float*)d_in[5];
  const float* r3w = (const float*)d_in[6];
  const float* r3b = (const float*)d_in[7];
  const float* r1w = (const float*)d_in[8];
  const float* r1b = (const float*)d_in[9];
  const float* emb = (const float*)d_in[10];
  const float* dw1 = (const float*)d_in[11];
  const float* db1 = (const float*)d_in[12];
  const float* dw2 = (const float*)d_in[13];
  const float* db2 = (const float*)d_in[14];
  float* out = (float*)d_out;

  float* wsf = (float*)d_ws;
  float* P = wsf + OFF_P;
  float* enorm = wsf + OFF_ENORM;
  float* acc = wsf + OFF_ACC;
  float* zrowf = wsf + OFF_ZROW;
  float* embT = wsf + OFF_EMBT;
  float* ssq = wsf + OFF_SSQ;
  ushort_t* WD2H = (ushort_t*)(wsf + OFF_WD2);
  ushort_t* WD2L = WD2H + 12288;
  ushort_t* sb = (ushort_t*)(wsf + OFF_SHORT);
  ushort_t* H1H = sb + SO_H1H;
  ushort_t* H1L = sb + SO_H1L;
  float* Qf = (float*)(sb + SO_H1L);
  ushort_t* NBH = sb + SO_NBH;
  ushort_t* NBL = sb + SO_NBL;
  ushort_t* A1H = NBH;
  ushort_t* A1L = NBL;
  ushort_t* QB = NBL;
  ushort_t* W1H = sb + SO_W1H;
  ushort_t* W1L = sb + SO_W1L;
  ushort_t* W2H = sb + SO_W2H;
  ushort_t* W2L = sb + SO_W2L;
  ushort_t* W3EH = sb + SO_W3EH;
  ushort_t* W3EL = sb + SO_W3EL;
  ushort_t* W3D = sb + SO_W3D;
  ushort_t* W1REH = sb + SO_W1REH;
  ushort_t* W1REL = sb + SO_W1REL;
  ushort_t* W1RD = sb + SO_W1RD;
  ushort_t* WD1 = sb + SO_WD1;
  const ushort_t* zrow = (const ushort_t*)zrowf;
  // K-split scratch (raw fp32 partials), in regions dead at time of use:
  float* NBf = (float*)(sb + SO_NBH);   // conv2 SC0 (A1 consumed by conv1)
  float* H1f = (float*)(sb + SO_H1H);   // res3 SC0 (H1 dead after conv2)
  const size_t RMS_LDS = 64 * 257 * sizeof(float);

  k_prep<<<35443, 256, 0, stream>>>(x, ew1, ew2, r3w, r1w, dw1, dw2, emb,
                                    W1H, W1L, W2H, W2L, W3EH, W3EL, W3D,
                                    W1REH, W1REL, W1RD, WD1, WD2H, WD2L, enorm,
                                    acc, zrowf, embT, ssq, A1H, A1L);

  // conv1 (split, K=64): M=65536 -> 1024 blocks
  k_gemm<0, 4, 1, 0><<<dim3(1024), 512, 0, stream>>>(
      A1H, A1L, W1H, W1L, 64, eb1, nullptr, nullptr, H1H, H1L, zrow, nullptr);

  // conv2 K-split + fused epi/rms (idx0) -> P, NBH/NBL, ssq0
  k_gemmks<1, 1, 0><<<dim3(128, 2), 512, 0, stream>>>(
      H1H, H1L, W2H, W2L, 4096, 2048, NBf, P, nullptr, nullptr, zrow);
  k_epi<0, 1><<<256, 256, 0, stream>>>(NBf, P, eb2, nullptr, P, ssq + 0,
                                       rmsw + 0, NBH, NBL);

  // res3-enc rb0 + fused epi/rms (idx1) -> Qf, NBH/NBL
  k_gemmks<2, 1, 0><<<dim3(128, 2), 512, 0, stream>>>(
      NBH, NBL, W3EH, W3EL, 2304, 1152, H1f, Qf, nullptr, nullptr, zrow);
  k_epi<1, 1><<<256, 256, 0, stream>>>(H1f, Qf, r3b, P, Qf, ssq + 256,
                                       rmsw + 1 * 16384, NBH, NBL);
  // res1-enc rb0 -> P (ssq512); standalone rms idx2 -> NBH/NBL
  k_gemm<0, 2, 1, 1><<<dim3(256), 512, 0, stream>>>(
      NBH, NBL, W1REH, W1REL, 256, r1b, Qf, P, nullptr, nullptr, zrow, ssq + 512);
  k_rmsnorm<1><<<256, 256, RMS_LDS, stream>>>(P, rmsw + 2 * 16384, ssq + 512,
                                              NBH, NBL);
  // res3-enc rb1 + fused epi/rms (idx3)
  k_gemmks<2, 1, 0><<<dim3(128, 2), 512, 0, stream>>>(
      NBH, NBL, W3EH + 589824, W3EL + 589824, 2304, 1152, H1f, Qf, nullptr,
      nullptr, zrow);
  k_epi<1, 1><<<256, 256, 0, stream>>>(H1f, Qf, r3b + 256, P, Qf, ssq + 768,
                                       rmsw + 3 * 16384, NBH, NBL);
  // res1-enc rb1 -> P (no ssq)
  k_gemm<0, 2, 1, 0><<<dim3(256), 512, 0, stream>>>(
      NBH, NBL, W1REH + 65536, W1REL + 65536, 256, r1b + 256, Qf, P, nullptr,
      nullptr, zrow, nullptr);

  // VQ: P -> Qf (q), sse -> acc[0], q-ssq -> slot 4; standalone rms idx4
  k_vq<<<1024, 256, 0, stream>>>(P, embT, emb, enorm, Qf, acc + 0, ssq + 1024);
  k_rmsnorm<0><<<256, 256, RMS_LDS, stream>>>(Qf, rmsw + 4 * 16384, ssq + 1024,
                                              NBH, NBL);

  // res3-dec rb2 + fused epi/rms (idx5, H-only) -> P, NBH
  k_gemmks<2, 0, 0><<<dim3(128, 2), 512, 0, stream>>>(
      NBH, nullptr, W3D, nullptr, 2304, 1152, H1f, P, nullptr, nullptr, zrow);
  k_epi<1, 2><<<256, 256, 0, stream>>>(H1f, P, r3b + 2 * 256, Qf, P, ssq + 1280,
                                       rmsw + 5 * 16384, NBH, nullptr);
  // res1-dec rb2 -> Qf (ssq1536); standalone rms idx6 -> NBH
  k_gemm<0, 2, 0, 1><<<dim3(256), 512, 0, stream>>>(
      NBH, nullptr, W1RD, nullptr, 256, r1b + 2 * 256, P, Qf, nullptr, nullptr,
      zrow, ssq + 1536);
  k_rmsnorm<0><<<256, 256, RMS_LDS, stream>>>(Qf, rmsw + 6 * 16384, ssq + 1536,
                                              NBH, NBL);
  // res3-dec rb3 + fused epi/rms (idx7, H-only) -> P, NBH
  k_gemmks<2, 0, 0><<<dim3(128, 2), 512, 0, stream>>>(
      NBH, nullptr, W3D + 589824, nullptr, 2304, 1152, H1f, P, nullptr, nullptr,
      zrow);
  k_epi<1, 2><<<256, 256, 0, stream>>>(H1f, P, r3b + 3 * 256, Qf, P, ssq + 1792,
                                       rmsw + 7 * 16384, NBH, nullptr);
  // res1-dec rb3 (EPI5) -> Qf + QB
  k_gemm<0, 5, 0, 0><<<dim3(256), 512, 0, stream>>>(
      NBH, nullptr, W1RD + 65536, nullptr, 256, r1b + 3 * 256, P, Qf, QB, nullptr,
      zrow, nullptr);

  // deconv1 (K=1024, 4 parity classes, BM=128, direct bf16 scatter)
  k_gemmks<3, 0, 3><<<dim3(128, 1, 4), 512, 0, stream>>>(
      QB, nullptr, WD1, nullptr, 1024, 1024, nullptr, nullptr, db1, H1H, zrow);

  // deconv2: GEMM (G = tokens x W, 48 cols) + gather/loss. G lives in P.
  k_dec2gemm<<<512, 256, 0, stream>>>(H1H, WD2H, WD2L, P);
  k_dec2gather<<<256, 256, 0, stream>>>(P, db2, x, out + 4, acc + 1);
  k_final<<<1, 64, 0, stream>>>(acc, out);
}

// Round 12
// 793.856 us; speedup vs baseline: 1.4163x; 1.0406x over previous
//
#include <hip/hip_runtime.h>
#include <hip/hip_bf16.h>

typedef unsigned short ushort_t;
typedef __attribute__((ext_vector_type(8))) short short8v;
typedef __attribute__((ext_vector_type(4))) float f32x4;

__device__ __forceinline__ ushort_t f2bs(float v) {
  union { __hip_bfloat16 h; ushort_t u; } cv;
  cv.h = __float2bfloat16(v);
  return cv.u;
}
__device__ __forceinline__ float bs2f(ushort_t u) {
  union { ushort_t u; __hip_bfloat16 h; } cv;
  cv.u = u;
  return __bfloat162float(cv.h);
}

__device__ __forceinline__ void glds16(const ushort_t* g, ushort_t* l) {
  __builtin_amdgcn_global_load_lds(
      (const __attribute__((address_space(1))) unsigned int*)(uintptr_t)g,
      (__attribute__((address_space(3))) unsigned int*)(unsigned int)(uintptr_t)l,
      16, 0, 0);
}

// ---------------- workspace layout ----------------
static constexpr size_t OFF_P = 0;
static constexpr size_t OFF_ENORM = 4194304;
static constexpr size_t OFF_WD2 = 4194816;    // WD2H[12288]+WD2L[12288] ushorts
static constexpr size_t OFF_ACC = 4207360;
static constexpr size_t OFF_ZROW = 4207368;
static constexpr size_t OFF_EMBT = 4207432;   // fp32 embT [c=256][code=512]
static constexpr size_t OFF_SSQ = 4338504;    // 8 slots x 256 samples
static constexpr size_t OFF_SHORT = 4340552;  // 16B aligned (x4 bytes)
static constexpr size_t SO_H1H = 0;
static constexpr size_t SO_H1L = 16777216;
static constexpr size_t SO_NBH = 33554432;
static constexpr size_t SO_NBL = 37748736;
static constexpr size_t SO_W1H = 41943040;
static constexpr size_t SO_W1L = 41959424;
static constexpr size_t SO_W2H = 41975808;
static constexpr size_t SO_W2L = 43024384;
static constexpr size_t SO_W3EH = 44072960;
static constexpr size_t SO_W3EL = 45252608;
static constexpr size_t SO_W3D = 46432256;
static constexpr size_t SO_W1REH = 47611904;
static constexpr size_t SO_W1REL = 47742976;
static constexpr size_t SO_W1RD = 47874048;
static constexpr size_t SO_WD1 = 48005120;

__device__ __forceinline__ void split_store(float v, ushort_t* hi, ushort_t* lo, size_t i) {
  ushort_t h = f2bs(v);
  hi[i] = h;
  lo[i] = f2bs(v - bs2f(h));
}

// ---------------- fused prep (unchanged) ----------------
__global__ void __launch_bounds__(256) k_prep(
    const float* __restrict__ x, const float* __restrict__ ew1,
    const float* __restrict__ ew2, const float* __restrict__ r3w,
    const float* __restrict__ r1w, const float* __restrict__ dw1,
    const float* __restrict__ dw2, const float* __restrict__ emb,
    ushort_t* __restrict__ W1H, ushort_t* __restrict__ W1L,
    ushort_t* __restrict__ W2H, ushort_t* __restrict__ W2L,
    ushort_t* __restrict__ W3EH, ushort_t* __restrict__ W3EL,
    ushort_t* __restrict__ W3D, ushort_t* __restrict__ W1REH,
    ushort_t* __restrict__ W1REL, ushort_t* __restrict__ W1RD,
    ushort_t* __restrict__ WD1, ushort_t* __restrict__ WD2H,
    ushort_t* __restrict__ WD2L,
    float* __restrict__ enorm, float* __restrict__ acc, float* __restrict__ zrow,
    float* __restrict__ embT, float* __restrict__ ssq,
    ushort_t* __restrict__ A1H, ushort_t* __restrict__ A1L) {
  int b = blockIdx.x, t = threadIdx.x;
  if (b < 64) {
    int i = b * 256 + t;
    int oc = i >> 6, k = i & 63;
    float v = 0.f;
    if (k < 48) {
      int tap = k / 3, ic = k - 3 * tap;
      v = ew1[(oc * 3 + ic) * 16 + tap];
    }
    split_store(v, W1H, W1L, i);
  } else if (b < 4160) {
    int i = (b - 64) * 256 + t;
    int oc = i >> 12, k = i & 4095;
    int tap = k >> 8, ic = k & 255;
    split_store(ew2[(oc * 256 + ic) * 16 + tap], W2H, W2L, i);
  } else if (b < 8768) {
    int i = (b - 4160) * 256 + t;
    int rb = i / 589824, r2 = i - rb * 589824;
    int oc = r2 / 2304, k = r2 - oc * 2304;
    int r9 = k >> 8, ic = k & 255;
    split_store(r3w[((rb * 256 + oc) * 256 + ic) * 9 + r9], W3EH, W3EL, i);
  } else if (b < 13376) {
    int i = (b - 8768) * 256 + t;
    int rb = i / 589824, r2 = i - rb * 589824;
    int oc = r2 / 2304, k = r2 - oc * 2304;
    int r9 = k >> 8, ic = k & 255;
    W3D[i] = f2bs(r3w[(((rb + 2) * 256 + oc) * 256 + ic) * 9 + r9]);
  } else if (b < 13888) {
    int i = (b - 13376) * 256 + t;
    split_store(r1w[i], W1REH, W1REL, i);
  } else if (b < 14400) {
    int i = (b - 13888) * 256 + t;
    W1RD[i] = f2bs(r1w[2 * 65536 + i]);
  } else if (b < 18496) {
    int i = (b - 14400) * 256 + t;
    int cls = i >> 18, r2 = i & 262143;
    int oc = r2 >> 10, k = r2 & 1023;
    int tap = k >> 8, ic = k & 255;
    int s = tap >> 1, sx = tap & 1;
    int py = cls >> 1, px = cls & 1;
    int ky = py + 2 - 2 * s, kx = px + 2 - 2 * sx;
    WD1[i] = f2bs(dw1[(ic * 256 + oc) * 16 + ky * 4 + kx]);
  } else if (b < 18544) {
    int i = (b - 18496) * 256 + t;  // [0, 12288)
    int j = i >> 8, ic = i & 255;
    int kyx = j / 3, oc = j - kyx * 3;
    split_store(dw2[(ic * 3 + oc) * 16 + kyx], WD2H, WD2L, (size_t)j * 256 + ic);
  } else if (b < 18546) {
    int e = (b - 18544) * 256 + t;
    float s = 0.f;
    for (int c = 0; c < 256; ++c) {
      float v = emb[e * 256 + c];
      s += v * v;
    }
    enorm[e] = s;
  } else if (b == 18546) {
    if (t < 2) acc[t] = 0.f;
    if (t < 64) zrow[t] = 0.f;
    for (int k = t; k < 2048; k += 256) ssq[k] = 0.f;
  } else if (b < 34931) {
    int i = (b - 18547) * 256 + t;
    int t1 = i >> 6, k = i & 63;
    float v = 0.f;
    if (k < 48) {
      int tap = k / 3, ic = k - 3 * tap;
      int n = t1 >> 8, oy = (t1 >> 4) & 15, ox = t1 & 15;
      int ky = tap >> 2, kx = tap & 3;
      int iy = 2 * oy - 1 + ky, ix = 2 * ox - 1 + kx;
      if ((unsigned)iy < 32u && (unsigned)ix < 32u)
        v = x[((n * 3 + ic) * 32 + iy) * 32 + ix];
    }
    split_store(v, A1H, A1L, i);
  } else {
    int i = (b - 34931) * 256 + t;
    int code = i >> 8, c = i & 255;
    embT[c * 512 + code] = emb[i];
  }
}

// ---------------- MFMA GEMM (BN=256, BM=64, 8 waves, PIPE=3) ----------------
// SSQ: 0 none; 1 atomic ssq per sample; 2 fused rmsnorm (H+L -> outb/outb2);
// 3 fused rmsnorm (H only -> outb). For SSQ>=2, ssqp carries the rms weight
// slice (rmsw[c*64+j]); block = one 64-token sample so the full-sample SSQ
// is reduced in-block (red LDS) and normalization happens in-kernel —
// identical math chain to the standalone k_rmsnorm it replaces.
template <int MODE, int EPI, int STYLE, int SSQ>
__global__ __launch_bounds__(512) void k_gemm(const ushort_t* __restrict__ Ah,
                                              const ushort_t* __restrict__ Al,
                                              const ushort_t* __restrict__ Bh,
                                              const ushort_t* __restrict__ Bl, int K,
                                              const float* __restrict__ bias,
                                              const float* __restrict__ res,
                                              float* __restrict__ outf,
                                              ushort_t* __restrict__ outb,
                                              ushort_t* __restrict__ outb2,
                                              const ushort_t* __restrict__ zrow,
                                              float* __restrict__ ssqp) {
  constexpr int PIPE = 3;
  __shared__ __align__(16) ushort_t A0[PIPE][64 * 32];
  __shared__ __align__(16) ushort_t A1s[PIPE][64 * 32];
  __shared__ __align__(16) ushort_t B0[PIPE][256 * 32];
  __shared__ __align__(16) ushort_t B1[PIPE][256 * 32];
  __shared__ float red[512];
  const int t = threadIdx.x;
  const int w = t >> 6, l = t & 63;
  const int M0 = blockIdx.x * 64;
  int py = 0, px = 0;
  const ushort_t* Bb = Bh;
  if (MODE == 3) {
    int cls = blockIdx.z;
    py = cls >> 1;
    px = cls & 1;
    Bb = Bh + (size_t)cls * 262144;
  }
  const int srow = l & 15, chunk = l >> 4;
  const int fr = l & 15, quad = l >> 4;
  const int m_off = (w & 1) * 32, n_off = (w >> 1) * 64;
  const int mset = (m_off >> 4), nset = (n_off >> 4);

  const int aw = w & 3;
  const bool aH = (w < 4);
  const int atok = M0 + aw * 16 + srow;
  const size_t bb0 = (size_t)(2 * w * 16 + srow) * K + chunk * 8;
  const size_t bb1 = (size_t)((2 * w + 1) * 16 + srow) * K + chunk * 8;

  f32x4 acc[2][4];
#pragma unroll
  for (int i = 0; i < 2; ++i)
#pragma unroll
    for (int j = 0; j < 4; ++j) acc[i][j] = (f32x4){0.f, 0.f, 0.f, 0.f};

  const int n1 = atok >> 6, oy1 = (atok >> 3) & 7, ox1 = atok & 7;
  const ushort_t* zp = zrow + chunk * 8;

  const int SUB = (STYLE == 1) ? 32 : 64;

  size_t r1s = 0;
  bool v1s = true;
  if (MODE == 0) r1s = (size_t)atok * K + chunk * 8;

  auto stage = [&](int kk, int s) {
    const ushort_t* pa;
    if (MODE == 0) {
      size_t o = r1s + kk;
      pa = aH ? (Ah + o) : ((STYLE == 1) ? (Al + o) : (Ah + o + 32));
    } else {
      if ((kk & 255) == 0) {
        int tap = kk >> 8;
        int iy, ix;
        unsigned lim;
        if (MODE == 1) {
          int ky = tap >> 2, kx = tap & 3;
          iy = 2 * oy1 - 1 + ky; ix = 2 * ox1 - 1 + kx;
          lim = 16u;
        } else if (MODE == 2) {
          int ky = tap / 3, kx = tap - ky * 3;
          iy = oy1 - 1 + ky; ix = ox1 - 1 + kx;
          lim = 8u;
        } else {
          int s2 = tap >> 1, sx = tap & 1;
          iy = oy1 + s2 - py; ix = ox1 + sx - px;
          lim = 8u;
        }
        v1s = ((unsigned)iy < lim && (unsigned)ix < lim);
        if (MODE == 1)
          r1s = (size_t)(((n1 << 8) + (iy << 4) + ix)) << 8;
        else
          r1s = (size_t)(((n1 << 6) + (iy << 3) + ix)) << 8;
      }
      int kin = (kk & 255) + chunk * 8;
      if (v1s)
        pa = aH ? (Ah + r1s + kin)
                : ((STYLE == 1) ? (Al + r1s + kin) : (Ah + r1s + kin + 32));
      else
        pa = zp;
    }
    size_t bo0 = bb0 + kk, bo1 = bb1 + kk;
    glds16(pa, (aH ? A0[s] : A1s[s]) + aw * 512);
    glds16(Bb + bo0, B0[s] + (2 * w) * 512);
    glds16(Bb + bo1, B0[s] + (2 * w + 1) * 512);
    glds16((STYLE == 1) ? (Bl + bo0) : (Bb + bo0 + 32), B1[s] + (2 * w) * 512);
    glds16((STYLE == 1) ? (Bl + bo1) : (Bb + bo1 + 32), B1[s] + (2 * w + 1) * 512);
  };

  auto compute = [&](int s) {
    short8v af0[2], af1[2], bf0[4], bf1[4];
#pragma unroll
    for (int mi = 0; mi < 2; ++mi) {
      af0[mi] = *(const short8v*)(A0[s] + (mset + mi) * 512 + quad * 128 + fr * 8);
      af1[mi] = *(const short8v*)(A1s[s] + (mset + mi) * 512 + quad * 128 + fr * 8);
    }
#pragma unroll
    for (int nj = 0; nj < 4; ++nj) {
      bf0[nj] = *(const short8v*)(B0[s] + (nset + nj) * 512 + quad * 128 + fr * 8);
      bf1[nj] = *(const short8v*)(B1[s] + (nset + nj) * 512 + quad * 128 + fr * 8);
    }
#pragma unroll
    for (int mi = 0; mi < 2; ++mi)
#pragma unroll
      for (int nj = 0; nj < 4; ++nj) {
        acc[mi][nj] =
            __builtin_amdgcn_mfma_f32_16x16x32_bf16(af0[mi], bf0[nj], acc[mi][nj], 0, 0, 0);
        if (STYLE == 1) {
          acc[mi][nj] =
              __builtin_amdgcn_mfma_f32_16x16x32_bf16(af1[mi], bf0[nj], acc[mi][nj], 0, 0, 0);
          acc[mi][nj] =
              __builtin_amdgcn_mfma_f32_16x16x32_bf16(af0[mi], bf1[nj], acc[mi][nj], 0, 0, 0);
        } else {
          acc[mi][nj] =
              __builtin_amdgcn_mfma_f32_16x16x32_bf16(af1[mi], bf1[nj], acc[mi][nj], 0, 0, 0);
        }
      }
  };

  {
    const int nt = K / SUB;
    stage(0, 0);
    int ns = 1;
    if (nt > 1) {
      stage(SUB, 1);
      ns = 2;
    }
    int cb = 0, sb2 = ns % PIPE;
    for (int tt = 0; tt < nt; ++tt) {
      if (ns > tt + 1) {
        asm volatile("s_waitcnt vmcnt(5)" ::: "memory");
      } else {
        asm volatile("s_waitcnt vmcnt(0)" ::: "memory");
      }
      asm volatile("s_barrier" ::: "memory");
      if (ns < nt) {
        stage(ns * SUB, sb2);
        ++ns;
        sb2 = (sb2 + 1 == PIPE) ? 0 : sb2 + 1;
      }
      compute(cb);
      cb = (cb + 1 == PIPE) ? 0 : cb + 1;
    }
  }

  float sq = 0.f;
#pragma unroll
  for (int mi = 0; mi < 2; ++mi) {
    int mrow = m_off + mi * 16 + quad * 4;
#pragma unroll
    for (int nj = 0; nj < 4; ++nj) {
      int col = n_off + nj * 16 + fr;
      float bv = bias[col];
#pragma unroll
      for (int i = 0; i < 4; ++i) {
        int m = M0 + mrow + i;
        float v = fmaxf(acc[mi][nj][i] + bv, 0.f);
        if (EPI == 1) {
          outf[(size_t)m * 256 + col] = v;
          if (SSQ) sq += v * v;
        } else if (EPI == 2) {
          size_t o = (size_t)m * 256 + col;
          float vv = res[o] + v;
          outf[o] = vv;
          if (SSQ) sq += vv * vv;
          if (SSQ >= 2) acc[mi][nj][i] = vv;  // stash for fused norm pass
        } else if (EPI == 3) {
          int nn = m >> 6, jj = (m >> 3) & 7, ii = m & 7;
          int oy = 2 * jj + 1 - py, ox = 2 * ii + 1 - px;
          outb[(size_t)((nn << 8) + oy * 16 + ox) * 256 + col] = f2bs(v);
        } else if (EPI == 4) {
          size_t o = (size_t)m * 256 + col;
          ushort_t h = f2bs(v);
          outb[o] = h;
          outb2[o] = f2bs(v - bs2f(h));
        } else {  // EPI 5
          size_t o = (size_t)m * 256 + col;
          float vv = res[o] + v;
          outf[o] = vv;
          outb[o] = f2bs(vv);
        }
      }
    }
  }
  if (SSQ == 1) {
#pragma unroll
    for (int off = 32; off > 0; off >>= 1) sq += __shfl_down(sq, off, 64);
    if (l == 0) atomicAdd(&ssqp[M0 >> 6], sq);
  } else if (SSQ >= 2) {
    // block = one sample: reduce full-sample ssq, then normalize in-kernel
    red[t] = sq;
    __syncthreads();
    for (int k = 256; k > 0; k >>= 1) {
      if (t < k) red[t] += red[t + k];
      __syncthreads();
    }
    float scale = 1.0f / sqrtf(red[0] / 16384.f + 1.1920929e-07f);
    const float* rw = ssqp;  // rms weight slice [c*64 + j]
#pragma unroll
    for (int mi = 0; mi < 2; ++mi) {
      int mrow = m_off + mi * 16 + quad * 4;
#pragma unroll
      for (int nj = 0; nj < 4; ++nj) {
        int col = n_off + nj * 16 + fr;
#pragma unroll
        for (int i = 0; i < 4; ++i) {
          int m = M0 + mrow + i;
          float v = acc[mi][nj][i] * scale * rw[col * 64 + (m & 63)];
          ushort_t h = f2bs(v);
          size_t o = (size_t)m * 256 + col;
          outb[o] = h;
          if (SSQ == 2) outb2[o] = f2bs(v - bs2f(h));
        }
      }
    }
  }
}

// ---------------- K-split / wide MFMA GEMM (BM=128, BN=256) ----------------
template <int MODE, int STYLE, int EPIKS>
__global__ __launch_bounds__(512) void k_gemmks(const ushort_t* __restrict__ Ah,
                                                const ushort_t* __restrict__ Al,
                                                const ushort_t* __restrict__ Bh,
                                                const ushort_t* __restrict__ Bl,
                                                int K, int KH,
                                                float* __restrict__ sc0,
                                                float* __restrict__ sc1,
                                                const float* __restrict__ bias,
                                                ushort_t* __restrict__ outb,
                                                const ushort_t* __restrict__ zrow) {
  constexpr int PIPE = 3;
  __shared__ __align__(16) ushort_t A0[PIPE][128 * 32];
  __shared__ __align__(16) ushort_t A1s[PIPE][128 * 32];
  __shared__ __align__(16) ushort_t B0[PIPE][256 * 32];
  __shared__ __align__(16) ushort_t B1[PIPE][256 * 32];
  const int t = threadIdx.x;
  const int w = t >> 6, l = t & 63;
  const int M0 = blockIdx.x * 128;
  const int koff = blockIdx.y * KH;
  float* outp = blockIdx.y ? sc1 : sc0;
  int py = 0, px = 0;
  const ushort_t* Bb = Bh;
  if (MODE == 3) {
    int cls = blockIdx.z;
    py = cls >> 1;
    px = cls & 1;
    Bb = Bh + (size_t)cls * 262144;
  }
  const int srow = l & 15, chunk = l >> 4;
  const int fr = l & 15, quad = l >> 4;
  const int m_off = (w & 1) * 64, n_off = (w >> 1) * 64;
  const int mset = m_off >> 4, nset = n_off >> 4;

  const int atok = M0 + w * 16 + srow;
  const size_t bb0 = (size_t)(2 * w * 16 + srow) * K + chunk * 8;
  const size_t bb1 = (size_t)((2 * w + 1) * 16 + srow) * K + chunk * 8;

  f32x4 acc[4][4];
#pragma unroll
  for (int i = 0; i < 4; ++i)
#pragma unroll
    for (int j = 0; j < 4; ++j) acc[i][j] = (f32x4){0.f, 0.f, 0.f, 0.f};

  const int n1 = atok >> 6, oy1 = (atok >> 3) & 7, ox1 = atok & 7;
  const ushort_t* zp = zrow + chunk * 8;
  const int SUB = (STYLE == 1) ? 32 : 64;

  size_t r1s = 0;
  bool v1s = true;
  if (MODE == 0) r1s = (size_t)atok * K + chunk * 8;

  auto stage = [&](int kk, int s) {
    const ushort_t *pa, *pa2;
    if (MODE == 0) {
      size_t o = r1s + kk;
      pa = Ah + o;
      pa2 = (STYLE == 1) ? (Al + o) : (Ah + o + 32);
    } else {
      if ((kk & 255) == 0 || kk == koff) {  // koff may start mid-tap
        int tap = kk >> 8;
        int iy, ix;
        unsigned lim;
        if (MODE == 1) {
          int ky = tap >> 2, kx = tap & 3;
          iy = 2 * oy1 - 1 + ky; ix = 2 * ox1 - 1 + kx;
          lim = 16u;
        } else if (MODE == 2) {
          int ky = tap / 3, kx = tap - ky * 3;
          iy = oy1 - 1 + ky; ix = ox1 - 1 + kx;
          lim = 8u;
        } else {  // MODE 3
          int s2 = tap >> 1, sx = tap & 1;
          iy = oy1 + s2 - py; ix = ox1 + sx - px;
          lim = 8u;
        }
        v1s = ((unsigned)iy < lim && (unsigned)ix < lim);
        if (MODE == 1)
          r1s = (size_t)(((n1 << 8) + (iy << 4) + ix)) << 8;
        else
          r1s = (size_t)(((n1 << 6) + (iy << 3) + ix)) << 8;
      }
      int kin = (kk & 255) + chunk * 8;
      if (v1s) {
        pa = Ah + r1s + kin;
        pa2 = (STYLE == 1) ? (Al + r1s + kin) : (Ah + r1s + kin + 32);
      } else {
        pa = zp;
        pa2 = zp;
      }
    }
    size_t bo0 = bb0 + kk, bo1 = bb1 + kk;
    glds16(pa, A0[s] + w * 512);
    glds16(pa2, A1s[s] + w * 512);
    glds16(Bb + bo0, B0[s] + (2 * w) * 512);
    glds16(Bb + bo1, B0[s] + (2 * w + 1) * 512);
    glds16((STYLE == 1) ? (Bl + bo0) : (Bb + bo0 + 32), B1[s] + (2 * w) * 512);
    glds16((STYLE == 1) ? (Bl + bo1) : (Bb + bo1 + 32), B1[s] + (2 * w + 1) * 512);
  };

  auto compute = [&](int s) {
    short8v af0[4], af1[4], bf0[4], bf1[4];
#pragma unroll
    for (int mi = 0; mi < 4; ++mi) {
      af0[mi] = *(const short8v*)(A0[s] + (mset + mi) * 512 + quad * 128 + fr * 8);
      af1[mi] = *(const short8v*)(A1s[s] + (mset + mi) * 512 + quad * 128 + fr * 8);
    }
#pragma unroll
    for (int nj = 0; nj < 4; ++nj) {
      bf0[nj] = *(const short8v*)(B0[s] + (nset + nj) * 512 + quad * 128 + fr * 8);
      bf1[nj] = *(const short8v*)(B1[s] + (nset + nj) * 512 + quad * 128 + fr * 8);
    }
#pragma unroll
    for (int mi = 0; mi < 4; ++mi)
#pragma unroll
      for (int nj = 0; nj < 4; ++nj) {
        acc[mi][nj] =
            __builtin_amdgcn_mfma_f32_16x16x32_bf16(af0[mi], bf0[nj], acc[mi][nj], 0, 0, 0);
        if (STYLE == 1) {
          acc[mi][nj] =
              __builtin_amdgcn_mfma_f32_16x16x32_bf16(af1[mi], bf0[nj], acc[mi][nj], 0, 0, 0);
          acc[mi][nj] =
              __builtin_amdgcn_mfma_f32_16x16x32_bf16(af0[mi], bf1[nj], acc[mi][nj], 0, 0, 0);
        } else {
          acc[mi][nj] =
              __builtin_amdgcn_mfma_f32_16x16x32_bf16(af1[mi], bf1[nj], acc[mi][nj], 0, 0, 0);
        }
      }
  };

  {
    const int nt = KH / SUB;
    stage(koff, 0);
    int ns = 1;
    if (nt > 1) {
      stage(koff + SUB, 1);
      ns = 2;
    }
    int cb = 0, sb2 = ns % PIPE;
    for (int tt = 0; tt < nt; ++tt) {
      if (ns > tt + 1) {
        asm volatile("s_waitcnt vmcnt(6)" ::: "memory");
      } else {
        asm volatile("s_waitcnt vmcnt(0)" ::: "memory");
      }
      asm volatile("s_barrier" ::: "memory");
      if (ns < nt) {
        stage(koff + ns * SUB, sb2);
        ++ns;
        sb2 = (sb2 + 1 == PIPE) ? 0 : sb2 + 1;
      }
      compute(cb);
      cb = (cb + 1 == PIPE) ? 0 : cb + 1;
    }
  }

#pragma unroll
  for (int mi = 0; mi < 4; ++mi) {
    int mrow = m_off + mi * 16 + quad * 4;
#pragma unroll
    for (int nj = 0; nj < 4; ++nj) {
      int col = n_off + nj * 16 + fr;
      if (EPIKS == 0) {
#pragma unroll
        for (int i = 0; i < 4; ++i)
          outp[(size_t)(M0 + mrow + i) * 256 + col] = acc[mi][nj][i];
      } else {  // EPIKS 3: bias + relu + bf16 scatter (deconv1)
        float bv = bias[col];
#pragma unroll
        for (int i = 0; i < 4; ++i) {
          int m = M0 + mrow + i;
          float v = fmaxf(acc[mi][nj][i] + bv, 0.f);
          int nn = m >> 6, jj = (m >> 3) & 7, ii = m & 7;
          int oy = 2 * jj + 1 - py, ox = 2 * ii + 1 - px;
          outb[(size_t)((nn << 8) + oy * 16 + ox) * 256 + col] = f2bs(v);
        }
      }
    }
  }
}

// ---------------- K-split epilogue (+ optional fused rmsnorm) --------------
// One block per sample. Pass 2 re-reads out[] (L2-hot, each thread reads
// exactly what it wrote -> no extra barrier) instead of a 64 KB LDS stash:
// LDS 131->66 KB, 2 blocks/CU (r11's fusion was occupancy-starved).
template <int RES, int NORM>
__global__ void __launch_bounds__(256) k_epi(const float* __restrict__ sc0,
                                             const float* __restrict__ sc1,
                                             const float* __restrict__ bias,
                                             const float* __restrict__ res,
                                             float* __restrict__ out,
                                             float* __restrict__ ssqp,
                                             const float* __restrict__ rmsw,
                                             ushort_t* __restrict__ NBh,
                                             ushort_t* __restrict__ NBl) {
  __shared__ float red[256];
  __shared__ float wl[256 * 65];
  int s = blockIdx.x, t = threadIdx.x;
  size_t base = (size_t)s * 16384;
  float bv = bias[t];
  if (NORM) {
    for (int k = 0; k < 64; ++k) {
      int i = k * 256 + t;
      wl[(i >> 6) * 65 + (i & 63)] = rmsw[i];
    }
  }
  float sq = 0.f;
  for (int r = 0; r < 64; ++r) {
    size_t o = base + (size_t)r * 256 + t;
    float v = fmaxf(sc0[o] + sc1[o] + bv, 0.f);
    if (RES) v += res[o];
    out[o] = v;
    sq += v * v;
  }
  red[t] = sq;
  __syncthreads();
  for (int k = 128; k > 0; k >>= 1) {
    if (t < k) red[t] += red[t + k];
    __syncthreads();
  }
  if (t == 0) ssqp[s] = red[0];
  if (NORM) {
    float scale = 1.0f / sqrtf(red[0] / 16384.f + 1.1920929e-07f);
    ushort_t* oh = NBh + base;
    ushort_t* ol = (NORM == 1) ? (NBl + base) : nullptr;
    for (int r = 0; r < 64; ++r) {
      size_t o = base + (size_t)r * 256 + t;
      float v = out[o] * scale * wl[t * 65 + r];
      ushort_t h = f2bs(v);
      oh[r * 256 + t] = h;
      if (NORM == 1) ol[r * 256 + t] = f2bs(v - bs2f(h));
    }
  }
}

// ---------------- rmsnorm normalize-only (1 standalone site: after VQ) ------
template <int SPLIT>
__global__ void __launch_bounds__(256) k_rmsnorm(const float* __restrict__ in,
                                                 const float* __restrict__ rmsw,
                                                 const float* __restrict__ ssq,
                                                 ushort_t* __restrict__ NBh,
                                                 ushort_t* __restrict__ NBl) {
  extern __shared__ float wT[];  // 64*257 floats
  int n = blockIdx.x, t = threadIdx.x;
  const float* p = in + (size_t)n * 16384;
  for (int k = 0; k < 64; ++k) {
    int i = k * 256 + t;  // i = c*64 + j
    wT[(i & 63) * 257 + (i >> 6)] = rmsw[i];
  }
  float scale = 1.0f / sqrtf(ssq[n] / 16384.f + 1.1920929e-07f);
  __syncthreads();
  ushort_t* oh = NBh + (size_t)n * 16384;
  ushort_t* ol = NBl + (size_t)n * 16384;
  for (int j = 0; j < 64; ++j) {
    int i = j * 256 + t;
    float v = p[i] * scale * wT[j * 257 + t];
    ushort_t h = f2bs(v);
    oh[i] = h;
    if (SPLIT) ol[i] = f2bs(v - bs2f(h));
  }
}

// ---------------- VQ (unchanged) ----------------
__global__ void __launch_bounds__(256) k_vq(const float* __restrict__ enc,
                                            const float* __restrict__ embT,
                                            const float* __restrict__ emb,
                                            const float* __restrict__ enorm,
                                            float* __restrict__ q, float* __restrict__ sse,
                                            float* __restrict__ ssq4) {
  __shared__ float z[16][256];
  __shared__ float sc[512 * 16];
  __shared__ float bv[16][16];
  __shared__ int bi[16][16];
  __shared__ int idxs[16];
  int T0 = blockIdx.x * 16;
  int t = threadIdx.x;
  for (int j = 0; j < 16; ++j) z[j][t] = enc[(size_t)(T0 + j) * 256 + t];
  __syncthreads();
  float d0[16], d1[16];
#pragma unroll
  for (int j = 0; j < 16; ++j) { d0[j] = 0.f; d1[j] = 0.f; }
  for (int c4 = 0; c4 < 64; ++c4) {
    const float* eb = embT + (size_t)(c4 * 4) * 512 + t;
    float e00 = eb[0], f00 = eb[256];
    float e01 = eb[512], f01 = eb[768];
    float e02 = eb[1024], f02 = eb[1280];
    float e03 = eb[1536], f03 = eb[1792];
#pragma unroll
    for (int j = 0; j < 16; ++j) {
      float4 zv = *(const float4*)&z[j][c4 * 4];
      d0[j] += zv.x * e00 + zv.y * e01 + zv.z * e02 + zv.w * e03;
      d1[j] += zv.x * f00 + zv.y * f01 + zv.z * f02 + zv.w * f03;
    }
  }
  float en0 = enorm[t], en1 = enorm[t + 256];
#pragma unroll
  for (int j = 0; j < 16; ++j) {
    sc[t * 16 + j] = en0 - 2.f * d0[j];
    sc[(t + 256) * 16 + j] = en1 - 2.f * d1[j];
  }
  __syncthreads();
  {
    int j = t & 15, chunk = t >> 4;
    float best = 3.4e38f;
    int bidx = 0;
    int c0 = chunk * 32;
    for (int cc = 0; cc < 32; ++cc) {
      float v = sc[(c0 + cc) * 16 + j];
      if (v < best) { best = v; bidx = c0 + cc; }
    }
    bv[chunk][j] = best;
    bi[chunk][j] = bidx;
  }
  __syncthreads();
  if (t < 16) {
    float best = 3.4e38f;
    int bidx = 0;
    for (int c = 0; c < 16; ++c) {
      float v = bv[c][t];
      if (v < best) { best = v; bidx = bi[c][t]; }
    }
    idxs[t] = bidx;
  }
  __syncthreads();
  float sq = 0.f, sqq = 0.f;
  for (int j = 0; j < 16; ++j) {
    float e = emb[(size_t)idxs[j] * 256 + t];
    q[(size_t)(T0 + j) * 256 + t] = e;
    float d = z[j][t] - e;
    sq += d * d;
    sqq += e * e;
  }
  __syncthreads();
  sc[t] = sq;
  __syncthreads();
  for (int k = 128; k > 0; k >>= 1) {
    if (t < k) sc[t] += sc[t + k];
    __syncthreads();
  }
  if (t == 0) atomicAdd(sse, sc[0]);
  __syncthreads();
  sc[t] = sqq;
  __syncthreads();
  for (int k = 128; k > 0; k >>= 1) {
    if (t < k) sc[t] += sc[t + k];
    __syncthreads();
  }
  if (t == 0) atomicAdd(&ssq4[blockIdx.x >> 2], sc[0]);
}

// ---------------- deconv2 as GEMM (unchanged) ----------------
__global__ void __launch_bounds__(256) k_dec2gemm(const ushort_t* __restrict__ A,
                                                  const ushort_t* __restrict__ BH,
                                                  const ushort_t* __restrict__ BL,
                                                  float* __restrict__ G) {
  __shared__ __align__(16) ushort_t sBH[48 * 256];
  __shared__ __align__(16) ushort_t sBL[48 * 256];
  const int t = threadIdx.x;
  const int w = t >> 6, l = t & 63;
  const int fr = l & 15, quad = l >> 4, quad8 = quad * 8;
  for (int i = t * 8; i < 12288; i += 2048) {
    *(short8v*)(sBH + i) = *(const short8v*)(BH + i);
    *(short8v*)(sBL + i) = *(const short8v*)(BL + i);
  }
  __syncthreads();
  const int tok0 = blockIdx.x * 128 + w * 32;
  f32x4 acc[2][3];
#pragma unroll
  for (int i = 0; i < 2; ++i)
#pragma unroll
    for (int j = 0; j < 3; ++j) acc[i][j] = (f32x4){0.f, 0.f, 0.f, 0.f};
#pragma unroll
  for (int kk = 0; kk < 256; kk += 32) {
    short8v af[2];
#pragma unroll
    for (int mi = 0; mi < 2; ++mi)
      af[mi] = *(const short8v*)(A + (size_t)(tok0 + mi * 16 + fr) * 256 + kk + quad8);
#pragma unroll
    for (int nj = 0; nj < 3; ++nj) {
      short8v bh = *(const short8v*)(sBH + (nj * 16 + fr) * 256 + kk + quad8);
      short8v bl = *(const short8v*)(sBL + (nj * 16 + fr) * 256 + kk + quad8);
#pragma unroll
      for (int mi = 0; mi < 2; ++mi) {
        acc[mi][nj] =
            __builtin_amdgcn_mfma_f32_16x16x32_bf16(af[mi], bh, acc[mi][nj], 0, 0, 0);
        acc[mi][nj] =
            __builtin_amdgcn_mfma_f32_16x16x32_bf16(af[mi], bl, acc[mi][nj], 0, 0, 0);
      }
    }
  }
#pragma unroll
  for (int mi = 0; mi < 2; ++mi) {
    int mrow = mi * 16 + quad * 4;
#pragma unroll
    for (int nj = 0; nj < 3; ++nj) {
      int col = nj * 16 + fr;
#pragma unroll
      for (int i = 0; i < 4; ++i)
        G[(size_t)(tok0 + mrow + i) * 64 + col] = acc[mi][nj][i];
    }
  }
}

// ---------------- deconv2 gather + reconst loss (unchanged) ----------------
__global__ void __launch_bounds__(256) k_dec2gather(const float* __restrict__ G,
                                                    const float* __restrict__ bias,
                                                    const float* __restrict__ x,
                                                    float* __restrict__ dec,
                                                    float* __restrict__ sse) {
  __shared__ float GL[256 * 49];
  __shared__ float red[256];
  int n = blockIdx.x, t = threadIdx.x;
  for (int i = t; i < 12288; i += 256) {
    int r = i / 48, c = i - r * 48;
    GL[r * 49 + c] = G[(size_t)((n << 8) + r) * 64 + c];
  }
  __syncthreads();
  float sq = 0.f;
  for (int rep = 0; rep < 12; ++rep) {
    int o = rep * 256 + t;
    int oc = o >> 10, rem = o & 1023;
    int oy = rem >> 5, ox = rem & 31;
    int py = (oy + 1) & 1, dy = (oy + 1 - py) >> 1;
    int px = (ox + 1) & 1, dx = (ox + 1 - px) >> 1;
    int iy0 = dy - 1, ix0 = dx - 1;
    bool y0 = (unsigned)iy0 < 16u, y1 = (unsigned)dy < 16u;
    bool x0 = (unsigned)ix0 < 16u, x1 = (unsigned)dx < 16u;
    float v = bias[oc];
    if (y0 && x0) v += GL[(iy0 * 16 + ix0) * 49 + ((py + 2) * 4 + px + 2) * 3 + oc];
    if (y0 && x1) v += GL[(iy0 * 16 + dx) * 49 + ((py + 2) * 4 + px) * 3 + oc];
    if (y1 && x0) v += GL[(dy * 16 + ix0) * 49 + (py * 4 + px + 2) * 3 + oc];
    if (y1 && x1) v += GL[(dy * 16 + dx) * 49 + (py * 4 + px) * 3 + oc];
    int oi = ((n * 3 + oc) * 32 + oy) * 32 + ox;
    dec[oi] = v;
    float d = v - x[oi];
    sq += d * d;
  }
  red[t] = sq;
  __syncthreads();
  for (int k = 128; k > 0; k >>= 1) {
    if (t < k) red[t] += red[t + k];
    __syncthreads();
  }
  if (t == 0) atomicAdd(sse, red[0]);
}

__global__ void k_final(const float* __restrict__ acc, float* __restrict__ out) {
  if (threadIdx.x == 0 && blockIdx.x == 0) {
    float vq = acc[0] / 4194304.f;
    float rec = acc[1] / 786432.f;
    out[0] = rec + 2.f * vq;
    out[1] = rec;
    out[2] = vq;
    out[3] = vq;
  }
}

extern "C" void kernel_launch(void* const* d_in, const int* in_sizes, int n_in,
                              void* d_out, int out_size, void* d_ws, size_t ws_size,
                              hipStream_t stream) {
  (void)in_sizes; (void)n_in; (void)out_size; (void)ws_size;
  const float* x = (const float*)d_in[0];
  const float* ew1 = (const float*)d_in[1];
  const float* eb1 = (const float*)d_in[2];
  const float* ew2 = (const float*)d_in[3];
  const float* eb2 = (const float*)d_in[4];
  const float* rmsw = (const float*)d_in[5];
  const float* r3w = (const float*)d_in[6];
  const float* r3b = (const float*)d_in[7];
  const float* r1w = (const float*)d_in[8];
  const float* r1b = (const float*)d_in[9];
  const float* emb = (const float*)d_in[10];
  const float* dw1 = (const float*)d_in[11];
  const float* db1 = (const float*)d_in[12];
  const float* dw2 = (const float*)d_in[13];
  const float* db2 = (const float*)d_in[14];
  float* out = (float*)d_out;

  float* wsf = (float*)d_ws;
  float* P = wsf + OFF_P;
  float* enorm = wsf + OFF_ENORM;
  float* acc = wsf + OFF_ACC;
  float* zrowf = wsf + OFF_ZROW;
  float* embT = wsf + OFF_EMBT;
  float* ssq = wsf + OFF_SSQ;
  ushort_t* WD2H = (ushort_t*)(wsf + OFF_WD2);
  ushort_t* WD2L = WD2H + 12288;
  ushort_t* sb = (ushort_t*)(wsf + OFF_SHORT);
  ushort_t* H1H = sb + SO_H1H;
  ushort_t* H1L = sb + SO_H1L;
  float* Qf = (float*)(sb + SO_H1L);
  ushort_t* NBH = sb + SO_NBH;
  ushort_t* NBL = sb + SO_NBL;
  ushort_t* A1H = NBH;
  ushort_t* A1L = NBL;
  ushort_t* QB = NBL;
  ushort_t* W1H = sb + SO_W1H;
  ushort_t* W1L = sb + SO_W1L;
  ushort_t* W2H = sb + SO_W2H;
  ushort_t* W2L = sb + SO_W2L;
  ushort_t* W3EH = sb + SO_W3EH;
  ushort_t* W3EL = sb + SO_W3EL;
  ushort_t* W3D = sb + SO_W3D;
  ushort_t* W1REH = sb + SO_W1REH;
  ushort_t* W1REL = sb + SO_W1REL;
  ushort_t* W1RD = sb + SO_W1RD;
  ushort_t* WD1 = sb + SO_WD1;
  const ushort_t* zrow = (const ushort_t*)zrowf;
  float* NBf = (float*)(sb + SO_NBH);   // conv2 SC0 (A1 consumed by conv1)
  float* H1f = (float*)(sb + SO_H1H);   // res3 SC0 (H1 dead after conv2)
  const size_t RMS_LDS = 64 * 257 * sizeof(float);

  k_prep<<<35443, 256, 0, stream>>>(x, ew1, ew2, r3w, r1w, dw1, dw2, emb,
                                    W1H, W1L, W2H, W2L, W3EH, W3EL, W3D,
                                    W1REH, W1REL, W1RD, WD1, WD2H, WD2L, enorm,
                                    acc, zrowf, embT, ssq, A1H, A1L);

  // conv1 (split, K=64): M=65536 -> 1024 blocks
  k_gemm<0, 4, 1, 0><<<dim3(1024), 512, 0, stream>>>(
      A1H, A1L, W1H, W1L, 64, eb1, nullptr, nullptr, H1H, H1L, zrow, nullptr);

  // conv2 K-split + fused epi/rms (idx0) -> P, NBH/NBL, ssq0
  k_gemmks<1, 1, 0><<<dim3(128, 2), 512, 0, stream>>>(
      H1H, H1L, W2H, W2L, 4096, 2048, NBf, P, nullptr, nullptr, zrow);
  k_epi<0, 1><<<256, 256, 0, stream>>>(NBf, P, eb2, nullptr, P, ssq + 0,
                                       rmsw + 0, NBH, NBL);

  // res3-enc rb0 + fused epi/rms (idx1) -> Qf, NBH/NBL
  k_gemmks<2, 1, 0><<<dim3(128, 2), 512, 0, stream>>>(
      NBH, NBL, W3EH, W3EL, 2304, 1152, H1f, Qf, nullptr, nullptr, zrow);
  k_epi<1, 1><<<256, 256, 0, stream>>>(H1f, Qf, r3b, P, Qf, ssq + 256,
                                       rmsw + 1 * 16384, NBH, NBL);
  // res1-enc rb0 -> P, fused rms idx2 -> NBH/NBL (SSQ=2)
  k_gemm<0, 2, 1, 2><<<dim3(256), 512, 0, stream>>>(
      NBH, NBL, W1REH, W1REL, 256, r1b, Qf, P, NBH, NBL, zrow,
      (float*)(rmsw + 2 * 16384));
  // res3-enc rb1 + fused epi/rms (idx3)
  k_gemmks<2, 1, 0><<<dim3(128, 2), 512, 0, stream>>>(
      NBH, NBL, W3EH + 589824, W3EL + 589824, 2304, 1152, H1f, Qf, nullptr,
      nullptr, zrow);
  k_epi<1, 1><<<256, 256, 0, stream>>>(H1f, Qf, r3b + 256, P, Qf, ssq + 768,
                                       rmsw + 3 * 16384, NBH, NBL);
  // res1-enc rb1 -> P (no ssq)
  k_gemm<0, 2, 1, 0><<<dim3(256), 512, 0, stream>>>(
      NBH, NBL, W1REH + 65536, W1REL + 65536, 256, r1b + 256, Qf, P, nullptr,
      nullptr, zrow, nullptr);

  // VQ: P -> Qf (q), sse -> acc[0], q-ssq -> slot 4; standalone rms idx4
  k_vq<<<1024, 256, 0, stream>>>(P, embT, emb, enorm, Qf, acc + 0, ssq + 1024);
  k_rmsnorm<0><<<256, 256, RMS_LDS, stream>>>(Qf, rmsw + 4 * 16384, ssq + 1024,
                                              NBH, NBL);

  // res3-dec rb2 + fused epi/rms (idx5, H-only) -> P, NBH
  k_gemmks<2, 0, 0><<<dim3(128, 2), 512, 0, stream>>>(
      NBH, nullptr, W3D, nullptr, 2304, 1152, H1f, P, nullptr, nullptr, zrow);
  k_epi<1, 2><<<256, 256, 0, stream>>>(H1f, P, r3b + 2 * 256, Qf, P, ssq + 1280,
                                       rmsw + 5 * 16384, NBH, nullptr);
  // res1-dec rb2 -> Qf, fused rms idx6 -> NBH (SSQ=3, H only)
  k_gemm<0, 2, 0, 3><<<dim3(256), 512, 0, stream>>>(
      NBH, nullptr, W1RD, nullptr, 256, r1b + 2 * 256, P, Qf, NBH, nullptr,
      zrow, (float*)(rmsw + 6 * 16384));
  // res3-dec rb3 + fused epi/rms (idx7, H-only) -> P, NBH
  k_gemmks<2, 0, 0><<<dim3(128, 2), 512, 0, stream>>>(
      NBH, nullptr, W3D + 589824, nullptr, 2304, 1152, H1f, P, nullptr, nullptr,
      zrow);
  k_epi<1, 2><<<256, 256, 0, stream>>>(H1f, P, r3b + 3 * 256, Qf, P, ssq + 1792,
                                       rmsw + 7 * 16384, NBH, nullptr);
  // res1-dec rb3 (EPI5) -> Qf + QB
  k_gemm<0, 5, 0, 0><<<dim3(256), 512, 0, stream>>>(
      NBH, nullptr, W1RD + 65536, nullptr, 256, r1b + 3 * 256, P, Qf, QB, nullptr,
      zrow, nullptr);

  // deconv1 (K=1024, 4 parity classes, BM=128, direct bf16 scatter)
  k_gemmks<3, 0, 3><<<dim3(128, 1, 4), 512, 0, stream>>>(
      QB, nullptr, WD1, nullptr, 1024, 1024, nullptr, nullptr, db1, H1H, zrow);

  // deconv2: GEMM (G = tokens x W, 48 cols) + gather/loss. G lives in P.
  k_dec2gemm<<<512, 256, 0, stream>>>(H1H, WD2H, WD2L, P);
  k_dec2gather<<<256, 256, 0, stream>>>(P, db2, x, out + 4, acc + 1);
  k_final<<<1, 64, 0, stream>>>(acc, out);
}

// Round 13
// 783.143 us; speedup vs baseline: 1.4356x; 1.0137x over previous
//
#include <hip/hip_runtime.h>
#include <hip/hip_bf16.h>

typedef unsigned short ushort_t;
typedef __attribute__((ext_vector_type(8))) short short8v;
typedef __attribute__((ext_vector_type(4))) float f32x4;

__device__ __forceinline__ ushort_t f2bs(float v) {
  union { __hip_bfloat16 h; ushort_t u; } cv;
  cv.h = __float2bfloat16(v);
  return cv.u;
}
__device__ __forceinline__ float bs2f(ushort_t u) {
  union { ushort_t u; __hip_bfloat16 h; } cv;
  cv.u = u;
  return __bfloat162float(cv.h);
}

__device__ __forceinline__ void glds16(const ushort_t* g, ushort_t* l) {
  __builtin_amdgcn_global_load_lds(
      (const __attribute__((address_space(1))) unsigned int*)(uintptr_t)g,
      (__attribute__((address_space(3))) unsigned int*)(unsigned int)(uintptr_t)l,
      16, 0, 0);
}

// ---------------- workspace layout ----------------
static constexpr size_t OFF_P = 0;
static constexpr size_t OFF_ENORM = 4194304;
static constexpr size_t OFF_WD2 = 4194816;    // WD2H[12288]+WD2L[12288] ushorts
static constexpr size_t OFF_ACC = 4207360;
static constexpr size_t OFF_ZROW = 4207368;
static constexpr size_t OFF_EMBT = 4207432;   // fp32 embT [c=256][code=512]
static constexpr size_t OFF_SSQ = 4338504;    // 8 slots x 256 samples
static constexpr size_t OFF_SHORT = 4340552;  // 16B aligned (x4 bytes)
static constexpr size_t SO_H1H = 0;
static constexpr size_t SO_H1L = 16777216;
static constexpr size_t SO_NBH = 33554432;
static constexpr size_t SO_NBL = 37748736;
static constexpr size_t SO_W1H = 41943040;
static constexpr size_t SO_W1L = 41959424;
static constexpr size_t SO_W2H = 41975808;
static constexpr size_t SO_W2L = 43024384;
static constexpr size_t SO_W3EH = 44072960;
static constexpr size_t SO_W3EL = 45252608;
static constexpr size_t SO_W3D = 46432256;
static constexpr size_t SO_W1REH = 47611904;
static constexpr size_t SO_W1REL = 47742976;
static constexpr size_t SO_W1RD = 47874048;
static constexpr size_t SO_WD1 = 48005120;

__device__ __forceinline__ void split_store(float v, ushort_t* hi, ushort_t* lo, size_t i) {
  ushort_t h = f2bs(v);
  hi[i] = h;
  lo[i] = f2bs(v - bs2f(h));
}

// ---------------- fused prep (unchanged) ----------------
__global__ void __launch_bounds__(256) k_prep(
    const float* __restrict__ x, const float* __restrict__ ew1,
    const float* __restrict__ ew2, const float* __restrict__ r3w,
    const float* __restrict__ r1w, const float* __restrict__ dw1,
    const float* __restrict__ dw2, const float* __restrict__ emb,
    ushort_t* __restrict__ W1H, ushort_t* __restrict__ W1L,
    ushort_t* __restrict__ W2H, ushort_t* __restrict__ W2L,
    ushort_t* __restrict__ W3EH, ushort_t* __restrict__ W3EL,
    ushort_t* __restrict__ W3D, ushort_t* __restrict__ W1REH,
    ushort_t* __restrict__ W1REL, ushort_t* __restrict__ W1RD,
    ushort_t* __restrict__ WD1, ushort_t* __restrict__ WD2H,
    ushort_t* __restrict__ WD2L,
    float* __restrict__ enorm, float* __restrict__ acc, float* __restrict__ zrow,
    float* __restrict__ embT, float* __restrict__ ssq,
    ushort_t* __restrict__ A1H, ushort_t* __restrict__ A1L) {
  int b = blockIdx.x, t = threadIdx.x;
  if (b < 64) {
    int i = b * 256 + t;
    int oc = i >> 6, k = i & 63;
    float v = 0.f;
    if (k < 48) {
      int tap = k / 3, ic = k - 3 * tap;
      v = ew1[(oc * 3 + ic) * 16 + tap];
    }
    split_store(v, W1H, W1L, i);
  } else if (b < 4160) {
    int i = (b - 64) * 256 + t;
    int oc = i >> 12, k = i & 4095;
    int tap = k >> 8, ic = k & 255;
    split_store(ew2[(oc * 256 + ic) * 16 + tap], W2H, W2L, i);
  } else if (b < 8768) {
    int i = (b - 4160) * 256 + t;
    int rb = i / 589824, r2 = i - rb * 589824;
    int oc = r2 / 2304, k = r2 - oc * 2304;
    int r9 = k >> 8, ic = k & 255;
    split_store(r3w[((rb * 256 + oc) * 256 + ic) * 9 + r9], W3EH, W3EL, i);
  } else if (b < 13376) {
    int i = (b - 8768) * 256 + t;
    int rb = i / 589824, r2 = i - rb * 589824;
    int oc = r2 / 2304, k = r2 - oc * 2304;
    int r9 = k >> 8, ic = k & 255;
    W3D[i] = f2bs(r3w[(((rb + 2) * 256 + oc) * 256 + ic) * 9 + r9]);
  } else if (b < 13888) {
    int i = (b - 13376) * 256 + t;
    split_store(r1w[i], W1REH, W1REL, i);
  } else if (b < 14400) {
    int i = (b - 13888) * 256 + t;
    W1RD[i] = f2bs(r1w[2 * 65536 + i]);
  } else if (b < 18496) {
    int i = (b - 14400) * 256 + t;
    int cls = i >> 18, r2 = i & 262143;
    int oc = r2 >> 10, k = r2 & 1023;
    int tap = k >> 8, ic = k & 255;
    int s = tap >> 1, sx = tap & 1;
    int py = cls >> 1, px = cls & 1;
    int ky = py + 2 - 2 * s, kx = px + 2 - 2 * sx;
    WD1[i] = f2bs(dw1[(ic * 256 + oc) * 16 + ky * 4 + kx]);
  } else if (b < 18544) {
    int i = (b - 18496) * 256 + t;  // [0, 12288)
    int j = i >> 8, ic = i & 255;
    int kyx = j / 3, oc = j - kyx * 3;
    split_store(dw2[(ic * 3 + oc) * 16 + kyx], WD2H, WD2L, (size_t)j * 256 + ic);
  } else if (b < 18546) {
    int e = (b - 18544) * 256 + t;
    float s = 0.f;
    for (int c = 0; c < 256; ++c) {
      float v = emb[e * 256 + c];
      s += v * v;
    }
    enorm[e] = s;
  } else if (b == 18546) {
    if (t < 2) acc[t] = 0.f;
    if (t < 64) zrow[t] = 0.f;
    for (int k = t; k < 2048; k += 256) ssq[k] = 0.f;
  } else if (b < 34931) {
    int i = (b - 18547) * 256 + t;
    int t1 = i >> 6, k = i & 63;
    float v = 0.f;
    if (k < 48) {
      int tap = k / 3, ic = k - 3 * tap;
      int n = t1 >> 8, oy = (t1 >> 4) & 15, ox = t1 & 15;
      int ky = tap >> 2, kx = tap & 3;
      int iy = 2 * oy - 1 + ky, ix = 2 * ox - 1 + kx;
      if ((unsigned)iy < 32u && (unsigned)ix < 32u)
        v = x[((n * 3 + ic) * 32 + iy) * 32 + ix];
    }
    split_store(v, A1H, A1L, i);
  } else {
    int i = (b - 34931) * 256 + t;
    int code = i >> 8, c = i & 255;
    embT[c * 512 + code] = emb[i];
  }
}

// ---------------- MFMA GEMM (BN=256, BM=64, 8 waves, PIPE=3) ----------------
// SSQ: 0 none; 1 atomic ssq per sample; 2 fused rmsnorm (H+L -> outb/outb2);
// 3 fused rmsnorm (H only -> outb). For SSQ>=2, ssqp carries the rms weight
// slice (rmsw[c*64+j]); block = one 64-token sample.
template <int MODE, int EPI, int STYLE, int SSQ>
__global__ __launch_bounds__(512) void k_gemm(const ushort_t* __restrict__ Ah,
                                              const ushort_t* __restrict__ Al,
                                              const ushort_t* __restrict__ Bh,
                                              const ushort_t* __restrict__ Bl, int K,
                                              const float* __restrict__ bias,
                                              const float* __restrict__ res,
                                              float* __restrict__ outf,
                                              ushort_t* __restrict__ outb,
                                              ushort_t* __restrict__ outb2,
                                              const ushort_t* __restrict__ zrow,
                                              float* __restrict__ ssqp) {
  constexpr int PIPE = 3;
  __shared__ __align__(16) ushort_t A0[PIPE][64 * 32];
  __shared__ __align__(16) ushort_t A1s[PIPE][64 * 32];
  __shared__ __align__(16) ushort_t B0[PIPE][256 * 32];
  __shared__ __align__(16) ushort_t B1[PIPE][256 * 32];
  __shared__ float red[512];
  const int t = threadIdx.x;
  const int w = t >> 6, l = t & 63;
  const int M0 = blockIdx.x * 64;
  int py = 0, px = 0;
  const ushort_t* Bb = Bh;
  if (MODE == 3) {
    int cls = blockIdx.z;
    py = cls >> 1;
    px = cls & 1;
    Bb = Bh + (size_t)cls * 262144;
  }
  const int srow = l & 15, chunk = l >> 4;
  const int fr = l & 15, quad = l >> 4;
  const int m_off = (w & 1) * 32, n_off = (w >> 1) * 64;
  const int mset = (m_off >> 4), nset = (n_off >> 4);

  const int aw = w & 3;
  const bool aH = (w < 4);
  const int atok = M0 + aw * 16 + srow;
  const size_t bb0 = (size_t)(2 * w * 16 + srow) * K + chunk * 8;
  const size_t bb1 = (size_t)((2 * w + 1) * 16 + srow) * K + chunk * 8;

  f32x4 acc[2][4];
#pragma unroll
  for (int i = 0; i < 2; ++i)
#pragma unroll
    for (int j = 0; j < 4; ++j) acc[i][j] = (f32x4){0.f, 0.f, 0.f, 0.f};

  const int n1 = atok >> 6, oy1 = (atok >> 3) & 7, ox1 = atok & 7;
  const ushort_t* zp = zrow + chunk * 8;

  const int SUB = (STYLE == 1) ? 32 : 64;

  size_t r1s = 0;
  bool v1s = true;
  if (MODE == 0) r1s = (size_t)atok * K + chunk * 8;

  auto stage = [&](int kk, int s) {
    const ushort_t* pa;
    if (MODE == 0) {
      size_t o = r1s + kk;
      pa = aH ? (Ah + o) : ((STYLE == 1) ? (Al + o) : (Ah + o + 32));
    } else {
      if ((kk & 255) == 0) {
        int tap = kk >> 8;
        int iy, ix;
        unsigned lim;
        if (MODE == 1) {
          int ky = tap >> 2, kx = tap & 3;
          iy = 2 * oy1 - 1 + ky; ix = 2 * ox1 - 1 + kx;
          lim = 16u;
        } else if (MODE == 2) {
          int ky = tap / 3, kx = tap - ky * 3;
          iy = oy1 - 1 + ky; ix = ox1 - 1 + kx;
          lim = 8u;
        } else {
          int s2 = tap >> 1, sx = tap & 1;
          iy = oy1 + s2 - py; ix = ox1 + sx - px;
          lim = 8u;
        }
        v1s = ((unsigned)iy < lim && (unsigned)ix < lim);
        if (MODE == 1)
          r1s = (size_t)(((n1 << 8) + (iy << 4) + ix)) << 8;
        else
          r1s = (size_t)(((n1 << 6) + (iy << 3) + ix)) << 8;
      }
      int kin = (kk & 255) + chunk * 8;
      if (v1s)
        pa = aH ? (Ah + r1s + kin)
                : ((STYLE == 1) ? (Al + r1s + kin) : (Ah + r1s + kin + 32));
      else
        pa = zp;
    }
    size_t bo0 = bb0 + kk, bo1 = bb1 + kk;
    glds16(pa, (aH ? A0[s] : A1s[s]) + aw * 512);
    glds16(Bb + bo0, B0[s] + (2 * w) * 512);
    glds16(Bb + bo1, B0[s] + (2 * w + 1) * 512);
    glds16((STYLE == 1) ? (Bl + bo0) : (Bb + bo0 + 32), B1[s] + (2 * w) * 512);
    glds16((STYLE == 1) ? (Bl + bo1) : (Bb + bo1 + 32), B1[s] + (2 * w + 1) * 512);
  };

  auto compute = [&](int s) {
    short8v af0[2], af1[2], bf0[4], bf1[4];
#pragma unroll
    for (int mi = 0; mi < 2; ++mi) {
      af0[mi] = *(const short8v*)(A0[s] + (mset + mi) * 512 + quad * 128 + fr * 8);
      af1[mi] = *(const short8v*)(A1s[s] + (mset + mi) * 512 + quad * 128 + fr * 8);
    }
#pragma unroll
    for (int nj = 0; nj < 4; ++nj) {
      bf0[nj] = *(const short8v*)(B0[s] + (nset + nj) * 512 + quad * 128 + fr * 8);
      bf1[nj] = *(const short8v*)(B1[s] + (nset + nj) * 512 + quad * 128 + fr * 8);
    }
#pragma unroll
    for (int mi = 0; mi < 2; ++mi)
#pragma unroll
      for (int nj = 0; nj < 4; ++nj) {
        acc[mi][nj] =
            __builtin_amdgcn_mfma_f32_16x16x32_bf16(af0[mi], bf0[nj], acc[mi][nj], 0, 0, 0);
        if (STYLE == 1) {
          acc[mi][nj] =
              __builtin_amdgcn_mfma_f32_16x16x32_bf16(af1[mi], bf0[nj], acc[mi][nj], 0, 0, 0);
          acc[mi][nj] =
              __builtin_amdgcn_mfma_f32_16x16x32_bf16(af0[mi], bf1[nj], acc[mi][nj], 0, 0, 0);
        } else {
          acc[mi][nj] =
              __builtin_amdgcn_mfma_f32_16x16x32_bf16(af1[mi], bf1[nj], acc[mi][nj], 0, 0, 0);
        }
      }
  };

  {
    const int nt = K / SUB;
    stage(0, 0);
    int ns = 1;
    if (nt > 1) {
      stage(SUB, 1);
      ns = 2;
    }
    int cb = 0, sb2 = ns % PIPE;
    for (int tt = 0; tt < nt; ++tt) {
      if (ns > tt + 1) {
        asm volatile("s_waitcnt vmcnt(5)" ::: "memory");
      } else {
        asm volatile("s_waitcnt vmcnt(0)" ::: "memory");
      }
      asm volatile("s_barrier" ::: "memory");
      if (ns < nt) {
        stage(ns * SUB, sb2);
        ++ns;
        sb2 = (sb2 + 1 == PIPE) ? 0 : sb2 + 1;
      }
      compute(cb);
      cb = (cb + 1 == PIPE) ? 0 : cb + 1;
    }
  }

  float sq = 0.f;
#pragma unroll
  for (int mi = 0; mi < 2; ++mi) {
    int mrow = m_off + mi * 16 + quad * 4;
#pragma unroll
    for (int nj = 0; nj < 4; ++nj) {
      int col = n_off + nj * 16 + fr;
      float bv = bias[col];
#pragma unroll
      for (int i = 0; i < 4; ++i) {
        int m = M0 + mrow + i;
        float v = fmaxf(acc[mi][nj][i] + bv, 0.f);
        if (EPI == 1) {
          outf[(size_t)m * 256 + col] = v;
          if (SSQ) sq += v * v;
        } else if (EPI == 2) {
          size_t o = (size_t)m * 256 + col;
          float vv = res[o] + v;
          outf[o] = vv;
          if (SSQ) sq += vv * vv;
          if (SSQ >= 2) acc[mi][nj][i] = vv;  // stash for fused norm pass
        } else if (EPI == 3) {
          int nn = m >> 6, jj = (m >> 3) & 7, ii = m & 7;
          int oy = 2 * jj + 1 - py, ox = 2 * ii + 1 - px;
          outb[(size_t)((nn << 8) + oy * 16 + ox) * 256 + col] = f2bs(v);
        } else if (EPI == 4) {
          size_t o = (size_t)m * 256 + col;
          ushort_t h = f2bs(v);
          outb[o] = h;
          outb2[o] = f2bs(v - bs2f(h));
        } else {  // EPI 5
          size_t o = (size_t)m * 256 + col;
          float vv = res[o] + v;
          outf[o] = vv;
          outb[o] = f2bs(vv);
        }
      }
    }
  }
  if (SSQ == 1) {
#pragma unroll
    for (int off = 32; off > 0; off >>= 1) sq += __shfl_down(sq, off, 64);
    if (l == 0) atomicAdd(&ssqp[M0 >> 6], sq);
  } else if (SSQ >= 2) {
    red[t] = sq;
    __syncthreads();
    for (int k = 256; k > 0; k >>= 1) {
      if (t < k) red[t] += red[t + k];
      __syncthreads();
    }
    float scale = 1.0f / sqrtf(red[0] / 16384.f + 1.1920929e-07f);
    const float* rw = ssqp;  // rms weight slice [c*64 + j]
#pragma unroll
    for (int mi = 0; mi < 2; ++mi) {
      int mrow = m_off + mi * 16 + quad * 4;
#pragma unroll
      for (int nj = 0; nj < 4; ++nj) {
        int col = n_off + nj * 16 + fr;
#pragma unroll
        for (int i = 0; i < 4; ++i) {
          int m = M0 + mrow + i;
          float v = acc[mi][nj][i] * scale * rw[col * 64 + (m & 63)];
          ushort_t h = f2bs(v);
          size_t o = (size_t)m * 256 + col;
          outb[o] = h;
          if (SSQ == 2) outb2[o] = f2bs(v - bs2f(h));
        }
      }
    }
  }
}

// ---------------- K-split / wide MFMA GEMM (BM=128, BN=256) ----------------
// EPIKS=0: raw fp32 partial -> sc0/sc1 (by blockIdx.y). EPIKS=3: deconv1
// bias+relu+bf16 scatter. EPIKS=4: conv1 bias+relu+split H/L store.
template <int MODE, int STYLE, int EPIKS>
__global__ __launch_bounds__(512) void k_gemmks(const ushort_t* __restrict__ Ah,
                                                const ushort_t* __restrict__ Al,
                                                const ushort_t* __restrict__ Bh,
                                                const ushort_t* __restrict__ Bl,
                                                int K, int KH,
                                                float* __restrict__ sc0,
                                                float* __restrict__ sc1,
                                                const float* __restrict__ bias,
                                                ushort_t* __restrict__ outb,
                                                ushort_t* __restrict__ outb2,
                                                const ushort_t* __restrict__ zrow) {
  constexpr int PIPE = 3;
  __shared__ __align__(16) ushort_t A0[PIPE][128 * 32];
  __shared__ __align__(16) ushort_t A1s[PIPE][128 * 32];
  __shared__ __align__(16) ushort_t B0[PIPE][256 * 32];
  __shared__ __align__(16) ushort_t B1[PIPE][256 * 32];
  const int t = threadIdx.x;
  const int w = t >> 6, l = t & 63;
  const int M0 = blockIdx.x * 128;
  const int koff = blockIdx.y * KH;
  float* outp = blockIdx.y ? sc1 : sc0;
  int py = 0, px = 0;
  const ushort_t* Bb = Bh;
  if (MODE == 3) {
    int cls = blockIdx.z;
    py = cls >> 1;
    px = cls & 1;
    Bb = Bh + (size_t)cls * 262144;
  }
  const int srow = l & 15, chunk = l >> 4;
  const int fr = l & 15, quad = l >> 4;
  const int m_off = (w & 1) * 64, n_off = (w >> 1) * 64;
  const int mset = m_off >> 4, nset = n_off >> 4;

  const int atok = M0 + w * 16 + srow;
  const size_t bb0 = (size_t)(2 * w * 16 + srow) * K + chunk * 8;
  const size_t bb1 = (size_t)((2 * w + 1) * 16 + srow) * K + chunk * 8;

  f32x4 acc[4][4];
#pragma unroll
  for (int i = 0; i < 4; ++i)
#pragma unroll
    for (int j = 0; j < 4; ++j) acc[i][j] = (f32x4){0.f, 0.f, 0.f, 0.f};

  const int n1 = atok >> 6, oy1 = (atok >> 3) & 7, ox1 = atok & 7;
  const ushort_t* zp = zrow + chunk * 8;
  const int SUB = (STYLE == 1) ? 32 : 64;

  size_t r1s = 0;
  bool v1s = true;
  if (MODE == 0) r1s = (size_t)atok * K + chunk * 8;

  auto stage = [&](int kk, int s) {
    const ushort_t *pa, *pa2;
    if (MODE == 0) {
      size_t o = r1s + kk;
      pa = Ah + o;
      pa2 = (STYLE == 1) ? (Al + o) : (Ah + o + 32);
    } else {
      if ((kk & 255) == 0 || kk == koff) {  // koff may start mid-tap
        int tap = kk >> 8;
        int iy, ix;
        unsigned lim;
        if (MODE == 1) {
          int ky = tap >> 2, kx = tap & 3;
          iy = 2 * oy1 - 1 + ky; ix = 2 * ox1 - 1 + kx;
          lim = 16u;
        } else if (MODE == 2) {
          int ky = tap / 3, kx = tap - ky * 3;
          iy = oy1 - 1 + ky; ix = ox1 - 1 + kx;
          lim = 8u;
        } else {  // MODE 3
          int s2 = tap >> 1, sx = tap & 1;
          iy = oy1 + s2 - py; ix = ox1 + sx - px;
          lim = 8u;
        }
        v1s = ((unsigned)iy < lim && (unsigned)ix < lim);
        if (MODE == 1)
          r1s = (size_t)(((n1 << 8) + (iy << 4) + ix)) << 8;
        else
          r1s = (size_t)(((n1 << 6) + (iy << 3) + ix)) << 8;
      }
      int kin = (kk & 255) + chunk * 8;
      if (v1s) {
        pa = Ah + r1s + kin;
        pa2 = (STYLE == 1) ? (Al + r1s + kin) : (Ah + r1s + kin + 32);
      } else {
        pa = zp;
        pa2 = zp;
      }
    }
    size_t bo0 = bb0 + kk, bo1 = bb1 + kk;
    glds16(pa, A0[s] + w * 512);
    glds16(pa2, A1s[s] + w * 512);
    glds16(Bb + bo0, B0[s] + (2 * w) * 512);
    glds16(Bb + bo1, B0[s] + (2 * w + 1) * 512);
    glds16((STYLE == 1) ? (Bl + bo0) : (Bb + bo0 + 32), B1[s] + (2 * w) * 512);
    glds16((STYLE == 1) ? (Bl + bo1) : (Bb + bo1 + 32), B1[s] + (2 * w + 1) * 512);
  };

  auto compute = [&](int s) {
    short8v af0[4], af1[4], bf0[4], bf1[4];
#pragma unroll
    for (int mi = 0; mi < 4; ++mi) {
      af0[mi] = *(const short8v*)(A0[s] + (mset + mi) * 512 + quad * 128 + fr * 8);
      af1[mi] = *(const short8v*)(A1s[s] + (mset + mi) * 512 + quad * 128 + fr * 8);
    }
#pragma unroll
    for (int nj = 0; nj < 4; ++nj) {
      bf0[nj] = *(const short8v*)(B0[s] + (nset + nj) * 512 + quad * 128 + fr * 8);
      bf1[nj] = *(const short8v*)(B1[s] + (nset + nj) * 512 + quad * 128 + fr * 8);
    }
#pragma unroll
    for (int mi = 0; mi < 4; ++mi)
#pragma unroll
      for (int nj = 0; nj < 4; ++nj) {
        acc[mi][nj] =
            __builtin_amdgcn_mfma_f32_16x16x32_bf16(af0[mi], bf0[nj], acc[mi][nj], 0, 0, 0);
        if (STYLE == 1) {
          acc[mi][nj] =
              __builtin_amdgcn_mfma_f32_16x16x32_bf16(af1[mi], bf0[nj], acc[mi][nj], 0, 0, 0);
          acc[mi][nj] =
              __builtin_amdgcn_mfma_f32_16x16x32_bf16(af0[mi], bf1[nj], acc[mi][nj], 0, 0, 0);
        } else {
          acc[mi][nj] =
              __builtin_amdgcn_mfma_f32_16x16x32_bf16(af1[mi], bf1[nj], acc[mi][nj], 0, 0, 0);
        }
      }
  };

  {
    const int nt = KH / SUB;
    stage(koff, 0);
    int ns = 1;
    if (nt > 1) {
      stage(koff + SUB, 1);
      ns = 2;
    }
    int cb = 0, sb2 = ns % PIPE;
    for (int tt = 0; tt < nt; ++tt) {
      if (ns > tt + 1) {
        asm volatile("s_waitcnt vmcnt(6)" ::: "memory");
      } else {
        asm volatile("s_waitcnt vmcnt(0)" ::: "memory");
      }
      asm volatile("s_barrier" ::: "memory");
      if (ns < nt) {
        stage(koff + ns * SUB, sb2);
        ++ns;
        sb2 = (sb2 + 1 == PIPE) ? 0 : sb2 + 1;
      }
      compute(cb);
      cb = (cb + 1 == PIPE) ? 0 : cb + 1;
    }
  }

#pragma unroll
  for (int mi = 0; mi < 4; ++mi) {
    int mrow = m_off + mi * 16 + quad * 4;
#pragma unroll
    for (int nj = 0; nj < 4; ++nj) {
      int col = n_off + nj * 16 + fr;
      if (EPIKS == 0) {
#pragma unroll
        for (int i = 0; i < 4; ++i)
          outp[(size_t)(M0 + mrow + i) * 256 + col] = acc[mi][nj][i];
      } else if (EPIKS == 3) {  // bias + relu + bf16 scatter (deconv1)
        float bv = bias[col];
#pragma unroll
        for (int i = 0; i < 4; ++i) {
          int m = M0 + mrow + i;
          float v = fmaxf(acc[mi][nj][i] + bv, 0.f);
          int nn = m >> 6, jj = (m >> 3) & 7, ii = m & 7;
          int oy = 2 * jj + 1 - py, ox = 2 * ii + 1 - px;
          outb[(size_t)((nn << 8) + oy * 16 + ox) * 256 + col] = f2bs(v);
        }
      } else {  // EPIKS 4: bias + relu + split H/L store (conv1)
        float bv = bias[col];
#pragma unroll
        for (int i = 0; i < 4; ++i) {
          int m = M0 + mrow + i;
          float v = fmaxf(acc[mi][nj][i] + bv, 0.f);
          size_t o = (size_t)m * 256 + col;
          ushort_t h = f2bs(v);
          outb[o] = h;
          outb2[o] = f2bs(v - bs2f(h));
        }
      }
    }
  }
}

// ---------------- K-split epilogue (+ optional fused rmsnorm) --------------
template <int RES, int NORM>
__global__ void __launch_bounds__(256) k_epi(const float* __restrict__ sc0,
                                             const float* __restrict__ sc1,
                                             const float* __restrict__ bias,
                                             const float* __restrict__ res,
                                             float* __restrict__ out,
                                             float* __restrict__ ssqp,
                                             const float* __restrict__ rmsw,
                                             ushort_t* __restrict__ NBh,
                                             ushort_t* __restrict__ NBl) {
  __shared__ float red[256];
  __shared__ float wl[256 * 65];
  int s = blockIdx.x, t = threadIdx.x;
  size_t base = (size_t)s * 16384;
  float bv = bias[t];
  if (NORM) {
    for (int k = 0; k < 64; ++k) {
      int i = k * 256 + t;
      wl[(i >> 6) * 65 + (i & 63)] = rmsw[i];
    }
  }
  float sq = 0.f;
  for (int r = 0; r < 64; ++r) {
    size_t o = base + (size_t)r * 256 + t;
    float v = fmaxf(sc0[o] + sc1[o] + bv, 0.f);
    if (RES) v += res[o];
    out[o] = v;
    sq += v * v;
  }
  red[t] = sq;
  __syncthreads();
  for (int k = 128; k > 0; k >>= 1) {
    if (t < k) red[t] += red[t + k];
    __syncthreads();
  }
  if (t == 0) ssqp[s] = red[0];
  if (NORM) {
    float scale = 1.0f / sqrtf(red[0] / 16384.f + 1.1920929e-07f);
    ushort_t* oh = NBh + base;
    ushort_t* ol = (NORM == 1) ? (NBl + base) : nullptr;
    for (int r = 0; r < 64; ++r) {
      size_t o = base + (size_t)r * 256 + t;
      float v = out[o] * scale * wl[t * 65 + r];
      ushort_t h = f2bs(v);
      oh[r * 256 + t] = h;
      if (NORM == 1) ol[r * 256 + t] = f2bs(v - bs2f(h));
    }
  }
}

// ---------------- rmsnorm normalize-only (1 standalone site: after VQ) ------
template <int SPLIT>
__global__ void __launch_bounds__(256) k_rmsnorm(const float* __restrict__ in,
                                                 const float* __restrict__ rmsw,
                                                 const float* __restrict__ ssq,
                                                 ushort_t* __restrict__ NBh,
                                                 ushort_t* __restrict__ NBl) {
  extern __shared__ float wT[];  // 64*257 floats
  int n = blockIdx.x, t = threadIdx.x;
  const float* p = in + (size_t)n * 16384;
  for (int k = 0; k < 64; ++k) {
    int i = k * 256 + t;  // i = c*64 + j
    wT[(i & 63) * 257 + (i >> 6)] = rmsw[i];
  }
  float scale = 1.0f / sqrtf(ssq[n] / 16384.f + 1.1920929e-07f);
  __syncthreads();
  ushort_t* oh = NBh + (size_t)n * 16384;
  ushort_t* ol = NBl + (size_t)n * 16384;
  for (int j = 0; j < 64; ++j) {
    int i = j * 256 + t;
    float v = p[i] * scale * wT[j * 257 + t];
    ushort_t h = f2bs(v);
    oh[i] = h;
    if (SPLIT) ol[i] = f2bs(v - bs2f(h));
  }
}

// ---------------- VQ (unchanged) ----------------
__global__ void __launch_bounds__(256) k_vq(const float* __restrict__ enc,
                                            const float* __restrict__ embT,
                                            const float* __restrict__ emb,
                                            const float* __restrict__ enorm,
                                            float* __restrict__ q, float* __restrict__ sse,
                                            float* __restrict__ ssq4) {
  __shared__ float z[16][256];
  __shared__ float sc[512 * 16];
  __shared__ float bv[16][16];
  __shared__ int bi[16][16];
  __shared__ int idxs[16];
  int T0 = blockIdx.x * 16;
  int t = threadIdx.x;
  for (int j = 0; j < 16; ++j) z[j][t] = enc[(size_t)(T0 + j) * 256 + t];
  __syncthreads();
  float d0[16], d1[16];
#pragma unroll
  for (int j = 0; j < 16; ++j) { d0[j] = 0.f; d1[j] = 0.f; }
  for (int c4 = 0; c4 < 64; ++c4) {
    const float* eb = embT + (size_t)(c4 * 4) * 512 + t;
    float e00 = eb[0], f00 = eb[256];
    float e01 = eb[512], f01 = eb[768];
    float e02 = eb[1024], f02 = eb[1280];
    float e03 = eb[1536], f03 = eb[1792];
#pragma unroll
    for (int j = 0; j < 16; ++j) {
      float4 zv = *(const float4*)&z[j][c4 * 4];
      d0[j] += zv.x * e00 + zv.y * e01 + zv.z * e02 + zv.w * e03;
      d1[j] += zv.x * f00 + zv.y * f01 + zv.z * f02 + zv.w * f03;
    }
  }
  float en0 = enorm[t], en1 = enorm[t + 256];
#pragma unroll
  for (int j = 0; j < 16; ++j) {
    sc[t * 16 + j] = en0 - 2.f * d0[j];
    sc[(t + 256) * 16 + j] = en1 - 2.f * d1[j];
  }
  __syncthreads();
  {
    int j = t & 15, chunk = t >> 4;
    float best = 3.4e38f;
    int bidx = 0;
    int c0 = chunk * 32;
    for (int cc = 0; cc < 32; ++cc) {
      float v = sc[(c0 + cc) * 16 + j];
      if (v < best) { best = v; bidx = c0 + cc; }
    }
    bv[chunk][j] = best;
    bi[chunk][j] = bidx;
  }
  __syncthreads();
  if (t < 16) {
    float best = 3.4e38f;
    int bidx = 0;
    for (int c = 0; c < 16; ++c) {
      float v = bv[c][t];
      if (v < best) { best = v; bidx = bi[c][t]; }
    }
    idxs[t] = bidx;
  }
  __syncthreads();
  float sq = 0.f, sqq = 0.f;
  for (int j = 0; j < 16; ++j) {
    float e = emb[(size_t)idxs[j] * 256 + t];
    q[(size_t)(T0 + j) * 256 + t] = e;
    float d = z[j][t] - e;
    sq += d * d;
    sqq += e * e;
  }
  __syncthreads();
  sc[t] = sq;
  __syncthreads();
  for (int k = 128; k > 0; k >>= 1) {
    if (t < k) sc[t] += sc[t + k];
    __syncthreads();
  }
  if (t == 0) atomicAdd(sse, sc[0]);
  __syncthreads();
  sc[t] = sqq;
  __syncthreads();
  for (int k = 128; k > 0; k >>= 1) {
    if (t < k) sc[t] += sc[t + k];
    __syncthreads();
  }
  if (t == 0) atomicAdd(&ssq4[blockIdx.x >> 2], sc[0]);
}

// ---------------- deconv2 as GEMM (256 tokens/block: halves B staging) -----
__global__ void __launch_bounds__(256) k_dec2gemm(const ushort_t* __restrict__ A,
                                                  const ushort_t* __restrict__ BH,
                                                  const ushort_t* __restrict__ BL,
                                                  float* __restrict__ G) {
  __shared__ __align__(16) ushort_t sBH[48 * 256];
  __shared__ __align__(16) ushort_t sBL[48 * 256];
  const int t = threadIdx.x;
  const int w = t >> 6, l = t & 63;
  const int fr = l & 15, quad = l >> 4, quad8 = quad * 8;
  for (int i = t * 8; i < 12288; i += 2048) {
    *(short8v*)(sBH + i) = *(const short8v*)(BH + i);
    *(short8v*)(sBL + i) = *(const short8v*)(BL + i);
  }
  __syncthreads();
  const int tok0 = blockIdx.x * 256 + w * 64;
  f32x4 acc[4][3];
#pragma unroll
  for (int i = 0; i < 4; ++i)
#pragma unroll
    for (int j = 0; j < 3; ++j) acc[i][j] = (f32x4){0.f, 0.f, 0.f, 0.f};
#pragma unroll
  for (int kk = 0; kk < 256; kk += 32) {
    short8v af[4];
#pragma unroll
    for (int mi = 0; mi < 4; ++mi)
      af[mi] = *(const short8v*)(A + (size_t)(tok0 + mi * 16 + fr) * 256 + kk + quad8);
#pragma unroll
    for (int nj = 0; nj < 3; ++nj) {
      short8v bh = *(const short8v*)(sBH + (nj * 16 + fr) * 256 + kk + quad8);
      short8v bl = *(const short8v*)(sBL + (nj * 16 + fr) * 256 + kk + quad8);
#pragma unroll
      for (int mi = 0; mi < 4; ++mi) {
        acc[mi][nj] =
            __builtin_amdgcn_mfma_f32_16x16x32_bf16(af[mi], bh, acc[mi][nj], 0, 0, 0);
        acc[mi][nj] =
            __builtin_amdgcn_mfma_f32_16x16x32_bf16(af[mi], bl, acc[mi][nj], 0, 0, 0);
      }
    }
  }
#pragma unroll
  for (int mi = 0; mi < 4; ++mi) {
    int mrow = mi * 16 + quad * 4;
#pragma unroll
    for (int nj = 0; nj < 3; ++nj) {
      int col = nj * 16 + fr;
#pragma unroll
      for (int i = 0; i < 4; ++i)
        G[(size_t)(tok0 + mrow + i) * 64 + col] = acc[mi][nj][i];
    }
  }
}

// ---------------- deconv2 gather + reconst loss (unchanged) ----------------
__global__ void __launch_bounds__(256) k_dec2gather(const float* __restrict__ G,
                                                    const float* __restrict__ bias,
                                                    const float* __restrict__ x,
                                                    float* __restrict__ dec,
                                                    float* __restrict__ sse) {
  __shared__ float GL[256 * 49];
  __shared__ float red[256];
  int n = blockIdx.x, t = threadIdx.x;
  for (int i = t; i < 12288; i += 256) {
    int r = i / 48, c = i - r * 48;
    GL[r * 49 + c] = G[(size_t)((n << 8) + r) * 64 + c];
  }
  __syncthreads();
  float sq = 0.f;
  for (int rep = 0; rep < 12; ++rep) {
    int o = rep * 256 + t;
    int oc = o >> 10, rem = o & 1023;
    int oy = rem >> 5, ox = rem & 31;
    int py = (oy + 1) & 1, dy = (oy + 1 - py) >> 1;
    int px = (ox + 1) & 1, dx = (ox + 1 - px) >> 1;
    int iy0 = dy - 1, ix0 = dx - 1;
    bool y0 = (unsigned)iy0 < 16u, y1 = (unsigned)dy < 16u;
    bool x0 = (unsigned)ix0 < 16u, x1 = (unsigned)dx < 16u;
    float v = bias[oc];
    if (y0 && x0) v += GL[(iy0 * 16 + ix0) * 49 + ((py + 2) * 4 + px + 2) * 3 + oc];
    if (y0 && x1) v += GL[(iy0 * 16 + dx) * 49 + ((py + 2) * 4 + px) * 3 + oc];
    if (y1 && x0) v += GL[(dy * 16 + ix0) * 49 + (py * 4 + px + 2) * 3 + oc];
    if (y1 && x1) v += GL[(dy * 16 + dx) * 49 + (py * 4 + px) * 3 + oc];
    int oi = ((n * 3 + oc) * 32 + oy) * 32 + ox;
    dec[oi] = v;
    float d = v - x[oi];
    sq += d * d;
  }
  red[t] = sq;
  __syncthreads();
  for (int k = 128; k > 0; k >>= 1) {
    if (t < k) red[t] += red[t + k];
    __syncthreads();
  }
  if (t == 0) atomicAdd(sse, red[0]);
}

__global__ void k_final(const float* __restrict__ acc, float* __restrict__ out) {
  if (threadIdx.x == 0 && blockIdx.x == 0) {
    float vq = acc[0] / 4194304.f;
    float rec = acc[1] / 786432.f;
    out[0] = rec + 2.f * vq;
    out[1] = rec;
    out[2] = vq;
    out[3] = vq;
  }
}

extern "C" void kernel_launch(void* const* d_in, const int* in_sizes, int n_in,
                              void* d_out, int out_size, void* d_ws, size_t ws_size,
                              hipStream_t stream) {
  (void)in_sizes; (void)n_in; (void)out_size; (void)ws_size;
  const float* x = (const float*)d_in[0];
  const float* ew1 = (const float*)d_in[1];
  const float* eb1 = (const float*)d_in[2];
  const float* ew2 = (const float*)d_in[3];
  const float* eb2 = (const float*)d_in[4];
  const float* rmsw = (const float*)d_in[5];
  const float* r3w = (const float*)d_in[6];
  const float* r3b = (const float*)d_in[7];
  const float* r1w = (const float*)d_in[8];
  const float* r1b = (const float*)d_in[9];
  const float* emb = (const float*)d_in[10];
  const float* dw1 = (const float*)d_in[11];
  const float* db1 = (const float*)d_in[12];
  const float* dw2 = (const float*)d_in[13];
  const float* db2 = (const float*)d_in[14];
  float* out = (float*)d_out;

  float* wsf = (float*)d_ws;
  float* P = wsf + OFF_P;
  float* enorm = wsf + OFF_ENORM;
  float* acc = wsf + OFF_ACC;
  float* zrowf = wsf + OFF_ZROW;
  float* embT = wsf + OFF_EMBT;
  float* ssq = wsf + OFF_SSQ;
  ushort_t* WD2H = (ushort_t*)(wsf + OFF_WD2);
  ushort_t* WD2L = WD2H + 12288;
  ushort_t* sb = (ushort_t*)(wsf + OFF_SHORT);
  ushort_t* H1H = sb + SO_H1H;
  ushort_t* H1L = sb + SO_H1L;
  float* Qf = (float*)(sb + SO_H1L);
  ushort_t* NBH = sb + SO_NBH;
  ushort_t* NBL = sb + SO_NBL;
  ushort_t* A1H = NBH;
  ushort_t* A1L = NBL;
  ushort_t* QB = NBL;
  ushort_t* W1H = sb + SO_W1H;
  ushort_t* W1L = sb + SO_W1L;
  ushort_t* W2H = sb + SO_W2H;
  ushort_t* W2L = sb + SO_W2L;
  ushort_t* W3EH = sb + SO_W3EH;
  ushort_t* W3EL = sb + SO_W3EL;
  ushort_t* W3D = sb + SO_W3D;
  ushort_t* W1REH = sb + SO_W1REH;
  ushort_t* W1REL = sb + SO_W1REL;
  ushort_t* W1RD = sb + SO_W1RD;
  ushort_t* WD1 = sb + SO_WD1;
  const ushort_t* zrow = (const ushort_t*)zrowf;
  float* NBf = (float*)(sb + SO_NBH);   // conv2 SC0 (A1 consumed by conv1)
  float* H1f = (float*)(sb + SO_H1H);   // res3 SC0 (H1 dead after conv2)
  const size_t RMS_LDS = 64 * 257 * sizeof(float);

  k_prep<<<35443, 256, 0, stream>>>(x, ew1, ew2, r3w, r1w, dw1, dw2, emb,
                                    W1H, W1L, W2H, W2L, W3EH, W3EL, W3D,
                                    W1REH, W1REL, W1RD, WD1, WD2H, WD2L, enorm,
                                    acc, zrowf, embT, ssq, A1H, A1L);

  // conv1 (split, K=64, BM=128, EPIKS=4 split-store): 512 blocks
  k_gemmks<0, 1, 4><<<dim3(512), 512, 0, stream>>>(
      A1H, A1L, W1H, W1L, 64, 64, nullptr, nullptr, eb1, H1H, H1L, zrow);

  // conv2 K-split + fused epi/rms (idx0) -> P, NBH/NBL, ssq0
  k_gemmks<1, 1, 0><<<dim3(128, 2), 512, 0, stream>>>(
      H1H, H1L, W2H, W2L, 4096, 2048, NBf, P, nullptr, nullptr, nullptr, zrow);
  k_epi<0, 1><<<256, 256, 0, stream>>>(NBf, P, eb2, nullptr, P, ssq + 0,
                                       rmsw + 0, NBH, NBL);

  // res3-enc rb0 + fused epi/rms (idx1) -> Qf, NBH/NBL
  k_gemmks<2, 1, 0><<<dim3(128, 2), 512, 0, stream>>>(
      NBH, NBL, W3EH, W3EL, 2304, 1152, H1f, Qf, nullptr, nullptr, nullptr, zrow);
  k_epi<1, 1><<<256, 256, 0, stream>>>(H1f, Qf, r3b, P, Qf, ssq + 256,
                                       rmsw + 1 * 16384, NBH, NBL);
  // res1-enc rb0 -> P, fused rms idx2 -> NBH/NBL (SSQ=2)
  k_gemm<0, 2, 1, 2><<<dim3(256), 512, 0, stream>>>(
      NBH, NBL, W1REH, W1REL, 256, r1b, Qf, P, NBH, NBL, zrow,
      (float*)(rmsw + 2 * 16384));
  // res3-enc rb1 + fused epi/rms (idx3)
  k_gemmks<2, 1, 0><<<dim3(128, 2), 512, 0, stream>>>(
      NBH, NBL, W3EH + 589824, W3EL + 589824, 2304, 1152, H1f, Qf, nullptr,
      nullptr, nullptr, zrow);
  k_epi<1, 1><<<256, 256, 0, stream>>>(H1f, Qf, r3b + 256, P, Qf, ssq + 768,
                                       rmsw + 3 * 16384, NBH, NBL);
  // res1-enc rb1 -> P (no ssq)
  k_gemm<0, 2, 1, 0><<<dim3(256), 512, 0, stream>>>(
      NBH, NBL, W1REH + 65536, W1REL + 65536, 256, r1b + 256, Qf, P, nullptr,
      nullptr, zrow, nullptr);

  // VQ: P -> Qf (q), sse -> acc[0], q-ssq -> slot 4; standalone rms idx4
  k_vq<<<1024, 256, 0, stream>>>(P, embT, emb, enorm, Qf, acc + 0, ssq + 1024);
  k_rmsnorm<0><<<256, 256, RMS_LDS, stream>>>(Qf, rmsw + 4 * 16384, ssq + 1024,
                                              NBH, NBL);

  // res3-dec rb2 + fused epi/rms (idx5, H-only) -> P, NBH
  k_gemmks<2, 0, 0><<<dim3(128, 2), 512, 0, stream>>>(
      NBH, nullptr, W3D, nullptr, 2304, 1152, H1f, P, nullptr, nullptr, nullptr,
      zrow);
  k_epi<1, 2><<<256, 256, 0, stream>>>(H1f, P, r3b + 2 * 256, Qf, P, ssq + 1280,
                                       rmsw + 5 * 16384, NBH, nullptr);
  // res1-dec rb2 -> Qf, fused rms idx6 -> NBH (SSQ=3, H only)
  k_gemm<0, 2, 0, 3><<<dim3(256), 512, 0, stream>>>(
      NBH, nullptr, W1RD, nullptr, 256, r1b + 2 * 256, P, Qf, NBH, nullptr,
      zrow, (float*)(rmsw + 6 * 16384));
  // res3-dec rb3 + fused epi/rms (idx7, H-only) -> P, NBH
  k_gemmks<2, 0, 0><<<dim3(128, 2), 512, 0, stream>>>(
      NBH, nullptr, W3D + 589824, nullptr, 2304, 1152, H1f, P, nullptr, nullptr,
      nullptr, zrow);
  k_epi<1, 2><<<256, 256, 0, stream>>>(H1f, P, r3b + 3 * 256, Qf, P, ssq + 1792,
                                       rmsw + 7 * 16384, NBH, nullptr);
  // res1-dec rb3 (EPI5) -> Qf + QB
  k_gemm<0, 5, 0, 0><<<dim3(256), 512, 0, stream>>>(
      NBH, nullptr, W1RD + 65536, nullptr, 256, r1b + 3 * 256, P, Qf, QB, nullptr,
      zrow, nullptr);

  // deconv1 (K=1024, 4 parity classes, BM=128, direct bf16 scatter)
  k_gemmks<3, 0, 3><<<dim3(128, 1, 4), 512, 0, stream>>>(
      QB, nullptr, WD1, nullptr, 1024, 1024, nullptr, nullptr, db1, H1H, nullptr,
      zrow);

  // deconv2: GEMM (G = tokens x W, 48 cols) + gather/loss. G lives in P.
  k_dec2gemm<<<256, 256, 0, stream>>>(H1H, WD2H, WD2L, P);
  k_dec2gather<<<256, 256, 0, stream>>>(P, db2, x, out + 4, acc + 1);
  k_final<<<1, 64, 0, stream>>>(acc, out);
}

// Round 14
// 772.825 us; speedup vs baseline: 1.4548x; 1.0134x over previous
//
#include <hip/hip_runtime.h>
#include <hip/hip_bf16.h>

typedef unsigned short ushort_t;
typedef __attribute__((ext_vector_type(8))) short short8v;
typedef __attribute__((ext_vector_type(4))) float f32x4;

__device__ __forceinline__ ushort_t f2bs(float v) {
  union { __hip_bfloat16 h; ushort_t u; } cv;
  cv.h = __float2bfloat16(v);
  return cv.u;
}
__device__ __forceinline__ float bs2f(ushort_t u) {
  union { ushort_t u; __hip_bfloat16 h; } cv;
  cv.u = u;
  return __bfloat162float(cv.h);
}

__device__ __forceinline__ void glds16(const ushort_t* g, ushort_t* l) {
  __builtin_amdgcn_global_load_lds(
      (const __attribute__((address_space(1))) unsigned int*)(uintptr_t)g,
      (__attribute__((address_space(3))) unsigned int*)(unsigned int)(uintptr_t)l,
      16, 0, 0);
}

// ---------------- workspace layout ----------------
static constexpr size_t OFF_P = 0;
static constexpr size_t OFF_ENORM = 4194304;
static constexpr size_t OFF_WD2 = 4194816;    // WD2H[12288]+WD2L[12288] ushorts
static constexpr size_t OFF_ACC = 4207360;
static constexpr size_t OFF_ZROW = 4207368;
static constexpr size_t OFF_EMBT = 4207432;   // fp32 embT [c=256][code=512]
static constexpr size_t OFF_SSQ = 4338504;    // 8 slots x 256 samples
static constexpr size_t OFF_SHORT = 4340552;  // 16B aligned (x4 bytes)
static constexpr size_t SO_H1H = 0;
static constexpr size_t SO_H1L = 16777216;
static constexpr size_t SO_NBH = 33554432;
static constexpr size_t SO_NBL = 37748736;
static constexpr size_t SO_W1H = 41943040;
static constexpr size_t SO_W1L = 41959424;
static constexpr size_t SO_W2H = 41975808;
static constexpr size_t SO_W2L = 43024384;
static constexpr size_t SO_W3EH = 44072960;
static constexpr size_t SO_W3EL = 45252608;
static constexpr size_t SO_W3D = 46432256;
static constexpr size_t SO_W1REH = 47611904;
static constexpr size_t SO_W1REL = 47742976;
static constexpr size_t SO_W1RD = 47874048;
static constexpr size_t SO_WD1 = 48005120;

__device__ __forceinline__ void split_store(float v, ushort_t* hi, ushort_t* lo, size_t i) {
  ushort_t h = f2bs(v);
  hi[i] = h;
  lo[i] = f2bs(v - bs2f(h));
}

// ---------------- fused prep (unchanged) ----------------
__global__ void __launch_bounds__(256) k_prep(
    const float* __restrict__ x, const float* __restrict__ ew1,
    const float* __restrict__ ew2, const float* __restrict__ r3w,
    const float* __restrict__ r1w, const float* __restrict__ dw1,
    const float* __restrict__ dw2, const float* __restrict__ emb,
    ushort_t* __restrict__ W1H, ushort_t* __restrict__ W1L,
    ushort_t* __restrict__ W2H, ushort_t* __restrict__ W2L,
    ushort_t* __restrict__ W3EH, ushort_t* __restrict__ W3EL,
    ushort_t* __restrict__ W3D, ushort_t* __restrict__ W1REH,
    ushort_t* __restrict__ W1REL, ushort_t* __restrict__ W1RD,
    ushort_t* __restrict__ WD1, ushort_t* __restrict__ WD2H,
    ushort_t* __restrict__ WD2L,
    float* __restrict__ enorm, float* __restrict__ acc, float* __restrict__ zrow,
    float* __restrict__ embT, float* __restrict__ ssq,
    ushort_t* __restrict__ A1H, ushort_t* __restrict__ A1L) {
  int b = blockIdx.x, t = threadIdx.x;
  if (b < 64) {
    int i = b * 256 + t;
    int oc = i >> 6, k = i & 63;
    float v = 0.f;
    if (k < 48) {
      int tap = k / 3, ic = k - 3 * tap;
      v = ew1[(oc * 3 + ic) * 16 + tap];
    }
    split_store(v, W1H, W1L, i);
  } else if (b < 4160) {
    int i = (b - 64) * 256 + t;
    int oc = i >> 12, k = i & 4095;
    int tap = k >> 8, ic = k & 255;
    split_store(ew2[(oc * 256 + ic) * 16 + tap], W2H, W2L, i);
  } else if (b < 8768) {
    int i = (b - 4160) * 256 + t;
    int rb = i / 589824, r2 = i - rb * 589824;
    int oc = r2 / 2304, k = r2 - oc * 2304;
    int r9 = k >> 8, ic = k & 255;
    split_store(r3w[((rb * 256 + oc) * 256 + ic) * 9 + r9], W3EH, W3EL, i);
  } else if (b < 13376) {
    int i = (b - 8768) * 256 + t;
    int rb = i / 589824, r2 = i - rb * 589824;
    int oc = r2 / 2304, k = r2 - oc * 2304;
    int r9 = k >> 8, ic = k & 255;
    W3D[i] = f2bs(r3w[(((rb + 2) * 256 + oc) * 256 + ic) * 9 + r9]);
  } else if (b < 13888) {
    int i = (b - 13376) * 256 + t;
    split_store(r1w[i], W1REH, W1REL, i);
  } else if (b < 14400) {
    int i = (b - 13888) * 256 + t;
    W1RD[i] = f2bs(r1w[2 * 65536 + i]);
  } else if (b < 18496) {
    int i = (b - 14400) * 256 + t;
    int cls = i >> 18, r2 = i & 262143;
    int oc = r2 >> 10, k = r2 & 1023;
    int tap = k >> 8, ic = k & 255;
    int s = tap >> 1, sx = tap & 1;
    int py = cls >> 1, px = cls & 1;
    int ky = py + 2 - 2 * s, kx = px + 2 - 2 * sx;
    WD1[i] = f2bs(dw1[(ic * 256 + oc) * 16 + ky * 4 + kx]);
  } else if (b < 18544) {
    int i = (b - 18496) * 256 + t;  // [0, 12288)
    int j = i >> 8, ic = i & 255;
    int kyx = j / 3, oc = j - kyx * 3;
    split_store(dw2[(ic * 3 + oc) * 16 + kyx], WD2H, WD2L, (size_t)j * 256 + ic);
  } else if (b < 18546) {
    int e = (b - 18544) * 256 + t;
    float s = 0.f;
    for (int c = 0; c < 256; ++c) {
      float v = emb[e * 256 + c];
      s += v * v;
    }
    enorm[e] = s;
  } else if (b == 18546) {
    if (t < 2) acc[t] = 0.f;
    if (t < 64) zrow[t] = 0.f;
    for (int k = t; k < 2048; k += 256) ssq[k] = 0.f;
  } else if (b < 34931) {
    int i = (b - 18547) * 256 + t;
    int t1 = i >> 6, k = i & 63;
    float v = 0.f;
    if (k < 48) {
      int tap = k / 3, ic = k - 3 * tap;
      int n = t1 >> 8, oy = (t1 >> 4) & 15, ox = t1 & 15;
      int ky = tap >> 2, kx = tap & 3;
      int iy = 2 * oy - 1 + ky, ix = 2 * ox - 1 + kx;
      if ((unsigned)iy < 32u && (unsigned)ix < 32u)
        v = x[((n * 3 + ic) * 32 + iy) * 32 + ix];
    }
    split_store(v, A1H, A1L, i);
  } else {
    int i = (b - 34931) * 256 + t;
    int code = i >> 8, c = i & 255;
    embT[c * 512 + code] = emb[i];
  }
}

// ---------------- MFMA GEMM (BN=256, BM=64, 8 waves, PIPE=3) ----------------
// SSQ: 0 none; 1 atomic ssq per sample; 2 fused rmsnorm (H+L -> outb/outb2);
// 3 fused rmsnorm (H only -> outb). For SSQ>=2, ssqp carries the rms weight
// slice (rmsw[c*64+j]); block = one 64-token sample.
template <int MODE, int EPI, int STYLE, int SSQ>
__global__ __launch_bounds__(512) void k_gemm(const ushort_t* __restrict__ Ah,
                                              const ushort_t* __restrict__ Al,
                                              const ushort_t* __restrict__ Bh,
                                              const ushort_t* __restrict__ Bl, int K,
                                              const float* __restrict__ bias,
                                              const float* __restrict__ res,
                                              float* __restrict__ outf,
                                              ushort_t* __restrict__ outb,
                                              ushort_t* __restrict__ outb2,
                                              const ushort_t* __restrict__ zrow,
                                              float* __restrict__ ssqp) {
  constexpr int PIPE = 3;
  __shared__ __align__(16) ushort_t A0[PIPE][64 * 32];
  __shared__ __align__(16) ushort_t A1s[PIPE][64 * 32];
  __shared__ __align__(16) ushort_t B0[PIPE][256 * 32];
  __shared__ __align__(16) ushort_t B1[PIPE][256 * 32];
  __shared__ float red[512];
  const int t = threadIdx.x;
  const int w = t >> 6, l = t & 63;
  const int M0 = blockIdx.x * 64;
  int py = 0, px = 0;
  const ushort_t* Bb = Bh;
  if (MODE == 3) {
    int cls = blockIdx.z;
    py = cls >> 1;
    px = cls & 1;
    Bb = Bh + (size_t)cls * 262144;
  }
  const int srow = l & 15, chunk = l >> 4;
  const int fr = l & 15, quad = l >> 4;
  const int m_off = (w & 1) * 32, n_off = (w >> 1) * 64;
  const int mset = (m_off >> 4), nset = (n_off >> 4);

  const int aw = w & 3;
  const bool aH = (w < 4);
  const int atok = M0 + aw * 16 + srow;
  const size_t bb0 = (size_t)(2 * w * 16 + srow) * K + chunk * 8;
  const size_t bb1 = (size_t)((2 * w + 1) * 16 + srow) * K + chunk * 8;

  f32x4 acc[2][4];
#pragma unroll
  for (int i = 0; i < 2; ++i)
#pragma unroll
    for (int j = 0; j < 4; ++j) acc[i][j] = (f32x4){0.f, 0.f, 0.f, 0.f};

  const int n1 = atok >> 6, oy1 = (atok >> 3) & 7, ox1 = atok & 7;
  const ushort_t* zp = zrow + chunk * 8;

  const int SUB = (STYLE == 1) ? 32 : 64;

  size_t r1s = 0;
  bool v1s = true;
  if (MODE == 0) r1s = (size_t)atok * K + chunk * 8;

  auto stage = [&](int kk, int s) {
    const ushort_t* pa;
    if (MODE == 0) {
      size_t o = r1s + kk;
      pa = aH ? (Ah + o) : ((STYLE == 1) ? (Al + o) : (Ah + o + 32));
    } else {
      if ((kk & 255) == 0) {
        int tap = kk >> 8;
        int iy, ix;
        unsigned lim;
        if (MODE == 1) {
          int ky = tap >> 2, kx = tap & 3;
          iy = 2 * oy1 - 1 + ky; ix = 2 * ox1 - 1 + kx;
          lim = 16u;
        } else if (MODE == 2) {
          int ky = tap / 3, kx = tap - ky * 3;
          iy = oy1 - 1 + ky; ix = ox1 - 1 + kx;
          lim = 8u;
        } else {
          int s2 = tap >> 1, sx = tap & 1;
          iy = oy1 + s2 - py; ix = ox1 + sx - px;
          lim = 8u;
        }
        v1s = ((unsigned)iy < lim && (unsigned)ix < lim);
        if (MODE == 1)
          r1s = (size_t)(((n1 << 8) + (iy << 4) + ix)) << 8;
        else
          r1s = (size_t)(((n1 << 6) + (iy << 3) + ix)) << 8;
      }
      int kin = (kk & 255) + chunk * 8;
      if (v1s)
        pa = aH ? (Ah + r1s + kin)
                : ((STYLE == 1) ? (Al + r1s + kin) : (Ah + r1s + kin + 32));
      else
        pa = zp;
    }
    size_t bo0 = bb0 + kk, bo1 = bb1 + kk;
    glds16(pa, (aH ? A0[s] : A1s[s]) + aw * 512);
    glds16(Bb + bo0, B0[s] + (2 * w) * 512);
    glds16(Bb + bo1, B0[s] + (2 * w + 1) * 512);
    glds16((STYLE == 1) ? (Bl + bo0) : (Bb + bo0 + 32), B1[s] + (2 * w) * 512);
    glds16((STYLE == 1) ? (Bl + bo1) : (Bb + bo1 + 32), B1[s] + (2 * w + 1) * 512);
  };

  auto compute = [&](int s) {
    short8v af0[2], af1[2], bf0[4], bf1[4];
#pragma unroll
    for (int mi = 0; mi < 2; ++mi) {
      af0[mi] = *(const short8v*)(A0[s] + (mset + mi) * 512 + quad * 128 + fr * 8);
      af1[mi] = *(const short8v*)(A1s[s] + (mset + mi) * 512 + quad * 128 + fr * 8);
    }
#pragma unroll
    for (int nj = 0; nj < 4; ++nj) {
      bf0[nj] = *(const short8v*)(B0[s] + (nset + nj) * 512 + quad * 128 + fr * 8);
      bf1[nj] = *(const short8v*)(B1[s] + (nset + nj) * 512 + quad * 128 + fr * 8);
    }
#pragma unroll
    for (int mi = 0; mi < 2; ++mi)
#pragma unroll
      for (int nj = 0; nj < 4; ++nj) {
        acc[mi][nj] =
            __builtin_amdgcn_mfma_f32_16x16x32_bf16(af0[mi], bf0[nj], acc[mi][nj], 0, 0, 0);
        if (STYLE == 1) {
          acc[mi][nj] =
              __builtin_amdgcn_mfma_f32_16x16x32_bf16(af1[mi], bf0[nj], acc[mi][nj], 0, 0, 0);
          acc[mi][nj] =
              __builtin_amdgcn_mfma_f32_16x16x32_bf16(af0[mi], bf1[nj], acc[mi][nj], 0, 0, 0);
        } else {
          acc[mi][nj] =
              __builtin_amdgcn_mfma_f32_16x16x32_bf16(af1[mi], bf1[nj], acc[mi][nj], 0, 0, 0);
        }
      }
  };

  {
    const int nt = K / SUB;
    stage(0, 0);
    int ns = 1;
    if (nt > 1) {
      stage(SUB, 1);
      ns = 2;
    }
    int cb = 0, sb2 = ns % PIPE;
    for (int tt = 0; tt < nt; ++tt) {
      if (ns > tt + 1) {
        asm volatile("s_waitcnt vmcnt(5)" ::: "memory");
      } else {
        asm volatile("s_waitcnt vmcnt(0)" ::: "memory");
      }
      asm volatile("s_barrier" ::: "memory");
      if (ns < nt) {
        stage(ns * SUB, sb2);
        ++ns;
        sb2 = (sb2 + 1 == PIPE) ? 0 : sb2 + 1;
      }
      compute(cb);
      cb = (cb + 1 == PIPE) ? 0 : cb + 1;
    }
  }

  float sq = 0.f;
#pragma unroll
  for (int mi = 0; mi < 2; ++mi) {
    int mrow = m_off + mi * 16 + quad * 4;
#pragma unroll
    for (int nj = 0; nj < 4; ++nj) {
      int col = n_off + nj * 16 + fr;
      float bv = bias[col];
#pragma unroll
      for (int i = 0; i < 4; ++i) {
        int m = M0 + mrow + i;
        float v = fmaxf(acc[mi][nj][i] + bv, 0.f);
        if (EPI == 1) {
          outf[(size_t)m * 256 + col] = v;
          if (SSQ) sq += v * v;
        } else if (EPI == 2) {
          size_t o = (size_t)m * 256 + col;
          float vv = res[o] + v;
          outf[o] = vv;
          if (SSQ) sq += vv * vv;
          if (SSQ >= 2) acc[mi][nj][i] = vv;  // stash for fused norm pass
        } else if (EPI == 3) {
          int nn = m >> 6, jj = (m >> 3) & 7, ii = m & 7;
          int oy = 2 * jj + 1 - py, ox = 2 * ii + 1 - px;
          outb[(size_t)((nn << 8) + oy * 16 + ox) * 256 + col] = f2bs(v);
        } else if (EPI == 4) {
          size_t o = (size_t)m * 256 + col;
          ushort_t h = f2bs(v);
          outb[o] = h;
          outb2[o] = f2bs(v - bs2f(h));
        } else {  // EPI 5
          size_t o = (size_t)m * 256 + col;
          float vv = res[o] + v;
          outf[o] = vv;
          outb[o] = f2bs(vv);
        }
      }
    }
  }
  if (SSQ == 1) {
#pragma unroll
    for (int off = 32; off > 0; off >>= 1) sq += __shfl_down(sq, off, 64);
    if (l == 0) atomicAdd(&ssqp[M0 >> 6], sq);
  } else if (SSQ >= 2) {
    red[t] = sq;
    __syncthreads();
    for (int k = 256; k > 0; k >>= 1) {
      if (t < k) red[t] += red[t + k];
      __syncthreads();
    }
    float scale = 1.0f / sqrtf(red[0] / 16384.f + 1.1920929e-07f);
    const float* rw = ssqp;  // rms weight slice [c*64 + j]
#pragma unroll
    for (int mi = 0; mi < 2; ++mi) {
      int mrow = m_off + mi * 16 + quad * 4;
#pragma unroll
      for (int nj = 0; nj < 4; ++nj) {
        int col = n_off + nj * 16 + fr;
#pragma unroll
        for (int i = 0; i < 4; ++i) {
          int m = M0 + mrow + i;
          float v = acc[mi][nj][i] * scale * rw[col * 64 + (m & 63)];
          ushort_t h = f2bs(v);
          size_t o = (size_t)m * 256 + col;
          outb[o] = h;
          if (SSQ == 2) outb2[o] = f2bs(v - bs2f(h));
        }
      }
    }
  }
}

// ---------------- K-split / wide MFMA GEMM (BM=128, BN=256) ----------------
// EPIKS=0: raw fp32 partial -> sc0/sc1 (by blockIdx.y). EPIKS=3: deconv1
// bias+relu+bf16 scatter. EPIKS=4: conv1 bias+relu+split H/L store.
template <int MODE, int STYLE, int EPIKS>
__global__ __launch_bounds__(512) void k_gemmks(const ushort_t* __restrict__ Ah,
                                                const ushort_t* __restrict__ Al,
                                                const ushort_t* __restrict__ Bh,
                                                const ushort_t* __restrict__ Bl,
                                                int K, int KH,
                                                float* __restrict__ sc0,
                                                float* __restrict__ sc1,
                                                const float* __restrict__ bias,
                                                ushort_t* __restrict__ outb,
                                                ushort_t* __restrict__ outb2,
                                                const ushort_t* __restrict__ zrow) {
  constexpr int PIPE = 3;
  __shared__ __align__(16) ushort_t A0[PIPE][128 * 32];
  __shared__ __align__(16) ushort_t A1s[PIPE][128 * 32];
  __shared__ __align__(16) ushort_t B0[PIPE][256 * 32];
  __shared__ __align__(16) ushort_t B1[PIPE][256 * 32];
  const int t = threadIdx.x;
  const int w = t >> 6, l = t & 63;
  const int M0 = blockIdx.x * 128;
  const int koff = blockIdx.y * KH;
  float* outp = blockIdx.y ? sc1 : sc0;
  int py = 0, px = 0;
  const ushort_t* Bb = Bh;
  if (MODE == 3) {
    int cls = blockIdx.z;
    py = cls >> 1;
    px = cls & 1;
    Bb = Bh + (size_t)cls * 262144;
  }
  const int srow = l & 15, chunk = l >> 4;
  const int fr = l & 15, quad = l >> 4;
  const int m_off = (w & 1) * 64, n_off = (w >> 1) * 64;
  const int mset = m_off >> 4, nset = n_off >> 4;

  const int atok = M0 + w * 16 + srow;
  const size_t bb0 = (size_t)(2 * w * 16 + srow) * K + chunk * 8;
  const size_t bb1 = (size_t)((2 * w + 1) * 16 + srow) * K + chunk * 8;

  f32x4 acc[4][4];
#pragma unroll
  for (int i = 0; i < 4; ++i)
#pragma unroll
    for (int j = 0; j < 4; ++j) acc[i][j] = (f32x4){0.f, 0.f, 0.f, 0.f};

  const int n1 = atok >> 6, oy1 = (atok >> 3) & 7, ox1 = atok & 7;
  const ushort_t* zp = zrow + chunk * 8;
  const int SUB = (STYLE == 1) ? 32 : 64;

  size_t r1s = 0;
  bool v1s = true;
  if (MODE == 0) r1s = (size_t)atok * K + chunk * 8;

  auto stage = [&](int kk, int s) {
    const ushort_t *pa, *pa2;
    if (MODE == 0) {
      size_t o = r1s + kk;
      pa = Ah + o;
      pa2 = (STYLE == 1) ? (Al + o) : (Ah + o + 32);
    } else {
      if ((kk & 255) == 0 || kk == koff) {  // koff may start mid-tap
        int tap = kk >> 8;
        int iy, ix;
        unsigned lim;
        if (MODE == 1) {
          int ky = tap >> 2, kx = tap & 3;
          iy = 2 * oy1 - 1 + ky; ix = 2 * ox1 - 1 + kx;
          lim = 16u;
        } else if (MODE == 2) {
          int ky = tap / 3, kx = tap - ky * 3;
          iy = oy1 - 1 + ky; ix = ox1 - 1 + kx;
          lim = 8u;
        } else {  // MODE 3
          int s2 = tap >> 1, sx = tap & 1;
          iy = oy1 + s2 - py; ix = ox1 + sx - px;
          lim = 8u;
        }
        v1s = ((unsigned)iy < lim && (unsigned)ix < lim);
        if (MODE == 1)
          r1s = (size_t)(((n1 << 8) + (iy << 4) + ix)) << 8;
        else
          r1s = (size_t)(((n1 << 6) + (iy << 3) + ix)) << 8;
      }
      int kin = (kk & 255) + chunk * 8;
      if (v1s) {
        pa = Ah + r1s + kin;
        pa2 = (STYLE == 1) ? (Al + r1s + kin) : (Ah + r1s + kin + 32);
      } else {
        pa = zp;
        pa2 = zp;
      }
    }
    size_t bo0 = bb0 + kk, bo1 = bb1 + kk;
    glds16(pa, A0[s] + w * 512);
    glds16(pa2, A1s[s] + w * 512);
    glds16(Bb + bo0, B0[s] + (2 * w) * 512);
    glds16(Bb + bo1, B0[s] + (2 * w + 1) * 512);
    glds16((STYLE == 1) ? (Bl + bo0) : (Bb + bo0 + 32), B1[s] + (2 * w) * 512);
    glds16((STYLE == 1) ? (Bl + bo1) : (Bb + bo1 + 32), B1[s] + (2 * w + 1) * 512);
  };

  auto compute = [&](int s) {
    short8v af0[4], af1[4], bf0[4], bf1[4];
#pragma unroll
    for (int mi = 0; mi < 4; ++mi) {
      af0[mi] = *(const short8v*)(A0[s] + (mset + mi) * 512 + quad * 128 + fr * 8);
      af1[mi] = *(const short8v*)(A1s[s] + (mset + mi) * 512 + quad * 128 + fr * 8);
    }
#pragma unroll
    for (int nj = 0; nj < 4; ++nj) {
      bf0[nj] = *(const short8v*)(B0[s] + (nset + nj) * 512 + quad * 128 + fr * 8);
      bf1[nj] = *(const short8v*)(B1[s] + (nset + nj) * 512 + quad * 128 + fr * 8);
    }
#pragma unroll
    for (int mi = 0; mi < 4; ++mi)
#pragma unroll
      for (int nj = 0; nj < 4; ++nj) {
        acc[mi][nj] =
            __builtin_amdgcn_mfma_f32_16x16x32_bf16(af0[mi], bf0[nj], acc[mi][nj], 0, 0, 0);
        if (STYLE == 1) {
          acc[mi][nj] =
              __builtin_amdgcn_mfma_f32_16x16x32_bf16(af1[mi], bf0[nj], acc[mi][nj], 0, 0, 0);
          acc[mi][nj] =
              __builtin_amdgcn_mfma_f32_16x16x32_bf16(af0[mi], bf1[nj], acc[mi][nj], 0, 0, 0);
        } else {
          acc[mi][nj] =
              __builtin_amdgcn_mfma_f32_16x16x32_bf16(af1[mi], bf1[nj], acc[mi][nj], 0, 0, 0);
        }
      }
  };

  {
    const int nt = KH / SUB;
    stage(koff, 0);
    int ns = 1;
    if (nt > 1) {
      stage(koff + SUB, 1);
      ns = 2;
    }
    int cb = 0, sb2 = ns % PIPE;
    for (int tt = 0; tt < nt; ++tt) {
      if (ns > tt + 1) {
        asm volatile("s_waitcnt vmcnt(6)" ::: "memory");
      } else {
        asm volatile("s_waitcnt vmcnt(0)" ::: "memory");
      }
      asm volatile("s_barrier" ::: "memory");
      if (ns < nt) {
        stage(koff + ns * SUB, sb2);
        ++ns;
        sb2 = (sb2 + 1 == PIPE) ? 0 : sb2 + 1;
      }
      compute(cb);
      cb = (cb + 1 == PIPE) ? 0 : cb + 1;
    }
  }

#pragma unroll
  for (int mi = 0; mi < 4; ++mi) {
    int mrow = m_off + mi * 16 + quad * 4;
#pragma unroll
    for (int nj = 0; nj < 4; ++nj) {
      int col = n_off + nj * 16 + fr;
      if (EPIKS == 0) {
#pragma unroll
        for (int i = 0; i < 4; ++i)
          outp[(size_t)(M0 + mrow + i) * 256 + col] = acc[mi][nj][i];
      } else if (EPIKS == 3) {  // bias + relu + bf16 scatter (deconv1)
        float bv = bias[col];
#pragma unroll
        for (int i = 0; i < 4; ++i) {
          int m = M0 + mrow + i;
          float v = fmaxf(acc[mi][nj][i] + bv, 0.f);
          int nn = m >> 6, jj = (m >> 3) & 7, ii = m & 7;
          int oy = 2 * jj + 1 - py, ox = 2 * ii + 1 - px;
          outb[(size_t)((nn << 8) + oy * 16 + ox) * 256 + col] = f2bs(v);
        }
      } else {  // EPIKS 4: bias + relu + split H/L store (conv1)
        float bv = bias[col];
#pragma unroll
        for (int i = 0; i < 4; ++i) {
          int m = M0 + mrow + i;
          float v = fmaxf(acc[mi][nj][i] + bv, 0.f);
          size_t o = (size_t)m * 256 + col;
          ushort_t h = f2bs(v);
          outb[o] = h;
          outb2[o] = f2bs(v - bs2f(h));
        }
      }
    }
  }
}

// ---------------- K-split epilogue (+ optional fused rmsnorm) --------------
// One block per sample. Per-thread values kept in REGISTERS (fully unrolled,
// static indexing) — no 64 KB LDS stash (r11 occupancy trap) and no global
// out[] re-read in the NORM pass (r12's extra 16.7 MB/epi).
template <int RES, int NORM>
__global__ void __launch_bounds__(256) k_epi(const float* __restrict__ sc0,
                                             const float* __restrict__ sc1,
                                             const float* __restrict__ bias,
                                             const float* __restrict__ res,
                                             float* __restrict__ out,
                                             float* __restrict__ ssqp,
                                             const float* __restrict__ rmsw,
                                             ushort_t* __restrict__ NBh,
                                             ushort_t* __restrict__ NBl) {
  __shared__ float red[256];
  __shared__ float wl[256 * 65];
  int s = blockIdx.x, t = threadIdx.x;
  size_t base = (size_t)s * 16384;
  float bv = bias[t];
  if (NORM) {
    for (int k = 0; k < 64; ++k) {
      int i = k * 256 + t;
      wl[(i >> 6) * 65 + (i & 63)] = rmsw[i];
    }
  }
  float vstash[64];
  float sq = 0.f;
#pragma unroll
  for (int r = 0; r < 64; ++r) {
    size_t o = base + (size_t)r * 256 + t;
    float v = fmaxf(sc0[o] + sc1[o] + bv, 0.f);
    if (RES) v += res[o];
    out[o] = v;
    vstash[r] = v;
    sq += v * v;
  }
  red[t] = sq;
  __syncthreads();
  for (int k = 128; k > 0; k >>= 1) {
    if (t < k) red[t] += red[t + k];
    __syncthreads();
  }
  if (t == 0) ssqp[s] = red[0];
  if (NORM) {
    float scale = 1.0f / sqrtf(red[0] / 16384.f + 1.1920929e-07f);
    ushort_t* oh = NBh + base;
    ushort_t* ol = (NORM == 1) ? (NBl + base) : nullptr;
#pragma unroll
    for (int r = 0; r < 64; ++r) {
      float v = vstash[r] * scale * wl[t * 65 + r];
      ushort_t h = f2bs(v);
      oh[r * 256 + t] = h;
      if (NORM == 1) ol[r * 256 + t] = f2bs(v - bs2f(h));
    }
  }
}

// ---------------- rmsnorm normalize-only (1 standalone site: after VQ) ------
template <int SPLIT>
__global__ void __launch_bounds__(256) k_rmsnorm(const float* __restrict__ in,
                                                 const float* __restrict__ rmsw,
                                                 const float* __restrict__ ssq,
                                                 ushort_t* __restrict__ NBh,
                                                 ushort_t* __restrict__ NBl) {
  extern __shared__ float wT[];  // 64*257 floats
  int n = blockIdx.x, t = threadIdx.x;
  const float* p = in + (size_t)n * 16384;
  for (int k = 0; k < 64; ++k) {
    int i = k * 256 + t;  // i = c*64 + j
    wT[(i & 63) * 257 + (i >> 6)] = rmsw[i];
  }
  float scale = 1.0f / sqrtf(ssq[n] / 16384.f + 1.1920929e-07f);
  __syncthreads();
  ushort_t* oh = NBh + (size_t)n * 16384;
  ushort_t* ol = NBl + (size_t)n * 16384;
  for (int j = 0; j < 64; ++j) {
    int i = j * 256 + t;
    float v = p[i] * scale * wT[j * 257 + t];
    ushort_t h = f2bs(v);
    oh[i] = h;
    if (SPLIT) ol[i] = f2bs(v - bs2f(h));
  }
}

// ---------------- VQ (unchanged) ----------------
__global__ void __launch_bounds__(256) k_vq(const float* __restrict__ enc,
                                            const float* __restrict__ embT,
                                            const float* __restrict__ emb,
                                            const float* __restrict__ enorm,
                                            float* __restrict__ q, float* __restrict__ sse,
                                            float* __restrict__ ssq4) {
  __shared__ float z[16][256];
  __shared__ float sc[512 * 16];
  __shared__ float bv[16][16];
  __shared__ int bi[16][16];
  __shared__ int idxs[16];
  int T0 = blockIdx.x * 16;
  int t = threadIdx.x;
  for (int j = 0; j < 16; ++j) z[j][t] = enc[(size_t)(T0 + j) * 256 + t];
  __syncthreads();
  float d0[16], d1[16];
#pragma unroll
  for (int j = 0; j < 16; ++j) { d0[j] = 0.f; d1[j] = 0.f; }
  for (int c4 = 0; c4 < 64; ++c4) {
    const float* eb = embT + (size_t)(c4 * 4) * 512 + t;
    float e00 = eb[0], f00 = eb[256];
    float e01 = eb[512], f01 = eb[768];
    float e02 = eb[1024], f02 = eb[1280];
    float e03 = eb[1536], f03 = eb[1792];
#pragma unroll
    for (int j = 0; j < 16; ++j) {
      float4 zv = *(const float4*)&z[j][c4 * 4];
      d0[j] += zv.x * e00 + zv.y * e01 + zv.z * e02 + zv.w * e03;
      d1[j] += zv.x * f00 + zv.y * f01 + zv.z * f02 + zv.w * f03;
    }
  }
  float en0 = enorm[t], en1 = enorm[t + 256];
#pragma unroll
  for (int j = 0; j < 16; ++j) {
    sc[t * 16 + j] = en0 - 2.f * d0[j];
    sc[(t + 256) * 16 + j] = en1 - 2.f * d1[j];
  }
  __syncthreads();
  {
    int j = t & 15, chunk = t >> 4;
    float best = 3.4e38f;
    int bidx = 0;
    int c0 = chunk * 32;
    for (int cc = 0; cc < 32; ++cc) {
      float v = sc[(c0 + cc) * 16 + j];
      if (v < best) { best = v; bidx = c0 + cc; }
    }
    bv[chunk][j] = best;
    bi[chunk][j] = bidx;
  }
  __syncthreads();
  if (t < 16) {
    float best = 3.4e38f;
    int bidx = 0;
    for (int c = 0; c < 16; ++c) {
      float v = bv[c][t];
      if (v < best) { best = v; bidx = bi[c][t]; }
    }
    idxs[t] = bidx;
  }
  __syncthreads();
  float sq = 0.f, sqq = 0.f;
  for (int j = 0; j < 16; ++j) {
    float e = emb[(size_t)idxs[j] * 256 + t];
    q[(size_t)(T0 + j) * 256 + t] = e;
    float d = z[j][t] - e;
    sq += d * d;
    sqq += e * e;
  }
  __syncthreads();
  sc[t] = sq;
  __syncthreads();
  for (int k = 128; k > 0; k >>= 1) {
    if (t < k) sc[t] += sc[t + k];
    __syncthreads();
  }
  if (t == 0) atomicAdd(sse, sc[0]);
  __syncthreads();
  sc[t] = sqq;
  __syncthreads();
  for (int k = 128; k > 0; k >>= 1) {
    if (t < k) sc[t] += sc[t + k];
    __syncthreads();
  }
  if (t == 0) atomicAdd(&ssq4[blockIdx.x >> 2], sc[0]);
}

// ---------------- deconv2 as GEMM (256 tokens/block; G packed stride 48) ---
__global__ void __launch_bounds__(256) k_dec2gemm(const ushort_t* __restrict__ A,
                                                  const ushort_t* __restrict__ BH,
                                                  const ushort_t* __restrict__ BL,
                                                  float* __restrict__ G) {
  __shared__ __align__(16) ushort_t sBH[48 * 256];
  __shared__ __align__(16) ushort_t sBL[48 * 256];
  const int t = threadIdx.x;
  const int w = t >> 6, l = t & 63;
  const int fr = l & 15, quad = l >> 4, quad8 = quad * 8;
  for (int i = t * 8; i < 12288; i += 2048) {
    *(short8v*)(sBH + i) = *(const short8v*)(BH + i);
    *(short8v*)(sBL + i) = *(const short8v*)(BL + i);
  }
  __syncthreads();
  const int tok0 = blockIdx.x * 256 + w * 64;
  f32x4 acc[4][3];
#pragma unroll
  for (int i = 0; i < 4; ++i)
#pragma unroll
    for (int j = 0; j < 3; ++j) acc[i][j] = (f32x4){0.f, 0.f, 0.f, 0.f};
#pragma unroll
  for (int kk = 0; kk < 256; kk += 32) {
    short8v af[4];
#pragma unroll
    for (int mi = 0; mi < 4; ++mi)
      af[mi] = *(const short8v*)(A + (size_t)(tok0 + mi * 16 + fr) * 256 + kk + quad8);
#pragma unroll
    for (int nj = 0; nj < 3; ++nj) {
      short8v bh = *(const short8v*)(sBH + (nj * 16 + fr) * 256 + kk + quad8);
      short8v bl = *(const short8v*)(sBL + (nj * 16 + fr) * 256 + kk + quad8);
#pragma unroll
      for (int mi = 0; mi < 4; ++mi) {
        acc[mi][nj] =
            __builtin_amdgcn_mfma_f32_16x16x32_bf16(af[mi], bh, acc[mi][nj], 0, 0, 0);
        acc[mi][nj] =
            __builtin_amdgcn_mfma_f32_16x16x32_bf16(af[mi], bl, acc[mi][nj], 0, 0, 0);
      }
    }
  }
#pragma unroll
  for (int mi = 0; mi < 4; ++mi) {
    int mrow = mi * 16 + quad * 4;
#pragma unroll
    for (int nj = 0; nj < 3; ++nj) {
      int col = nj * 16 + fr;
#pragma unroll
      for (int i = 0; i < 4; ++i)
        G[(size_t)(tok0 + mrow + i) * 48 + col] = acc[mi][nj][i];
    }
  }
}

// ---------------- deconv2 gather + reconst loss (G stride 48, linear stage) -
__global__ void __launch_bounds__(256) k_dec2gather(const float* __restrict__ G,
                                                    const float* __restrict__ bias,
                                                    const float* __restrict__ x,
                                                    float* __restrict__ dec,
                                                    float* __restrict__ sse) {
  __shared__ float GL[256 * 49];
  __shared__ float red[256];
  int n = blockIdx.x, t = threadIdx.x;
  const float* Gs = G + (size_t)n * 12288;
  for (int i = t; i < 12288; i += 256) {
    int r = i / 48, c = i - r * 48;
    GL[r * 49 + c] = Gs[i];
  }
  __syncthreads();
  float sq = 0.f;
  for (int rep = 0; rep < 12; ++rep) {
    int o = rep * 256 + t;
    int oc = o >> 10, rem = o & 1023;
    int oy = rem >> 5, ox = rem & 31;
    int py = (oy + 1) & 1, dy = (oy + 1 - py) >> 1;
    int px = (ox + 1) & 1, dx = (ox + 1 - px) >> 1;
    int iy0 = dy - 1, ix0 = dx - 1;
    bool y0 = (unsigned)iy0 < 16u, y1 = (unsigned)dy < 16u;
    bool x0 = (unsigned)ix0 < 16u, x1 = (unsigned)dx < 16u;
    float v = bias[oc];
    if (y0 && x0) v += GL[(iy0 * 16 + ix0) * 49 + ((py + 2) * 4 + px + 2) * 3 + oc];
    if (y0 && x1) v += GL[(iy0 * 16 + dx) * 49 + ((py + 2) * 4 + px) * 3 + oc];
    if (y1 && x0) v += GL[(dy * 16 + ix0) * 49 + (py * 4 + px + 2) * 3 + oc];
    if (y1 && x1) v += GL[(dy * 16 + dx) * 49 + (py * 4 + px) * 3 + oc];
    int oi = ((n * 3 + oc) * 32 + oy) * 32 + ox;
    dec[oi] = v;
    float d = v - x[oi];
    sq += d * d;
  }
  red[t] = sq;
  __syncthreads();
  for (int k = 128; k > 0; k >>= 1) {
    if (t < k) red[t] += red[t + k];
    __syncthreads();
  }
  if (t == 0) atomicAdd(sse, red[0]);
}

__global__ void k_final(const float* __restrict__ acc, float* __restrict__ out) {
  if (threadIdx.x == 0 && blockIdx.x == 0) {
    float vq = acc[0] / 4194304.f;
    float rec = acc[1] / 786432.f;
    out[0] = rec + 2.f * vq;
    out[1] = rec;
    out[2] = vq;
    out[3] = vq;
  }
}

extern "C" void kernel_launch(void* const* d_in, const int* in_sizes, int n_in,
                              void* d_out, int out_size, void* d_ws, size_t ws_size,
                              hipStream_t stream) {
  (void)in_sizes; (void)n_in; (void)out_size; (void)ws_size;
  const float* x = (const float*)d_in[0];
  const float* ew1 = (const float*)d_in[1];
  const float* eb1 = (const float*)d_in[2];
  const float* ew2 = (const float*)d_in[3];
  const float* eb2 = (const float*)d_in[4];
  const float* rmsw = (const float*)d_in[5];
  const float* r3w = (const float*)d_in[6];
  const float* r3b = (const float*)d_in[7];
  const float* r1w = (const float*)d_in[8];
  const float* r1b = (const float*)d_in[9];
  const float* emb = (const float*)d_in[10];
  const float* dw1 = (const float*)d_in[11];
  const float* db1 = (const float*)d_in[12];
  const float* dw2 = (const float*)d_in[13];
  const float* db2 = (const float*)d_in[14];
  float* out = (float*)d_out;

  float* wsf = (float*)d_ws;
  float* P = wsf + OFF_P;
  float* enorm = wsf + OFF_ENORM;
  float* acc = wsf + OFF_ACC;
  float* zrowf = wsf + OFF_ZROW;
  float* embT = wsf + OFF_EMBT;
  float* ssq = wsf + OFF_SSQ;
  ushort_t* WD2H = (ushort_t*)(wsf + OFF_WD2);
  ushort_t* WD2L = WD2H + 12288;
  ushort_t* sb = (ushort_t*)(wsf + OFF_SHORT);
  ushort_t* H1H = sb + SO_H1H;
  ushort_t* H1L = sb + SO_H1L;
  float* Qf = (float*)(sb + SO_H1L);
  ushort_t* NBH = sb + SO_NBH;
  ushort_t* NBL = sb + SO_NBL;
  ushort_t* A1H = NBH;
  ushort_t* A1L = NBL;
  ushort_t* QB = NBL;
  ushort_t* W1H = sb + SO_W1H;
  ushort_t* W1L = sb + SO_W1L;
  ushort_t* W2H = sb + SO_W2H;
  ushort_t* W2L = sb + SO_W2L;
  ushort_t* W3EH = sb + SO_W3EH;
  ushort_t* W3EL = sb + SO_W3EL;
  ushort_t* W3D = sb + SO_W3D;
  ushort_t* W1REH = sb + SO_W1REH;
  ushort_t* W1REL = sb + SO_W1REL;
  ushort_t* W1RD = sb + SO_W1RD;
  ushort_t* WD1 = sb + SO_WD1;
  const ushort_t* zrow = (const ushort_t*)zrowf;
  float* NBf = (float*)(sb + SO_NBH);   // conv2 SC0 (A1 consumed by conv1)
  float* H1f = (float*)(sb + SO_H1H);   // res3 SC0 (H1 dead after conv2)
  const size_t RMS_LDS = 64 * 257 * sizeof(float);

  k_prep<<<35443, 256, 0, stream>>>(x, ew1, ew2, r3w, r1w, dw1, dw2, emb,
                                    W1H, W1L, W2H, W2L, W3EH, W3EL, W3D,
                                    W1REH, W1REL, W1RD, WD1, WD2H, WD2L, enorm,
                                    acc, zrowf, embT, ssq, A1H, A1L);

  // conv1 (split, K=64, BM=128, EPIKS=4 split-store): 512 blocks
  k_gemmks<0, 1, 4><<<dim3(512), 512, 0, stream>>>(
      A1H, A1L, W1H, W1L, 64, 64, nullptr, nullptr, eb1, H1H, H1L, zrow);

  // conv2 K-split + fused epi/rms (idx0) -> P, NBH/NBL, ssq0
  k_gemmks<1, 1, 0><<<dim3(128, 2), 512, 0, stream>>>(
      H1H, H1L, W2H, W2L, 4096, 2048, NBf, P, nullptr, nullptr, nullptr, zrow);
  k_epi<0, 1><<<256, 256, 0, stream>>>(NBf, P, eb2, nullptr, P, ssq + 0,
                                       rmsw + 0, NBH, NBL);

  // res3-enc rb0 + fused epi/rms (idx1) -> Qf, NBH/NBL
  k_gemmks<2, 1, 0><<<dim3(128, 2), 512, 0, stream>>>(
      NBH, NBL, W3EH, W3EL, 2304, 1152, H1f, Qf, nullptr, nullptr, nullptr, zrow);
  k_epi<1, 1><<<256, 256, 0, stream>>>(H1f, Qf, r3b, P, Qf, ssq + 256,
                                       rmsw + 1 * 16384, NBH, NBL);
  // res1-enc rb0 -> P, fused rms idx2 -> NBH/NBL (SSQ=2)
  k_gemm<0, 2, 1, 2><<<dim3(256), 512, 0, stream>>>(
      NBH, NBL, W1REH, W1REL, 256, r1b, Qf, P, NBH, NBL, zrow,
      (float*)(rmsw + 2 * 16384));
  // res3-enc rb1 + fused epi/rms (idx3)
  k_gemmks<2, 1, 0><<<dim3(128, 2), 512, 0, stream>>>(
      NBH, NBL, W3EH + 589824, W3EL + 589824, 2304, 1152, H1f, Qf, nullptr,
      nullptr, nullptr, zrow);
  k_epi<1, 1><<<256, 256, 0, stream>>>(H1f, Qf, r3b + 256, P, Qf, ssq + 768,
                                       rmsw + 3 * 16384, NBH, NBL);
  // res1-enc rb1 -> P (no ssq)
  k_gemm<0, 2, 1, 0><<<dim3(256), 512, 0, stream>>>(
      NBH, NBL, W1REH + 65536, W1REL + 65536, 256, r1b + 256, Qf, P, nullptr,
      nullptr, zrow, nullptr);

  // VQ: P -> Qf (q), sse -> acc[0], q-ssq -> slot 4; standalone rms idx4
  k_vq<<<1024, 256, 0, stream>>>(P, embT, emb, enorm, Qf, acc + 0, ssq + 1024);
  k_rmsnorm<0><<<256, 256, RMS_LDS, stream>>>(Qf, rmsw + 4 * 16384, ssq + 1024,
                                              NBH, NBL);

  // res3-dec rb2 + fused epi/rms (idx5, H-only) -> P, NBH
  k_gemmks<2, 0, 0><<<dim3(128, 2), 512, 0, stream>>>(
      NBH, nullptr, W3D, nullptr, 2304, 1152, H1f, P, nullptr, nullptr, nullptr,
      zrow);
  k_epi<1, 2><<<256, 256, 0, stream>>>(H1f, P, r3b + 2 * 256, Qf, P, ssq + 1280,
                                       rmsw + 5 * 16384, NBH, nullptr);
  // res1-dec rb2 -> Qf, fused rms idx6 -> NBH (SSQ=3, H only)
  k_gemm<0, 2, 0, 3><<<dim3(256), 512, 0, stream>>>(
      NBH, nullptr, W1RD, nullptr, 256, r1b + 2 * 256, P, Qf, NBH, nullptr,
      zrow, (float*)(rmsw + 6 * 16384));
  // res3-dec rb3 + fused epi/rms (idx7, H-only) -> P, NBH
  k_gemmks<2, 0, 0><<<dim3(128, 2), 512, 0, stream>>>(
      NBH, nullptr, W3D + 589824, nullptr, 2304, 1152, H1f, P, nullptr, nullptr,
      nullptr, zrow);
  k_epi<1, 2><<<256, 256, 0, stream>>>(H1f, P, r3b + 3 * 256, Qf, P, ssq + 1792,
                                       rmsw + 7 * 16384, NBH, nullptr);
  // res1-dec rb3 (EPI5) -> Qf + QB
  k_gemm<0, 5, 0, 0><<<dim3(256), 512, 0, stream>>>(
      NBH, nullptr, W1RD + 65536, nullptr, 256, r1b + 3 * 256, P, Qf, QB, nullptr,
      zrow, nullptr);

  // deconv1 (K=1024, 4 parity classes, BM=128, direct bf16 scatter)
  k_gemmks<3, 0, 3><<<dim3(128, 1, 4), 512, 0, stream>>>(
      QB, nullptr, WD1, nullptr, 1024, 1024, nullptr, nullptr, db1, H1H, nullptr,
      zrow);

  // deconv2: GEMM (G = tokens x W, 48 cols, stride 48) + gather/loss.
  k_dec2gemm<<<256, 256, 0, stream>>>(H1H, WD2H, WD2L, P);
  k_dec2gather<<<256, 256, 0, stream>>>(P, db2, x, out + 4, acc + 1);
  k_final<<<1, 64, 0, stream>>>(acc, out);
}